// Round 1
// baseline (4067.915 us; speedup 1.0000x reference)
//
#include <hip/hip_runtime.h>
#include <math.h>

#define BATCH 16
#define NPTS 1024
#define KNN 20

__device__ __forceinline__ float lrelu(float v) { return v >= 0.f ? v : 0.2f * v; }

// ---------------- derived weights: Wd[o,c] = W[o, C+c] - W[o, c] ----------------
__global__ __launch_bounds__(256)
void wdiff_kernel(const float* __restrict__ W, float* __restrict__ Wd, int O, int Cc) {
  int e = blockIdx.x * 256 + threadIdx.x;
  if (e < O * Cc) {
    int o = e / Cc, c = e - o * Cc;
    Wd[e] = W[o * 2 * Cc + Cc + c] - W[o * 2 * Cc + c];
  }
}

// ---------------- knn for C=3 (CN layout [B,3,N]) ----------------
__global__ __launch_bounds__(256)
void knn3_kernel(const float* __restrict__ x, int* __restrict__ idxout) {
  __shared__ float px[NPTS], py[NPTS], pz[NPTS];
  const int b = blockIdx.y;
  const float* xb = x + (size_t)b * 3 * NPTS;
  for (int e = threadIdx.x; e < NPTS; e += 256) {
    px[e] = xb[e]; py[e] = xb[NPTS + e]; pz[e] = xb[2 * NPTS + e];
  }
  __syncthreads();
  const int i = blockIdx.x * 256 + threadIdx.x;
  const float xi = px[i], yi = py[i], zi = pz[i];
  float bv[KNN]; int bi[KNN];
  #pragma unroll
  for (int r = 0; r < KNN; ++r) { bv[r] = 3.4e38f; bi[r] = -1; }
  for (int j = 0; j < NPTS; ++j) {
    float dx = px[j] - xi, dy = py[j] - yi, dz = pz[j] - zi;
    float d = dx * dx + dy * dy + dz * dz;
    if (d < bv[KNN - 1]) {
      float v = d; int ji = j;
      #pragma unroll
      for (int r = 0; r < KNN; ++r) {
        bool c = v < bv[r];
        float tv = bv[r]; int ti = bi[r];
        bv[r] = c ? v : bv[r]; bi[r] = c ? ji : bi[r];
        v = c ? tv : v; ji = c ? ti : ji;
      }
    }
  }
  int* op = idxout + (size_t)(b * NPTS + i) * KNN;
  #pragma unroll
  for (int r = 0; r < KNN; ++r) op[r] = bi[r];
}

// ---------------- knn for big C (NC layout rows, row stride given) ----------------
template<int C>
__global__ __launch_bounds__(256)
void knn_big_kernel(const float* __restrict__ X, int rowStride,
                    const float* __restrict__ xx, int* __restrict__ idxout) {
  __shared__ __align__(16) float xi[8][C];
  __shared__ float sc[8][NPTS];
  const int b = blockIdx.y;
  const int i0 = blockIdx.x * 8;
  for (int e = threadIdx.x; e < 8 * C; e += 256) {
    int r = e / C, c = e - r * C;
    xi[r][c] = X[(size_t)(b * NPTS + i0 + r) * rowStride + c];
  }
  __syncthreads();
  // phase 1: scores sc[r][j] = xx[j] - 2 * dot(xi[r], xj)
  for (int jt = 0; jt < 4; ++jt) {
    const int j = jt * 256 + threadIdx.x;
    const float* xj = X + (size_t)(b * NPTS + j) * rowStride;
    float acc[8];
    #pragma unroll
    for (int r = 0; r < 8; ++r) acc[r] = 0.f;
    #pragma unroll
    for (int c4 = 0; c4 < C / 4; ++c4) {
      const float4 v = *reinterpret_cast<const float4*>(xj + c4 * 4);
      #pragma unroll
      for (int r = 0; r < 8; ++r) {
        const float4 w = *reinterpret_cast<const float4*>(&xi[r][c4 * 4]);
        acc[r] = fmaf(w.x, v.x, acc[r]);
        acc[r] = fmaf(w.y, v.y, acc[r]);
        acc[r] = fmaf(w.z, v.z, acc[r]);
        acc[r] = fmaf(w.w, v.w, acc[r]);
      }
    }
    const float xxj = xx[b * NPTS + j];
    #pragma unroll
    for (int r = 0; r < 8; ++r) sc[r][j] = fmaf(-2.f, acc[r], xxj);
  }
  __syncthreads();
  // phase 2: per-wave iterative argmin selection (one wave owns rows r, r+4)
  const int wv = threadIdx.x >> 6, lane = threadIdx.x & 63;
  for (int r = wv; r < 8; r += 4) {
    float bestv = 3.4e38f; int bestj = NPTS;
    #pragma unroll
    for (int s = 0; s < 16; ++s) {
      int j = lane + 64 * s;
      float v = sc[r][j];
      if (v < bestv || (v == bestv && j < bestj)) { bestv = v; bestj = j; }
    }
    int* op = idxout + (size_t)(b * NPTS + i0 + r) * KNN;
    for (int t = 0; t < KNN; ++t) {
      float rv = bestv; int rj = bestj;
      #pragma unroll
      for (int off = 32; off > 0; off >>= 1) {
        float ov = __shfl_xor(rv, off);
        int oj = __shfl_xor(rj, off);
        if (ov < rv || (ov == rv && oj < rj)) { rv = ov; rj = oj; }
      }
      if (lane == 0) op[t] = rj;
      if (bestj == rj) {   // owner lane: remove winner, rescan its 16 slots
        sc[r][rj] = 3.4e38f;
        bestv = 3.4e38f; bestj = NPTS;
        #pragma unroll
        for (int s = 0; s < 16; ++s) {
          int j = lane + 64 * s;
          float v = sc[r][j];
          if (v < bestv || (v == bestv && j < bestj)) { bestv = v; bestj = j; }
        }
      }
    }
  }
}

// ---------------- generic fp32 GEMM: out[b,n,o] = sum_c X[b,n,c]*W[o,c] ----------------
// EPI=0: plain store out[b*sob + n*son + o]
// EPI=1: lrelu + column-max over the block's 64 n -> out[b*sob + blockIdx.x*snb + o]
template<int EPI>
__global__ __launch_bounds__(256)
void gemm_kernel(const float* __restrict__ X, int sxb, int sxn, int sxc,
                 const float* __restrict__ W, int swo, int C,
                 float* __restrict__ out, int sob, int son, int snb) {
  __shared__ __align__(16) float Xs[16][64];
  __shared__ __align__(16) float Ws[16][64];
  __shared__ __align__(16) float red[16][64];
  const int b = blockIdx.z;
  const int n0 = blockIdx.x * 64, o0 = blockIdx.y * 64;
  const int tid = threadIdx.x;
  const int lr = tid & 63;
  const int c4 = (tid >> 6) * 4;
  const int tn = tid & 15, to = tid >> 4;
  float acc[4][4];
  #pragma unroll
  for (int i = 0; i < 4; ++i)
    #pragma unroll
    for (int j = 0; j < 4; ++j) acc[i][j] = 0.f;

  const size_t xbase = (size_t)b * sxb;
  for (int k0 = 0; k0 < C; k0 += 16) {
    #pragma unroll
    for (int u = 0; u < 4; ++u) {
      int c = k0 + c4 + u;
      float xv = 0.f, wv = 0.f;
      if (c < C) {
        xv = X[xbase + (size_t)(n0 + lr) * sxn + (size_t)c * sxc];
        wv = W[(size_t)(o0 + lr) * swo + c];
      }
      Xs[c4 + u][lr] = xv;
      Ws[c4 + u][lr] = wv;
    }
    __syncthreads();
    #pragma unroll
    for (int kk = 0; kk < 16; ++kk) {
      const float4 xa = *reinterpret_cast<const float4*>(&Xs[kk][tn * 4]);
      const float4 wb = *reinterpret_cast<const float4*>(&Ws[kk][to * 4]);
      const float xr[4] = {xa.x, xa.y, xa.z, xa.w};
      const float wr[4] = {wb.x, wb.y, wb.z, wb.w};
      #pragma unroll
      for (int i = 0; i < 4; ++i)
        #pragma unroll
        for (int j = 0; j < 4; ++j) acc[i][j] = fmaf(xr[i], wr[j], acc[i][j]);
    }
    __syncthreads();
  }

  if (EPI == 0) {
    #pragma unroll
    for (int i = 0; i < 4; ++i) {
      float4 st = make_float4(acc[i][0], acc[i][1], acc[i][2], acc[i][3]);
      *reinterpret_cast<float4*>(&out[(size_t)b * sob + (size_t)(n0 + tn * 4 + i) * son + o0 + to * 4]) = st;
    }
  } else {
    #pragma unroll
    for (int j = 0; j < 4; ++j) {
      float m = lrelu(acc[0][j]);
      #pragma unroll
      for (int i = 1; i < 4; ++i) m = fmaxf(m, lrelu(acc[i][j]));
      red[tn][to * 4 + j] = m;
    }
    __syncthreads();
    if (tid < 64) {
      float m = red[0][tid];
      #pragma unroll
      for (int t = 1; t < 16; ++t) m = fmaxf(m, red[t][tid]);
      out[(size_t)b * sob + (size_t)blockIdx.x * snb + o0 + tid] = m;
    }
  }
}

// ---------------- edge max: out[b,i,o] = max_t lrelu(y[b,idx[t],o] + z[b,i,o]) ----------------
__global__ __launch_bounds__(256)
void edge_max_kernel(const float* __restrict__ y, const float* __restrict__ z,
                     const int* __restrict__ idx, float* __restrict__ out,
                     int O, int outStride, int outOff, float* __restrict__ xx) {
  __shared__ float sred[256];
  const int b = blockIdx.y;
  const int ipb = 256 / O;
  const int i_l = threadIdx.x / O, o = threadIdx.x - i_l * O;
  const int i = blockIdx.x * ipb + i_l;
  const int* ip = idx + (size_t)(b * NPTS + i) * KNN;
  const float zv = z[(size_t)(b * NPTS + i) * O + o];
  float m = -3.4e38f;
  #pragma unroll
  for (int t = 0; t < KNN; ++t) {
    int j = ip[t];
    float v = y[(size_t)(b * NPTS + j) * O + o] + zv;
    m = fmaxf(m, lrelu(v));
  }
  out[(size_t)(b * NPTS + i) * outStride + outOff + o] = m;
  if (xx != nullptr) {
    sred[threadIdx.x] = m * m;
    __syncthreads();
    for (int s = O / 2; s > 0; s >>= 1) {
      if (o < s) sred[threadIdx.x] += sred[threadIdx.x + s];
      __syncthreads();
    }
    if (o == 0) xx[b * NPTS + i] = sred[threadIdx.x];
  }
}

// ---------------- transform-net fused conv1(64) -> lrelu -> conv2(tw2,128) -> lrelu -> max_k ----------------
__global__ __launch_bounds__(128)
void h12_kernel(const float* __restrict__ ya, const float* __restrict__ zb,
                const int* __restrict__ idx, const float* __restrict__ tw2,
                float* __restrict__ h2max) {
  __shared__ __align__(16) float h1s[20][64];
  __shared__ __align__(16) float zbs[8][64];
  __shared__ int idxs[8][KNN];
  const int b = blockIdx.y;
  const int i0 = blockIdx.x * 8;
  const int tid = threadIdx.x;  // 128, o2 = tid
  float w[64];
  #pragma unroll
  for (int c4 = 0; c4 < 16; ++c4) {
    float4 v = *reinterpret_cast<const float4*>(&tw2[(size_t)tid * 64 + c4 * 4]);
    w[c4 * 4 + 0] = v.x; w[c4 * 4 + 1] = v.y; w[c4 * 4 + 2] = v.z; w[c4 * 4 + 3] = v.w;
  }
  for (int e = tid; e < 8 * 64; e += 128) {
    int il = e >> 6, c = e & 63;
    zbs[il][c] = zb[(size_t)(b * NPTS + i0 + il) * 64 + c];
  }
  for (int e = tid; e < 8 * KNN; e += 128) {
    idxs[e / KNN][e % KNN] = idx[(size_t)(b * NPTS + i0) * KNN + e];
  }
  __syncthreads();
  for (int il = 0; il < 8; ++il) {
    for (int e = tid; e < 20 * 64; e += 128) {
      int t = e >> 6, c = e & 63;
      int j = idxs[il][t];
      float v = ya[(size_t)(b * NPTS + j) * 64 + c] + zbs[il][c];
      h1s[t][c] = lrelu(v);
    }
    __syncthreads();
    float m = -3.4e38f;
    for (int t = 0; t < 20; ++t) {
      float a = 0.f;
      #pragma unroll
      for (int c4 = 0; c4 < 16; ++c4) {
        float4 h = *reinterpret_cast<const float4*>(&h1s[t][c4 * 4]);
        a = fmaf(w[c4 * 4 + 0], h.x, a);
        a = fmaf(w[c4 * 4 + 1], h.y, a);
        a = fmaf(w[c4 * 4 + 2], h.z, a);
        a = fmaf(w[c4 * 4 + 3], h.w, a);
      }
      m = fmaxf(m, lrelu(a));
    }
    h2max[(size_t)(b * NPTS + i0 + il) * 128 + tid] = m;
    __syncthreads();
  }
}

// ---------------- reduce partial max over 16 n-tiles ----------------
__global__ __launch_bounds__(256)
void reduce_max_kernel(const float* __restrict__ part, float* __restrict__ outp) {
  const int b = blockIdx.y;
  const int o = blockIdx.x * 256 + threadIdx.x;
  float m = part[(size_t)(b * 16) * 1024 + o];
  #pragma unroll
  for (int t = 1; t < 16; ++t) m = fmaxf(m, part[(size_t)(b * 16 + t) * 1024 + o]);
  outp[b * 1024 + o] = m;
}

// ---------------- block reduce helper ----------------
__device__ __forceinline__ float block_reduce_sum(float v, float* rbuf) {
  #pragma unroll
  for (int off = 32; off > 0; off >>= 1) v += __shfl_xor(v, off);
  const int w = threadIdx.x >> 6, lane = threadIdx.x & 63;
  const int nw = blockDim.x >> 6;
  if (lane == 0) rbuf[w] = v;
  __syncthreads();
  float tot = 0.f;
  for (int i = 0; i < nw; ++i) tot += rbuf[i];
  __syncthreads();
  return tot;
}

// ---------------- fc1: l2n -> 1024x512 (no bias) -> LN -> lrelu ----------------
__global__ __launch_bounds__(256)
void fc1_kernel(const float* __restrict__ gin_g, const float* __restrict__ Wt,
                const float* __restrict__ gam, const float* __restrict__ bet,
                float* __restrict__ outp) {
  __shared__ __align__(16) float gin[1024];
  __shared__ float hbuf[512];
  __shared__ float rbuf[8];
  const int b = blockIdx.x, tid = threadIdx.x;
  for (int e = tid; e < 1024; e += 256) gin[e] = gin_g[b * 1024 + e];
  __syncthreads();
  float ps = 0.f;
  for (int e = tid; e < 1024; e += 256) ps = fmaf(gin[e], gin[e], ps);
  float ss = block_reduce_sum(ps, rbuf);
  float rinv = 1.0f / sqrtf(ss);
  #pragma unroll
  for (int r = 0; r < 2; ++r) {
    int o = tid + r * 256;
    const float* wrow = Wt + (size_t)o * 1024;
    float a = 0.f;
    for (int c4 = 0; c4 < 256; ++c4) {
      float4 wv = *reinterpret_cast<const float4*>(wrow + c4 * 4);
      float4 gv = *reinterpret_cast<const float4*>(&gin[c4 * 4]);
      a = fmaf(wv.x, gv.x, a); a = fmaf(wv.y, gv.y, a);
      a = fmaf(wv.z, gv.z, a); a = fmaf(wv.w, gv.w, a);
    }
    hbuf[o] = a * rinv;
  }
  __syncthreads();
  float pm = hbuf[tid] + hbuf[tid + 256];
  float mean = block_reduce_sum(pm, rbuf) * (1.f / 512.f);
  float d0 = hbuf[tid] - mean, d1 = hbuf[tid + 256] - mean;
  float var = block_reduce_sum(d0 * d0 + d1 * d1, rbuf) * (1.f / 512.f);
  float rs = 1.0f / sqrtf(var + 1e-5f);
  #pragma unroll
  for (int r = 0; r < 2; ++r) {
    int o = tid + r * 256;
    float yv = (hbuf[o] - mean) * rs * gam[o] + bet[o];
    outp[b * 512 + o] = lrelu(yv);
  }
}

// ---------------- fc2: l2n -> 512x256 (+bias) -> LN -> lrelu ----------------
__global__ __launch_bounds__(256)
void fc2_kernel(const float* __restrict__ inp, const float* __restrict__ Wt,
                const float* __restrict__ bias, const float* __restrict__ gam,
                const float* __restrict__ bet, float* __restrict__ outp) {
  __shared__ __align__(16) float gin[512];
  __shared__ float rbuf[8];
  const int b = blockIdx.x, tid = threadIdx.x;
  for (int e = tid; e < 512; e += 256) gin[e] = inp[b * 512 + e];
  __syncthreads();
  float ps = 0.f;
  for (int e = tid; e < 512; e += 256) ps = fmaf(gin[e], gin[e], ps);
  float ss = block_reduce_sum(ps, rbuf);
  float rinv = 1.0f / sqrtf(ss);
  const float* wrow = Wt + (size_t)tid * 512;
  float a = 0.f;
  for (int c4 = 0; c4 < 128; ++c4) {
    float4 wv = *reinterpret_cast<const float4*>(wrow + c4 * 4);
    float4 gv = *reinterpret_cast<const float4*>(&gin[c4 * 4]);
    a = fmaf(wv.x, gv.x, a); a = fmaf(wv.y, gv.y, a);
    a = fmaf(wv.z, gv.z, a); a = fmaf(wv.w, gv.w, a);
  }
  a = a * rinv + bias[tid];
  float mean = block_reduce_sum(a, rbuf) * (1.f / 256.f);
  float d = a - mean;
  float var = block_reduce_sum(d * d, rbuf) * (1.f / 256.f);
  float rs = 1.0f / sqrtf(var + 1e-5f);
  float yv = (a - mean) * rs * gam[tid] + bet[tid];
  outp[b * 256 + tid] = lrelu(yv);
}

// ---------------- fc3 + identity ----------------
__global__ __launch_bounds__(64)
void fc3_kernel(const float* __restrict__ inp, const float* __restrict__ Wt,
                const float* __restrict__ bias, float* __restrict__ tmat) {
  __shared__ float gin[256];
  const int b = blockIdx.x, tid = threadIdx.x;
  for (int e = tid; e < 256; e += 64) gin[e] = inp[b * 256 + e];
  __syncthreads();
  if (tid < 9) {
    const float* wrow = Wt + tid * 256;
    float a = 0.f;
    for (int c = 0; c < 256; ++c) a = fmaf(wrow[c], gin[c], a);
    a += bias[tid];
    if (tid == 0 || tid == 4 || tid == 8) a += 1.f;
    tmat[b * 9 + tid] = a;
  }
}

// ---------------- apply 3x3 transform: xt[b,i,n] = sum_j t[b,i,j]*x[b,j,n] ----------------
__global__ __launch_bounds__(256)
void xform_kernel(const float* __restrict__ x, const float* __restrict__ tmat,
                  float* __restrict__ xt) {
  const int b = blockIdx.y;
  const int n = blockIdx.x * 256 + threadIdx.x;
  const float* xb = x + (size_t)b * 3 * NPTS;
  const float x0 = xb[n], x1 = xb[NPTS + n], x2 = xb[2 * NPTS + n];
  const float* t = tmat + b * 9;
  float* ob = xt + (size_t)b * 3 * NPTS;
  #pragma unroll
  for (int i = 0; i < 3; ++i)
    ob[i * NPTS + n] = fmaf(t[3 * i], x0, fmaf(t[3 * i + 1], x1, t[3 * i + 2] * x2));
}

extern "C" void kernel_launch(void* const* d_in, const int* in_sizes, int n_in,
                              void* d_out, int out_size, void* d_ws, size_t ws_size,
                              hipStream_t stream) {
  (void)in_sizes; (void)n_in; (void)out_size; (void)ws_size;
  const float* x       = (const float*)d_in[0];
  const float* tw1     = (const float*)d_in[1];
  const float* tw2     = (const float*)d_in[2];
  const float* tw3     = (const float*)d_in[3];
  const float* tfc1_w  = (const float*)d_in[4];
  const float* tfc1_g  = (const float*)d_in[5];
  const float* tfc1_b  = (const float*)d_in[6];
  const float* tfc2_w  = (const float*)d_in[7];
  const float* tfc2_bias = (const float*)d_in[8];
  const float* tfc2_g  = (const float*)d_in[9];
  const float* tfc2_b  = (const float*)d_in[10];
  const float* tfc3_w  = (const float*)d_in[11];
  const float* tfc3_b  = (const float*)d_in[12];
  const float* w1      = (const float*)d_in[13];
  const float* w2      = (const float*)d_in[14];
  const float* w3      = (const float*)d_in[15];
  const float* w4      = (const float*)d_in[16];
  const float* w5      = (const float*)d_in[17];
  float* out = (float*)d_out;

  char* wsb = (char*)d_ws;
  size_t off = 0;
  auto alloc = [&](size_t bytes) -> void* {
    void* p = wsb + off;
    off += (bytes + 255) & ~(size_t)255;
    return p;
  };
  float* ybuf = (float*)alloc((size_t)BATCH * NPTS * 256 * 4);
  float* zbuf = (float*)alloc((size_t)BATCH * NPTS * 256 * 4);
  float* xc   = (float*)alloc((size_t)BATCH * NPTS * 512 * 4);
  float* h2m  = (float*)alloc((size_t)BATCH * NPTS * 128 * 4);
  float* part = (float*)alloc((size_t)BATCH * 16 * 1024 * 4);
  int*   idxb = (int*)alloc((size_t)BATCH * NPTS * KNN * 4);
  float* xxb  = (float*)alloc((size_t)BATCH * NPTS * 4);
  float* xt   = (float*)alloc((size_t)BATCH * 3 * NPTS * 4);
  float* gbuf = (float*)alloc((size_t)BATCH * 1024 * 4);
  float* f1o  = (float*)alloc((size_t)BATCH * 512 * 4);
  float* f2o  = (float*)alloc((size_t)BATCH * 256 * 4);
  float* tmat = (float*)alloc((size_t)BATCH * 9 * 4);
  float* tw1d = (float*)alloc(64 * 3 * 4);
  float* w1d  = (float*)alloc(64 * 3 * 4);
  float* w2d  = (float*)alloc(64 * 64 * 4);
  float* w3d  = (float*)alloc(128 * 64 * 4);
  float* w4d  = (float*)alloc(256 * 128 * 4);

  // derived weights
  wdiff_kernel<<<1, 256, 0, stream>>>(tw1, tw1d, 64, 3);
  wdiff_kernel<<<1, 256, 0, stream>>>(w1, w1d, 64, 3);
  wdiff_kernel<<<16, 256, 0, stream>>>(w2, w2d, 64, 64);
  wdiff_kernel<<<32, 256, 0, stream>>>(w3, w3d, 128, 64);
  wdiff_kernel<<<128, 256, 0, stream>>>(w4, w4d, 256, 128);

  // ---- transform net ----
  knn3_kernel<<<dim3(4, 16), 256, 0, stream>>>(x, idxb);
  // ya = tw1[:, :3] @ x   ; zb = (tw1[:,3:] - tw1[:,:3]) @ x   (both [B,N,64])
  gemm_kernel<0><<<dim3(16, 1, 16), 256, 0, stream>>>(x, 3 * NPTS, 1, NPTS, tw1, 6, 3,
                                                      ybuf, NPTS * 64, 64, 0);
  gemm_kernel<0><<<dim3(16, 1, 16), 256, 0, stream>>>(x, 3 * NPTS, 1, NPTS, tw1d, 3, 3,
                                                      zbuf, NPTS * 64, 64, 0);
  h12_kernel<<<dim3(128, 16), 128, 0, stream>>>(ybuf, zbuf, idxb, tw2, h2m);
  // h3 = lrelu(tw3 @ h2max), partial max over n
  gemm_kernel<1><<<dim3(16, 16, 16), 256, 0, stream>>>(h2m, NPTS * 128, 128, 1, tw3, 128, 128,
                                                       part, 16 * 1024, 0, 1024);
  reduce_max_kernel<<<dim3(4, 16), 256, 0, stream>>>(part, gbuf);
  fc1_kernel<<<16, 256, 0, stream>>>(gbuf, tfc1_w, tfc1_g, tfc1_b, f1o);
  fc2_kernel<<<16, 256, 0, stream>>>(f1o, tfc2_w, tfc2_bias, tfc2_g, tfc2_b, f2o);
  fc3_kernel<<<16, 64, 0, stream>>>(f2o, tfc3_w, tfc3_b, tmat);
  xform_kernel<<<dim3(4, 16), 256, 0, stream>>>(x, tmat, xt);

  // ---- EdgeConv 1 (C=3 -> O=64), input xt (CN layout) ----
  knn3_kernel<<<dim3(4, 16), 256, 0, stream>>>(xt, idxb);
  gemm_kernel<0><<<dim3(16, 1, 16), 256, 0, stream>>>(xt, 3 * NPTS, 1, NPTS, w1, 6, 3,
                                                      ybuf, NPTS * 64, 64, 0);
  gemm_kernel<0><<<dim3(16, 1, 16), 256, 0, stream>>>(xt, 3 * NPTS, 1, NPTS, w1d, 3, 3,
                                                      zbuf, NPTS * 64, 64, 0);
  edge_max_kernel<<<dim3(256, 16), 256, 0, stream>>>(ybuf, zbuf, idxb, xc, 64, 512, 0, xxb);

  // ---- EdgeConv 2 (C=64 -> O=64), input xc[:, :, 0:64] ----
  knn_big_kernel<64><<<dim3(128, 16), 256, 0, stream>>>(xc, 512, xxb, idxb);
  gemm_kernel<0><<<dim3(16, 1, 16), 256, 0, stream>>>(xc, NPTS * 512, 512, 1, w2, 128, 64,
                                                      ybuf, NPTS * 64, 64, 0);
  gemm_kernel<0><<<dim3(16, 1, 16), 256, 0, stream>>>(xc, NPTS * 512, 512, 1, w2d, 64, 64,
                                                      zbuf, NPTS * 64, 64, 0);
  edge_max_kernel<<<dim3(256, 16), 256, 0, stream>>>(ybuf, zbuf, idxb, xc, 64, 512, 64, xxb);

  // ---- EdgeConv 3 (C=64 -> O=128), input xc[:, :, 64:128] ----
  knn_big_kernel<64><<<dim3(128, 16), 256, 0, stream>>>(xc + 64, 512, xxb, idxb);
  gemm_kernel<0><<<dim3(16, 2, 16), 256, 0, stream>>>(xc + 64, NPTS * 512, 512, 1, w3, 128, 64,
                                                      ybuf, NPTS * 128, 128, 0);
  gemm_kernel<0><<<dim3(16, 2, 16), 256, 0, stream>>>(xc + 64, NPTS * 512, 512, 1, w3d, 64, 64,
                                                      zbuf, NPTS * 128, 128, 0);
  edge_max_kernel<<<dim3(512, 16), 256, 0, stream>>>(ybuf, zbuf, idxb, xc, 128, 512, 128, xxb);

  // ---- EdgeConv 4 (C=128 -> O=256), input xc[:, :, 128:256] ----
  knn_big_kernel<128><<<dim3(128, 16), 256, 0, stream>>>(xc + 128, 512, xxb, idxb);
  gemm_kernel<0><<<dim3(16, 4, 16), 256, 0, stream>>>(xc + 128, NPTS * 512, 512, 1, w4, 256, 128,
                                                      ybuf, NPTS * 256, 256, 0);
  gemm_kernel<0><<<dim3(16, 4, 16), 256, 0, stream>>>(xc + 128, NPTS * 512, 512, 1, w4d, 128, 128,
                                                      zbuf, NPTS * 256, 256, 0);
  edge_max_kernel<<<dim3(1024, 16), 256, 0, stream>>>(ybuf, zbuf, idxb, xc, 256, 512, 256, nullptr);

  // ---- final: x5 = lrelu(w5 @ xc) with max over n ----
  gemm_kernel<1><<<dim3(16, 16, 16), 256, 0, stream>>>(xc, NPTS * 512, 512, 1, w5, 512, 512,
                                                       part, 16 * 1024, 0, 1024);
  reduce_max_kernel<<<dim3(4, 16), 256, 0, stream>>>(part, out);
}

// Round 2
// 1702.021 us; speedup vs baseline: 2.3900x; 2.3900x over previous
//
#include <hip/hip_runtime.h>
#include <math.h>

#define BATCH 16
#define NPTS 1024
#define KNN 20

__device__ __forceinline__ float lrelu(float v) { return v >= 0.f ? v : 0.2f * v; }

// ---- weight prep: W[O][2C] -> WaT[C][O] = W[:, :C]^T ; WdT[C][O] = (W[:,C:]-W[:,:C])^T ----
__global__ __launch_bounds__(256)
void wsplit_t_kernel(const float* __restrict__ W, float* __restrict__ waT,
                     float* __restrict__ wdT, int O, int Cc) {
  int e = blockIdx.x * 256 + threadIdx.x;
  if (e < O * Cc) {
    int c = e / O, o = e - c * O;
    float a = W[o * 2 * Cc + c], bb = W[o * 2 * Cc + Cc + c];
    waT[e] = a; wdT[e] = bb - a;
  }
}

// ---- weight transpose: W[O][C] -> wT[C][O] ----
__global__ __launch_bounds__(256)
void wtrans_kernel(const float* __restrict__ W, float* __restrict__ wT, int O, int Cc) {
  int e = blockIdx.x * 256 + threadIdx.x;
  if (e < O * Cc) {
    int c = e / O, o = e - c * O;
    wT[e] = W[(size_t)o * Cc + c];
  }
}

// ---- xx[b][n] = sum_c x[b][c][n]^2 for C=3 CN input ----
__global__ __launch_bounds__(256)
void xx3_kernel(const float* __restrict__ x, float* __restrict__ xx) {
  const int b = blockIdx.y;
  const int n = blockIdx.x * 256 + threadIdx.x;
  const float* xb = x + (size_t)b * 3 * NPTS;
  float a = xb[n], bb = xb[NPTS + n], c = xb[2 * NPTS + n];
  xx[b * NPTS + n] = a * a + bb * bb + c * c;
}

// ---- knn on channel-major features: Xt[b][c][n], batch stride sb ----
// Block: 16 queries, all 1024 j. Scores in LDS; per-wave 4 queries selection.
template<int C>
__global__ __launch_bounds__(256)
void knn_cn_kernel(const float* __restrict__ Xt, long sb,
                   const float* __restrict__ xx, int* __restrict__ idxout) {
  __shared__ float sc[16][NPTS];   // 64 KB
  const int b = blockIdx.y, i0 = blockIdx.x * 16;
  const int tid = threadIdx.x;
  const float* Xb = Xt + (size_t)b * sb;
  const int j0 = tid * 4;
  float acc[16][4];
  #pragma unroll
  for (int q = 0; q < 16; ++q)
    #pragma unroll
    for (int u = 0; u < 4; ++u) acc[q][u] = 0.f;
  for (int c = 0; c < C; ++c) {
    const float4 xv = *reinterpret_cast<const float4*>(Xb + (size_t)c * NPTS + j0);
    const float* xr = Xb + (size_t)c * NPTS + i0;   // uniform addresses -> scalar loads
    #pragma unroll
    for (int q = 0; q < 16; ++q) {
      const float xiq = xr[q];
      acc[q][0] = fmaf(xiq, xv.x, acc[q][0]);
      acc[q][1] = fmaf(xiq, xv.y, acc[q][1]);
      acc[q][2] = fmaf(xiq, xv.z, acc[q][2]);
      acc[q][3] = fmaf(xiq, xv.w, acc[q][3]);
    }
  }
  const float4 xxj = *reinterpret_cast<const float4*>(xx + b * NPTS + j0);
  #pragma unroll
  for (int q = 0; q < 16; ++q) {
    float4 st;
    st.x = fmaf(-2.f, acc[q][0], xxj.x);
    st.y = fmaf(-2.f, acc[q][1], xxj.y);
    st.z = fmaf(-2.f, acc[q][2], xxj.z);
    st.w = fmaf(-2.f, acc[q][3], xxj.w);
    *reinterpret_cast<float4*>(&sc[q][j0]) = st;
  }
  __syncthreads();
  // selection: wave w owns queries 4w..4w+3; candidate set in registers + dead mask
  const int wv = tid >> 6, lane = tid & 63;
  for (int qq = 0; qq < 4; ++qq) {
    const int q = wv * 4 + qq;
    float v[16];
    #pragma unroll
    for (int s = 0; s < 16; ++s) v[s] = sc[q][lane + 64 * s];
    unsigned dead = 0u;
    float bestv; int bestj;
    auto rescan = [&]() {
      bestv = 3.4e38f; bestj = 1 << 30;
      #pragma unroll
      for (int s = 0; s < 16; ++s) {
        const bool ok = ((dead >> s) & 1u) == 0u;
        const float val = v[s];
        if (ok && val < bestv) { bestv = val; bestj = lane + 64 * s; }
      }
    };
    rescan();
    int myidx = 0;
    for (int t = 0; t < KNN; ++t) {
      float rv = bestv; int rj = bestj;
      #pragma unroll
      for (int off = 32; off > 0; off >>= 1) {
        const float ov = __shfl_xor(rv, off);
        const int oj = __shfl_xor(rj, off);
        if (ov < rv || (ov == rv && oj < rj)) { rv = ov; rj = oj; }
      }
      if (lane == t) myidx = rj;
      if (bestj == rj) { dead |= 1u << ((bestj - lane) >> 6); rescan(); }
    }
    if (lane < KNN) idxout[(size_t)(b * NPTS + i0 + q) * KNN + lane] = myidx;
  }
}

// ---- generic fp32 GEMM: out[b,n,o] = sum_c X[b,n,c]*W[o,c], W passed TRANSPOSED WT[c][o] ----
// EPI=0: plain NC store; EPI=1: lrelu + column-max over the block's 64 n
template<int EPI>
__global__ __launch_bounds__(256)
void gemm_kernel(const float* __restrict__ X, long sxb, int sxn, int sxc,
                 const float* __restrict__ WT, int ldW, int C,
                 float* __restrict__ out, int sob, int son, int snb) {
  __shared__ __align__(16) float Xs[16][64];
  __shared__ __align__(16) float Ws[16][64];
  __shared__ __align__(16) float red[16][64];
  const int b = blockIdx.z;
  const int n0 = blockIdx.x * 64, o0 = blockIdx.y * 64;
  const int tid = threadIdx.x;
  const int lr = tid & 63;
  const int c4 = (tid >> 6) * 4;
  const int tn = tid & 15, to = tid >> 4;
  float acc[4][4];
  #pragma unroll
  for (int i = 0; i < 4; ++i)
    #pragma unroll
    for (int j = 0; j < 4; ++j) acc[i][j] = 0.f;

  const size_t xbase = (size_t)b * sxb;
  for (int k0 = 0; k0 < C; k0 += 16) {
    #pragma unroll
    for (int u = 0; u < 4; ++u) {
      int c = k0 + c4 + u;
      float xv = 0.f, wv = 0.f;
      if (c < C) {
        xv = X[xbase + (size_t)(n0 + lr) * sxn + (size_t)c * sxc];
        wv = WT[(size_t)c * ldW + o0 + lr];
      }
      Xs[c4 + u][lr] = xv;
      Ws[c4 + u][lr] = wv;
    }
    __syncthreads();
    #pragma unroll
    for (int kk = 0; kk < 16; ++kk) {
      const float4 xa = *reinterpret_cast<const float4*>(&Xs[kk][tn * 4]);
      const float4 wb = *reinterpret_cast<const float4*>(&Ws[kk][to * 4]);
      const float xr[4] = {xa.x, xa.y, xa.z, xa.w};
      const float wr[4] = {wb.x, wb.y, wb.z, wb.w};
      #pragma unroll
      for (int i = 0; i < 4; ++i)
        #pragma unroll
        for (int j = 0; j < 4; ++j) acc[i][j] = fmaf(xr[i], wr[j], acc[i][j]);
    }
    __syncthreads();
  }

  if (EPI == 0) {
    #pragma unroll
    for (int i = 0; i < 4; ++i) {
      float4 st = make_float4(acc[i][0], acc[i][1], acc[i][2], acc[i][3]);
      *reinterpret_cast<float4*>(&out[(size_t)b * sob + (size_t)(n0 + tn * 4 + i) * son + o0 + to * 4]) = st;
    }
  } else {
    #pragma unroll
    for (int j = 0; j < 4; ++j) {
      float m = lrelu(acc[0][j]);
      #pragma unroll
      for (int i = 1; i < 4; ++i) m = fmaxf(m, lrelu(acc[i][j]));
      red[tn][to * 4 + j] = m;
    }
    __syncthreads();
    if (tid < 64) {
      float m = red[0][tid];
      #pragma unroll
      for (int t = 1; t < 16; ++t) m = fmaxf(m, red[t][tid]);
      out[(size_t)b * sob + (size_t)blockIdx.x * snb + o0 + tid] = m;
    }
  }
}

// ---- edge max, channel-major output via LDS transpose tile ----
// y,z are NC [B,N,O]; outCN base points at channel slice, batch stride 512*NPTS.
template<int O, int TI>
__global__ __launch_bounds__(256)
void edge_max_cn_kernel(const float* __restrict__ y, const float* __restrict__ z,
                        const int* __restrict__ idx, float* __restrict__ outCN,
                        float* __restrict__ xx) {
  __shared__ float tile[TI][O + 1];
  const int b = blockIdx.y;
  const int i0 = blockIdx.x * TI;
  const int wv = threadIdx.x >> 6, lane = threadIdx.x & 63;
  constexpr int OSEG = O / 64;
  constexpr int ROUNDS = TI * OSEG / 4;
  for (int r = 0; r < ROUNDS; ++r) {
    const int item = r * 4 + wv;
    const int il = item / OSEG, os = item - il * OSEG;
    const int i = i0 + il, o = os * 64 + lane;
    const int* ip = idx + (size_t)(b * NPTS + i) * KNN;
    const float zv = z[(size_t)(b * NPTS + i) * O + o];
    float m = -3.4e38f;
    #pragma unroll
    for (int t = 0; t < KNN; ++t) {
      int j = ip[t];
      float v = y[(size_t)(b * NPTS + j) * O + o] + zv;
      m = fmaxf(m, lrelu(v));
    }
    tile[il][o] = m;
  }
  __syncthreads();
  if (xx != nullptr && threadIdx.x < TI) {
    const int il = threadIdx.x;
    float s = 0.f;
    #pragma unroll
    for (int o = 0; o < O; ++o) { float v = tile[il][o]; s = fmaf(v, v, s); }
    xx[b * NPTS + i0 + il] = s;
  }
  for (int e = threadIdx.x; e < TI * O; e += 256) {
    const int o = e / TI, il = e - o * TI;
    outCN[(size_t)b * 512 * NPTS + (size_t)o * NPTS + i0 + il] = tile[il][o];
  }
}

// ---- transform-net fused conv1(64)->lrelu->conv2(tw2,128)->lrelu->max_k, CN output ----
__global__ __launch_bounds__(128)
void h12_kernel(const float* __restrict__ ya, const float* __restrict__ zb,
                const int* __restrict__ idx, const float* __restrict__ tw2,
                float* __restrict__ h2m) {
  __shared__ __align__(16) float h1s[20][64];
  __shared__ __align__(16) float zbs[8][64];
  __shared__ int idxs[8][KNN];
  __shared__ float ot[128][9];
  const int b = blockIdx.y;
  const int i0 = blockIdx.x * 8;
  const int tid = threadIdx.x;  // o2 = tid
  float w[64];
  #pragma unroll
  for (int c4 = 0; c4 < 16; ++c4) {
    float4 v = *reinterpret_cast<const float4*>(&tw2[(size_t)tid * 64 + c4 * 4]);
    w[c4 * 4 + 0] = v.x; w[c4 * 4 + 1] = v.y; w[c4 * 4 + 2] = v.z; w[c4 * 4 + 3] = v.w;
  }
  for (int e = tid; e < 8 * 64; e += 128) {
    int il = e >> 6, c = e & 63;
    zbs[il][c] = zb[(size_t)(b * NPTS + i0 + il) * 64 + c];
  }
  for (int e = tid; e < 8 * KNN; e += 128) {
    idxs[e / KNN][e % KNN] = idx[(size_t)(b * NPTS + i0) * KNN + e];
  }
  __syncthreads();
  for (int il = 0; il < 8; ++il) {
    for (int e = tid; e < 20 * 64; e += 128) {
      int t = e >> 6, c = e & 63;
      int j = idxs[il][t];
      float v = ya[(size_t)(b * NPTS + j) * 64 + c] + zbs[il][c];
      h1s[t][c] = lrelu(v);
    }
    __syncthreads();
    float m = -3.4e38f;
    for (int t = 0; t < 20; ++t) {
      float a = 0.f;
      #pragma unroll
      for (int c4 = 0; c4 < 16; ++c4) {
        float4 h = *reinterpret_cast<const float4*>(&h1s[t][c4 * 4]);
        a = fmaf(w[c4 * 4 + 0], h.x, a);
        a = fmaf(w[c4 * 4 + 1], h.y, a);
        a = fmaf(w[c4 * 4 + 2], h.z, a);
        a = fmaf(w[c4 * 4 + 3], h.w, a);
      }
      m = fmaxf(m, lrelu(a));
    }
    ot[tid][il] = m;
    __syncthreads();
  }
  for (int e = tid; e < 8 * 128; e += 128) {
    int o = e >> 3, il = e & 7;
    h2m[(size_t)(b * 128 + o) * NPTS + i0 + il] = ot[o][il];
  }
}

// ---- reduce partial max over 16 n-tiles ----
__global__ __launch_bounds__(256)
void reduce_max_kernel(const float* __restrict__ part, float* __restrict__ outp) {
  const int b = blockIdx.y;
  const int o = blockIdx.x * 256 + threadIdx.x;
  float m = part[(size_t)(b * 16) * 1024 + o];
  #pragma unroll
  for (int t = 1; t < 16; ++t) m = fmaxf(m, part[(size_t)(b * 16 + t) * 1024 + o]);
  outp[b * 1024 + o] = m;
}

// ---- block reduce helper ----
__device__ __forceinline__ float block_reduce_sum(float v, float* rbuf) {
  #pragma unroll
  for (int off = 32; off > 0; off >>= 1) v += __shfl_xor(v, off);
  const int w = threadIdx.x >> 6, lane = threadIdx.x & 63;
  const int nw = blockDim.x >> 6;
  if (lane == 0) rbuf[w] = v;
  __syncthreads();
  float tot = 0.f;
  for (int i = 0; i < nw; ++i) tot += rbuf[i];
  __syncthreads();
  return tot;
}

// ---- fc1: l2n -> 1024x512 (no bias) -> LN -> lrelu ----
__global__ __launch_bounds__(256)
void fc1_kernel(const float* __restrict__ gin_g, const float* __restrict__ Wt,
                const float* __restrict__ gam, const float* __restrict__ bet,
                float* __restrict__ outp) {
  __shared__ __align__(16) float gin[1024];
  __shared__ float hbuf[512];
  __shared__ float rbuf[8];
  const int b = blockIdx.x, tid = threadIdx.x;
  for (int e = tid; e < 1024; e += 256) gin[e] = gin_g[b * 1024 + e];
  __syncthreads();
  float ps = 0.f;
  for (int e = tid; e < 1024; e += 256) ps = fmaf(gin[e], gin[e], ps);
  float ss = block_reduce_sum(ps, rbuf);
  float rinv = 1.0f / sqrtf(ss);
  #pragma unroll
  for (int r = 0; r < 2; ++r) {
    int o = tid + r * 256;
    const float* wrow = Wt + (size_t)o * 1024;
    float a = 0.f;
    for (int c4 = 0; c4 < 256; ++c4) {
      float4 wv = *reinterpret_cast<const float4*>(wrow + c4 * 4);
      float4 gv = *reinterpret_cast<const float4*>(&gin[c4 * 4]);
      a = fmaf(wv.x, gv.x, a); a = fmaf(wv.y, gv.y, a);
      a = fmaf(wv.z, gv.z, a); a = fmaf(wv.w, gv.w, a);
    }
    hbuf[o] = a * rinv;
  }
  __syncthreads();
  float pm = hbuf[tid] + hbuf[tid + 256];
  float mean = block_reduce_sum(pm, rbuf) * (1.f / 512.f);
  float d0 = hbuf[tid] - mean, d1 = hbuf[tid + 256] - mean;
  float var = block_reduce_sum(d0 * d0 + d1 * d1, rbuf) * (1.f / 512.f);
  float rs = 1.0f / sqrtf(var + 1e-5f);
  #pragma unroll
  for (int r = 0; r < 2; ++r) {
    int o = tid + r * 256;
    float yv = (hbuf[o] - mean) * rs * gam[o] + bet[o];
    outp[b * 512 + o] = lrelu(yv);
  }
}

// ---- fc2: l2n -> 512x256 (+bias) -> LN -> lrelu ----
__global__ __launch_bounds__(256)
void fc2_kernel(const float* __restrict__ inp, const float* __restrict__ Wt,
                const float* __restrict__ bias, const float* __restrict__ gam,
                const float* __restrict__ bet, float* __restrict__ outp) {
  __shared__ __align__(16) float gin[512];
  __shared__ float rbuf[8];
  const int b = blockIdx.x, tid = threadIdx.x;
  for (int e = tid; e < 512; e += 256) gin[e] = inp[b * 512 + e];
  __syncthreads();
  float ps = 0.f;
  for (int e = tid; e < 512; e += 256) ps = fmaf(gin[e], gin[e], ps);
  float ss = block_reduce_sum(ps, rbuf);
  float rinv = 1.0f / sqrtf(ss);
  const float* wrow = Wt + (size_t)tid * 512;
  float a = 0.f;
  for (int c4 = 0; c4 < 128; ++c4) {
    float4 wv = *reinterpret_cast<const float4*>(wrow + c4 * 4);
    float4 gv = *reinterpret_cast<const float4*>(&gin[c4 * 4]);
    a = fmaf(wv.x, gv.x, a); a = fmaf(wv.y, gv.y, a);
    a = fmaf(wv.z, gv.z, a); a = fmaf(wv.w, gv.w, a);
  }
  a = a * rinv + bias[tid];
  float mean = block_reduce_sum(a, rbuf) * (1.f / 256.f);
  float d = a - mean;
  float var = block_reduce_sum(d * d, rbuf) * (1.f / 256.f);
  float rs = 1.0f / sqrtf(var + 1e-5f);
  float yv = (a - mean) * rs * gam[tid] + bet[tid];
  outp[b * 256 + tid] = lrelu(yv);
}

// ---- fc3 + identity ----
__global__ __launch_bounds__(64)
void fc3_kernel(const float* __restrict__ inp, const float* __restrict__ Wt,
                const float* __restrict__ bias, float* __restrict__ tmat) {
  __shared__ float gin[256];
  const int b = blockIdx.x, tid = threadIdx.x;
  for (int e = tid; e < 256; e += 64) gin[e] = inp[b * 256 + e];
  __syncthreads();
  if (tid < 9) {
    const float* wrow = Wt + tid * 256;
    float a = 0.f;
    for (int c = 0; c < 256; ++c) a = fmaf(wrow[c], gin[c], a);
    a += bias[tid];
    if (tid == 0 || tid == 4 || tid == 8) a += 1.f;
    tmat[b * 9 + tid] = a;
  }
}

// ---- apply 3x3 transform ----
__global__ __launch_bounds__(256)
void xform_kernel(const float* __restrict__ x, const float* __restrict__ tmat,
                  float* __restrict__ xt) {
  const int b = blockIdx.y;
  const int n = blockIdx.x * 256 + threadIdx.x;
  const float* xb = x + (size_t)b * 3 * NPTS;
  const float x0 = xb[n], x1 = xb[NPTS + n], x2 = xb[2 * NPTS + n];
  const float* t = tmat + b * 9;
  float* ob = xt + (size_t)b * 3 * NPTS;
  #pragma unroll
  for (int i = 0; i < 3; ++i)
    ob[i * NPTS + n] = fmaf(t[3 * i], x0, fmaf(t[3 * i + 1], x1, t[3 * i + 2] * x2));
}

extern "C" void kernel_launch(void* const* d_in, const int* in_sizes, int n_in,
                              void* d_out, int out_size, void* d_ws, size_t ws_size,
                              hipStream_t stream) {
  (void)in_sizes; (void)n_in; (void)out_size; (void)ws_size;
  const float* x       = (const float*)d_in[0];
  const float* tw1     = (const float*)d_in[1];
  const float* tw2     = (const float*)d_in[2];
  const float* tw3     = (const float*)d_in[3];
  const float* tfc1_w  = (const float*)d_in[4];
  const float* tfc1_g  = (const float*)d_in[5];
  const float* tfc1_b  = (const float*)d_in[6];
  const float* tfc2_w  = (const float*)d_in[7];
  const float* tfc2_bias = (const float*)d_in[8];
  const float* tfc2_g  = (const float*)d_in[9];
  const float* tfc2_b  = (const float*)d_in[10];
  const float* tfc3_w  = (const float*)d_in[11];
  const float* tfc3_b  = (const float*)d_in[12];
  const float* w1      = (const float*)d_in[13];
  const float* w2      = (const float*)d_in[14];
  const float* w3      = (const float*)d_in[15];
  const float* w4      = (const float*)d_in[16];
  const float* w5      = (const float*)d_in[17];
  float* out = (float*)d_out;

  char* wsb = (char*)d_ws;
  size_t off = 0;
  auto alloc = [&](size_t bytes) -> void* {
    void* p = wsb + off;
    off += (bytes + 255) & ~(size_t)255;
    return p;
  };
  float* ybuf = (float*)alloc((size_t)BATCH * NPTS * 256 * 4);
  float* zbuf = (float*)alloc((size_t)BATCH * NPTS * 256 * 4);
  float* xcT  = (float*)alloc((size_t)BATCH * 512 * NPTS * 4);   // channel-major x1..x4
  float* h2m  = (float*)alloc((size_t)BATCH * 128 * NPTS * 4);   // channel-major
  float* part = (float*)alloc((size_t)BATCH * 16 * 1024 * 4);
  int*   idxb = (int*)alloc((size_t)BATCH * NPTS * KNN * 4);
  float* xxb  = (float*)alloc((size_t)BATCH * NPTS * 4);
  float* xt   = (float*)alloc((size_t)BATCH * 3 * NPTS * 4);
  float* gbuf = (float*)alloc((size_t)BATCH * 1024 * 4);
  float* f1o  = (float*)alloc((size_t)BATCH * 512 * 4);
  float* f2o  = (float*)alloc((size_t)BATCH * 256 * 4);
  float* tmat = (float*)alloc((size_t)BATCH * 9 * 4);
  float* tw1aT = (float*)alloc(3 * 64 * 4);
  float* tw1dT = (float*)alloc(3 * 64 * 4);
  float* w1aT  = (float*)alloc(3 * 64 * 4);
  float* w1dT  = (float*)alloc(3 * 64 * 4);
  float* w2aT  = (float*)alloc(64 * 64 * 4);
  float* w2dT  = (float*)alloc(64 * 64 * 4);
  float* w3aT  = (float*)alloc(64 * 128 * 4);
  float* w3dT  = (float*)alloc(64 * 128 * 4);
  float* w4aT  = (float*)alloc(128 * 256 * 4);
  float* w4dT  = (float*)alloc(128 * 256 * 4);
  float* tw3T  = (float*)alloc(128 * 1024 * 4);
  float* w5T   = (float*)alloc(512 * 1024 * 4);

  // weight prep
  wsplit_t_kernel<<<1, 256, 0, stream>>>(tw1, tw1aT, tw1dT, 64, 3);
  wsplit_t_kernel<<<1, 256, 0, stream>>>(w1, w1aT, w1dT, 64, 3);
  wsplit_t_kernel<<<16, 256, 0, stream>>>(w2, w2aT, w2dT, 64, 64);
  wsplit_t_kernel<<<32, 256, 0, stream>>>(w3, w3aT, w3dT, 128, 64);
  wsplit_t_kernel<<<128, 256, 0, stream>>>(w4, w4aT, w4dT, 256, 128);
  wtrans_kernel<<<512, 256, 0, stream>>>(tw3, tw3T, 1024, 128);
  wtrans_kernel<<<2048, 256, 0, stream>>>(w5, w5T, 1024, 512);

  // ---- transform net ----
  xx3_kernel<<<dim3(4, 16), 256, 0, stream>>>(x, xxb);
  knn_cn_kernel<3><<<dim3(64, 16), 256, 0, stream>>>(x, 3 * NPTS, xxb, idxb);
  gemm_kernel<0><<<dim3(16, 1, 16), 256, 0, stream>>>(x, 3 * NPTS, 1, NPTS, tw1aT, 64, 3,
                                                      ybuf, NPTS * 64, 64, 0);
  gemm_kernel<0><<<dim3(16, 1, 16), 256, 0, stream>>>(x, 3 * NPTS, 1, NPTS, tw1dT, 64, 3,
                                                      zbuf, NPTS * 64, 64, 0);
  h12_kernel<<<dim3(128, 16), 128, 0, stream>>>(ybuf, zbuf, idxb, tw2, h2m);
  gemm_kernel<1><<<dim3(16, 16, 16), 256, 0, stream>>>(h2m, 128 * NPTS, 1, NPTS, tw3T, 1024, 128,
                                                       part, 16 * 1024, 0, 1024);
  reduce_max_kernel<<<dim3(4, 16), 256, 0, stream>>>(part, gbuf);
  fc1_kernel<<<16, 256, 0, stream>>>(gbuf, tfc1_w, tfc1_g, tfc1_b, f1o);
  fc2_kernel<<<16, 256, 0, stream>>>(f1o, tfc2_w, tfc2_bias, tfc2_g, tfc2_b, f2o);
  fc3_kernel<<<16, 64, 0, stream>>>(f2o, tfc3_w, tfc3_b, tmat);
  xform_kernel<<<dim3(4, 16), 256, 0, stream>>>(x, tmat, xt);

  // ---- EdgeConv 1 (C=3 -> O=64) on xt ----
  xx3_kernel<<<dim3(4, 16), 256, 0, stream>>>(xt, xxb);
  knn_cn_kernel<3><<<dim3(64, 16), 256, 0, stream>>>(xt, 3 * NPTS, xxb, idxb);
  gemm_kernel<0><<<dim3(16, 1, 16), 256, 0, stream>>>(xt, 3 * NPTS, 1, NPTS, w1aT, 64, 3,
                                                      ybuf, NPTS * 64, 64, 0);
  gemm_kernel<0><<<dim3(16, 1, 16), 256, 0, stream>>>(xt, 3 * NPTS, 1, NPTS, w1dT, 64, 3,
                                                      zbuf, NPTS * 64, 64, 0);
  edge_max_cn_kernel<64, 64><<<dim3(16, 16), 256, 0, stream>>>(ybuf, zbuf, idxb, xcT, xxb);

  // ---- EdgeConv 2 (C=64 -> O=64), input xcT ch 0..63 ----
  knn_cn_kernel<64><<<dim3(64, 16), 256, 0, stream>>>(xcT, 512 * NPTS, xxb, idxb);
  gemm_kernel<0><<<dim3(16, 1, 16), 256, 0, stream>>>(xcT, 512 * NPTS, 1, NPTS, w2aT, 64, 64,
                                                      ybuf, NPTS * 64, 64, 0);
  gemm_kernel<0><<<dim3(16, 1, 16), 256, 0, stream>>>(xcT, 512 * NPTS, 1, NPTS, w2dT, 64, 64,
                                                      zbuf, NPTS * 64, 64, 0);
  edge_max_cn_kernel<64, 64><<<dim3(16, 16), 256, 0, stream>>>(ybuf, zbuf, idxb,
                                                               xcT + 64 * NPTS, xxb);

  // ---- EdgeConv 3 (C=64 -> O=128), input xcT ch 64..127 ----
  knn_cn_kernel<64><<<dim3(64, 16), 256, 0, stream>>>(xcT + 64 * NPTS, 512 * NPTS, xxb, idxb);
  gemm_kernel<0><<<dim3(16, 2, 16), 256, 0, stream>>>(xcT + 64 * NPTS, 512 * NPTS, 1, NPTS,
                                                      w3aT, 128, 64, ybuf, NPTS * 128, 128, 0);
  gemm_kernel<0><<<dim3(16, 2, 16), 256, 0, stream>>>(xcT + 64 * NPTS, 512 * NPTS, 1, NPTS,
                                                      w3dT, 128, 64, zbuf, NPTS * 128, 128, 0);
  edge_max_cn_kernel<128, 64><<<dim3(16, 16), 256, 0, stream>>>(ybuf, zbuf, idxb,
                                                                xcT + 128 * NPTS, xxb);

  // ---- EdgeConv 4 (C=128 -> O=256), input xcT ch 128..255 ----
  knn_cn_kernel<128><<<dim3(64, 16), 256, 0, stream>>>(xcT + 128 * NPTS, 512 * NPTS, xxb, idxb);
  gemm_kernel<0><<<dim3(16, 4, 16), 256, 0, stream>>>(xcT + 128 * NPTS, 512 * NPTS, 1, NPTS,
                                                      w4aT, 256, 128, ybuf, NPTS * 256, 256, 0);
  gemm_kernel<0><<<dim3(16, 4, 16), 256, 0, stream>>>(xcT + 128 * NPTS, 512 * NPTS, 1, NPTS,
                                                      w4dT, 256, 128, zbuf, NPTS * 256, 256, 0);
  edge_max_cn_kernel<256, 32><<<dim3(32, 16), 256, 0, stream>>>(ybuf, zbuf, idxb,
                                                                xcT + 256 * NPTS, nullptr);

  // ---- final: x5 = lrelu(w5 @ xc) with max over n ----
  gemm_kernel<1><<<dim3(16, 16, 16), 256, 0, stream>>>(xcT, 512 * NPTS, 1, NPTS, w5T, 1024, 512,
                                                       part, 16 * 1024, 0, 1024);
  reduce_max_kernel<<<dim3(4, 16), 256, 0, stream>>>(part, out);
}

// Round 3
// 1443.911 us; speedup vs baseline: 2.8173x; 1.1788x over previous
//
#include <hip/hip_runtime.h>
#include <math.h>

#define BATCH 16
#define NPTS 1024
#define KNN 20

__device__ __forceinline__ float lrelu(float v) { return v >= 0.f ? v : 0.2f * v; }

// ---- weight prep: W[O][2C] -> WaT[C][O] = W[:, :C]^T ; WdT[C][O] = (W[:,C:]-W[:,:C])^T ----
__global__ __launch_bounds__(256)
void wsplit_t_kernel(const float* __restrict__ W, float* __restrict__ waT,
                     float* __restrict__ wdT, int O, int Cc) {
  int e = blockIdx.x * 256 + threadIdx.x;
  if (e < O * Cc) {
    int c = e / O, o = e - c * O;
    float a = W[o * 2 * Cc + c], bb = W[o * 2 * Cc + Cc + c];
    waT[e] = a; wdT[e] = bb - a;
  }
}

// ---- weight transpose: W[O][C] -> wT[C][O] ----
__global__ __launch_bounds__(256)
void wtrans_kernel(const float* __restrict__ W, float* __restrict__ wT, int O, int Cc) {
  int e = blockIdx.x * 256 + threadIdx.x;
  if (e < O * Cc) {
    int c = e / O, o = e - c * O;
    wT[e] = W[(size_t)o * Cc + c];
  }
}

// ---- xx[b][n] = sum_c x[b][c][n]^2 for C=3 CN input ----
__global__ __launch_bounds__(256)
void xx3_kernel(const float* __restrict__ x, float* __restrict__ xx) {
  const int b = blockIdx.y;
  const int n = blockIdx.x * 256 + threadIdx.x;
  const float* xb = x + (size_t)b * 3 * NPTS;
  float a = xb[n], bb = xb[NPTS + n], c = xb[2 * NPTS + n];
  xx[b * NPTS + n] = a * a + bb * bb + c * c;
}

// ---- knn on channel-major features: Xt[b][c][n], batch stride sb ----
template<int C>
__global__ __launch_bounds__(256)
void knn_cn_kernel(const float* __restrict__ Xt, long sb,
                   const float* __restrict__ xx, int* __restrict__ idxout) {
  __shared__ float sc[16][NPTS];   // 64 KB
  const int b = blockIdx.y, i0 = blockIdx.x * 16;
  const int tid = threadIdx.x;
  const float* Xb = Xt + (size_t)b * sb;
  const int j0 = tid * 4;
  float acc[16][4];
  #pragma unroll
  for (int q = 0; q < 16; ++q)
    #pragma unroll
    for (int u = 0; u < 4; ++u) acc[q][u] = 0.f;
  for (int c = 0; c < C; ++c) {
    const float4 xv = *reinterpret_cast<const float4*>(Xb + (size_t)c * NPTS + j0);
    const float* xr = Xb + (size_t)c * NPTS + i0;   // uniform addresses -> scalar loads
    #pragma unroll
    for (int q = 0; q < 16; ++q) {
      const float xiq = xr[q];
      acc[q][0] = fmaf(xiq, xv.x, acc[q][0]);
      acc[q][1] = fmaf(xiq, xv.y, acc[q][1]);
      acc[q][2] = fmaf(xiq, xv.z, acc[q][2]);
      acc[q][3] = fmaf(xiq, xv.w, acc[q][3]);
    }
  }
  const float4 xxj = *reinterpret_cast<const float4*>(xx + b * NPTS + j0);
  #pragma unroll
  for (int q = 0; q < 16; ++q) {
    float4 st;
    st.x = fmaf(-2.f, acc[q][0], xxj.x);
    st.y = fmaf(-2.f, acc[q][1], xxj.y);
    st.z = fmaf(-2.f, acc[q][2], xxj.z);
    st.w = fmaf(-2.f, acc[q][3], xxj.w);
    *reinterpret_cast<float4*>(&sc[q][j0]) = st;
  }
  __syncthreads();
  const int wv = tid >> 6, lane = tid & 63;
  for (int qq = 0; qq < 4; ++qq) {
    const int q = wv * 4 + qq;
    float v[16];
    #pragma unroll
    for (int s = 0; s < 16; ++s) v[s] = sc[q][lane + 64 * s];
    unsigned dead = 0u;
    float bestv; int bestj;
    auto rescan = [&]() {
      bestv = 3.4e38f; bestj = 1 << 30;
      #pragma unroll
      for (int s = 0; s < 16; ++s) {
        const bool ok = ((dead >> s) & 1u) == 0u;
        const float val = v[s];
        if (ok && val < bestv) { bestv = val; bestj = lane + 64 * s; }
      }
    };
    rescan();
    int myidx = 0;
    for (int t = 0; t < KNN; ++t) {
      float rv = bestv; int rj = bestj;
      #pragma unroll
      for (int off = 32; off > 0; off >>= 1) {
        const float ov = __shfl_xor(rv, off);
        const int oj = __shfl_xor(rj, off);
        if (ov < rv || (ov == rv && oj < rj)) { rv = ov; rj = oj; }
      }
      if (lane == t) myidx = rj;
      if (bestj == rj) { dead |= 1u << ((bestj - lane) >> 6); rescan(); }
    }
    if (lane < KNN) idxout[(size_t)(b * NPTS + i0 + q) * KNN + lane] = myidx;
  }
}

// ---- 64-tile GEMM: out[b,n,o] = sum_c X[b,n,c]*W[o,c], W passed TRANSPOSED WT[c][o] ----
__global__ __launch_bounds__(256)
void gemm_kernel(const float* __restrict__ X, long sxb, int sxn, int sxc,
                 const float* __restrict__ WT, int ldW, int C,
                 float* __restrict__ out, int sob, int son) {
  __shared__ __align__(16) float Xs[16][64];
  __shared__ __align__(16) float Ws[16][64];
  const int b = blockIdx.z;
  const int n0 = blockIdx.x * 64, o0 = blockIdx.y * 64;
  const int tid = threadIdx.x;
  const int lr = tid & 63;
  const int c4 = (tid >> 6) * 4;
  const int tn = tid & 15, to = tid >> 4;
  float acc[4][4];
  #pragma unroll
  for (int i = 0; i < 4; ++i)
    #pragma unroll
    for (int j = 0; j < 4; ++j) acc[i][j] = 0.f;

  const size_t xbase = (size_t)b * sxb;
  for (int k0 = 0; k0 < C; k0 += 16) {
    #pragma unroll
    for (int u = 0; u < 4; ++u) {
      int c = k0 + c4 + u;
      float xv = 0.f, wv = 0.f;
      if (c < C) {
        xv = X[xbase + (size_t)(n0 + lr) * sxn + (size_t)c * sxc];
        wv = WT[(size_t)c * ldW + o0 + lr];
      }
      Xs[c4 + u][lr] = xv;
      Ws[c4 + u][lr] = wv;
    }
    __syncthreads();
    #pragma unroll
    for (int kk = 0; kk < 16; ++kk) {
      const float4 xa = *reinterpret_cast<const float4*>(&Xs[kk][tn * 4]);
      const float4 wb = *reinterpret_cast<const float4*>(&Ws[kk][to * 4]);
      const float xr[4] = {xa.x, xa.y, xa.z, xa.w};
      const float wr[4] = {wb.x, wb.y, wb.z, wb.w};
      #pragma unroll
      for (int i = 0; i < 4; ++i)
        #pragma unroll
        for (int j = 0; j < 4; ++j) acc[i][j] = fmaf(xr[i], wr[j], acc[i][j]);
    }
    __syncthreads();
  }
  #pragma unroll
  for (int i = 0; i < 4; ++i) {
    float4 st = make_float4(acc[i][0], acc[i][1], acc[i][2], acc[i][3]);
    *reinterpret_cast<float4*>(&out[(size_t)b * sob + (size_t)(n0 + tn * 4 + i) * son + o0 + to * 4]) = st;
  }
}

// ---- 128x128-tile GEMM; X channel-major X[b][c][n] (stride scN along c) ----
// EPI=0: NC store out[b*sob + n*son + o]; EPI=1: lrelu+max over tile n -> out[b*sob + bx*snb + o0+o]
template<int EPI>
__global__ __launch_bounds__(256)
void gemm128_kernel(const float* __restrict__ X, long sxb, int scN,
                    const float* __restrict__ WT, int ldW, int C,
                    float* __restrict__ out, int sob, int son, int snb) {
  __shared__ __align__(16) float Xs[16][128];
  __shared__ __align__(16) float Ws[16][128];
  __shared__ __align__(16) float red[16][128];
  const int b = blockIdx.z;
  const int n0 = blockIdx.x * 128, o0 = blockIdx.y * 128;
  const int tid = threadIdx.x;
  const int tn = tid & 15, to = tid >> 4;
  float acc[8][8];
  #pragma unroll
  for (int i = 0; i < 8; ++i)
    #pragma unroll
    for (int j = 0; j < 8; ++j) acc[i][j] = 0.f;

  const size_t xbase = (size_t)b * sxb;
  for (int c0 = 0; c0 < C; c0 += 16) {
    #pragma unroll
    for (int it = 0; it < 2; ++it) {
      const int task = tid + it * 256;
      const int kk = task >> 5, n4 = (task & 31) * 4;
      *reinterpret_cast<float4*>(&Xs[kk][n4]) =
        *reinterpret_cast<const float4*>(&X[xbase + (size_t)(c0 + kk) * scN + n0 + n4]);
      *reinterpret_cast<float4*>(&Ws[kk][n4]) =
        *reinterpret_cast<const float4*>(&WT[(size_t)(c0 + kk) * ldW + o0 + n4]);
    }
    __syncthreads();
    #pragma unroll
    for (int kk = 0; kk < 16; ++kk) {
      const float4 xa0 = *reinterpret_cast<const float4*>(&Xs[kk][tn * 4]);
      const float4 xa1 = *reinterpret_cast<const float4*>(&Xs[kk][64 + tn * 4]);
      const float4 wb0 = *reinterpret_cast<const float4*>(&Ws[kk][to * 4]);
      const float4 wb1 = *reinterpret_cast<const float4*>(&Ws[kk][64 + to * 4]);
      const float xr[8] = {xa0.x, xa0.y, xa0.z, xa0.w, xa1.x, xa1.y, xa1.z, xa1.w};
      const float wr[8] = {wb0.x, wb0.y, wb0.z, wb0.w, wb1.x, wb1.y, wb1.z, wb1.w};
      #pragma unroll
      for (int i = 0; i < 8; ++i)
        #pragma unroll
        for (int j = 0; j < 8; ++j) acc[i][j] = fmaf(xr[i], wr[j], acc[i][j]);
    }
    __syncthreads();
  }

  if (EPI == 0) {
    #pragma unroll
    for (int i = 0; i < 8; ++i) {
      const int n = n0 + (i >> 2) * 64 + tn * 4 + (i & 3);
      float4 s0 = make_float4(acc[i][0], acc[i][1], acc[i][2], acc[i][3]);
      float4 s1 = make_float4(acc[i][4], acc[i][5], acc[i][6], acc[i][7]);
      *reinterpret_cast<float4*>(&out[(size_t)b * sob + (size_t)n * son + o0 + to * 4]) = s0;
      *reinterpret_cast<float4*>(&out[(size_t)b * sob + (size_t)n * son + o0 + 64 + to * 4]) = s1;
    }
  } else {
    #pragma unroll
    for (int j = 0; j < 8; ++j) {
      float m = lrelu(acc[0][j]);
      #pragma unroll
      for (int i = 1; i < 8; ++i) m = fmaxf(m, lrelu(acc[i][j]));
      red[tn][(j >> 2) * 64 + to * 4 + (j & 3)] = m;
    }
    __syncthreads();
    if (tid < 128) {
      float m = red[0][tid];
      #pragma unroll
      for (int t = 1; t < 16; ++t) m = fmaxf(m, red[t][tid]);
      out[(size_t)b * sob + (size_t)blockIdx.x * snb + o0 + tid] = m;
    }
  }
}

// ---- edge max, channel-major output via LDS transpose tile ----
template<int O, int TI>
__global__ __launch_bounds__(256)
void edge_max_cn_kernel(const float* __restrict__ y, const float* __restrict__ z,
                        const int* __restrict__ idx, float* __restrict__ outCN,
                        float* __restrict__ xx) {
  __shared__ float tile[TI][O + 1];
  const int b = blockIdx.y;
  const int i0 = blockIdx.x * TI;
  const int wv = threadIdx.x >> 6, lane = threadIdx.x & 63;
  constexpr int OSEG = O / 64;
  constexpr int ROUNDS = TI * OSEG / 4;
  for (int r = 0; r < ROUNDS; ++r) {
    const int item = r * 4 + wv;
    const int il = item / OSEG, os = item - il * OSEG;
    const int i = i0 + il, o = os * 64 + lane;
    const int* ip = idx + (size_t)(b * NPTS + i) * KNN;
    const float zv = z[(size_t)(b * NPTS + i) * O + o];
    float m = -3.4e38f;
    #pragma unroll
    for (int t = 0; t < KNN; ++t) {
      int j = ip[t];
      float v = y[(size_t)(b * NPTS + j) * O + o] + zv;
      m = fmaxf(m, lrelu(v));
    }
    tile[il][o] = m;
  }
  __syncthreads();
  if (xx != nullptr && threadIdx.x < TI) {
    const int il = threadIdx.x;
    float s = 0.f;
    #pragma unroll
    for (int o = 0; o < O; ++o) { float v = tile[il][o]; s = fmaf(v, v, s); }
    xx[b * NPTS + i0 + il] = s;
  }
  for (int e = threadIdx.x; e < TI * O; e += 256) {
    const int o = e / TI, il = e - o * TI;
    outCN[(size_t)b * 512 * NPTS + (size_t)o * NPTS + i0 + il] = tile[il][o];
  }
}

// ---- h12 as edge-GEMM: 4 points/block, 80 edges x 64k x 128out, max over k in-wave ----
__global__ __launch_bounds__(256)
void h12_gemm_kernel(const float* __restrict__ ya, const float* __restrict__ zb,
                     const int* __restrict__ idx, const float* __restrict__ tw2T,
                     float* __restrict__ h2m) {
  __shared__ __align__(16) float h1s[80][68];   // 21.76 KB, pad 68 -> conflict-free col reads
  __shared__ __align__(16) float ws[64][128];   // 32 KB, k-major weights
  __shared__ __align__(16) float zbs[4][64];
  __shared__ float ot[128][4];
  __shared__ int idxs[4][KNN];
  const int b = blockIdx.y;
  const int i0 = blockIdx.x * 4;
  const int tid = threadIdx.x;

  // stage weights (k-major), z rows, idx
  #pragma unroll
  for (int it = 0; it < 8; ++it) {
    const int f = tid + it * 256;              // 2048 float4 = 64*128 floats
    *reinterpret_cast<float4*>(&ws[0][0] + f * 4) =
      *reinterpret_cast<const float4*>(tw2T + (size_t)f * 4);
  }
  if (tid < 64) {
    const int p = tid >> 4, cq = (tid & 15) * 4;
    *reinterpret_cast<float4*>(&zbs[p][cq]) =
      *reinterpret_cast<const float4*>(&zb[(size_t)(b * NPTS + i0 + p) * 64 + cq]);
  }
  if (tid >= 64 && tid < 64 + 4 * KNN) {
    const int e = tid - 64;
    idxs[e / KNN][e % KNN] = idx[(size_t)(b * NPTS + i0) * KNN + e];
  }
  __syncthreads();

  // gather h1: 80 edges x 64 ch
  #pragma unroll
  for (int it = 0; it < 5; ++it) {
    const int task = tid + it * 256;           // 1280 float4 tasks
    const int e = task >> 4, cq = (task & 15) * 4;
    const int p = e / KNN, t = e - p * KNN;
    const int j = idxs[p][t];
    const float4 yv = *reinterpret_cast<const float4*>(&ya[(size_t)(b * NPTS + j) * 64 + cq]);
    const float4 zv = *reinterpret_cast<const float4*>(&zbs[p][cq]);
    float4 hv;
    hv.x = lrelu(yv.x + zv.x); hv.y = lrelu(yv.y + zv.y);
    hv.z = lrelu(yv.z + zv.z); hv.w = lrelu(yv.w + zv.w);
    *reinterpret_cast<float4*>(&h1s[e][cq]) = hv;
  }
  __syncthreads();

  // GEMM: 80 edges x 128 out, k=64; thread = (eg 0..15, og 0..15), acc[5 edges][8 outs]
  const int eg = tid >> 4, og = tid & 15;
  float acc[5][8];
  #pragma unroll
  for (int u = 0; u < 5; ++u)
    #pragma unroll
    for (int v = 0; v < 8; ++v) acc[u][v] = 0.f;
  #pragma unroll 4
  for (int kk = 0; kk < 64; ++kk) {
    float hv[5];
    #pragma unroll
    for (int u = 0; u < 5; ++u) hv[u] = h1s[eg * 5 + u][kk];
    const float4 w0 = *reinterpret_cast<const float4*>(&ws[kk][og * 4]);
    const float4 w1 = *reinterpret_cast<const float4*>(&ws[kk][64 + og * 4]);
    const float wr[8] = {w0.x, w0.y, w0.z, w0.w, w1.x, w1.y, w1.z, w1.w};
    #pragma unroll
    for (int u = 0; u < 5; ++u)
      #pragma unroll
      for (int v = 0; v < 8; ++v) acc[u][v] = fmaf(hv[u], wr[v], acc[u][v]);
  }

  // max over the thread's 5 edges (same point), then over the wave's 4 edge-groups
  const int p = eg >> 2, d = eg & 3;
  float m[8];
  #pragma unroll
  for (int v = 0; v < 8; ++v) {
    float mm = lrelu(acc[0][v]);
    #pragma unroll
    for (int u = 1; u < 5; ++u) mm = fmaxf(mm, lrelu(acc[u][v]));
    mm = fmaxf(mm, __shfl_xor(mm, 16));
    mm = fmaxf(mm, __shfl_xor(mm, 32));
    m[v] = mm;
  }
  if (d == 0) {
    #pragma unroll
    for (int v = 0; v < 8; ++v) {
      const int o = og * 4 + (v & 3) + (v >> 2) * 64;
      ot[o][p] = m[v];
    }
  }
  __syncthreads();
  if (tid < 128) {
    float4 st = make_float4(ot[tid][0], ot[tid][1], ot[tid][2], ot[tid][3]);
    *reinterpret_cast<float4*>(&h2m[(size_t)(b * 128 + tid) * NPTS + i0]) = st;
  }
}

// ---- reduce partial max over nt n-tiles ----
__global__ __launch_bounds__(256)
void reduce_max_kernel(const float* __restrict__ part, float* __restrict__ outp, int nt) {
  const int b = blockIdx.y;
  const int o = blockIdx.x * 256 + threadIdx.x;
  float m = part[(size_t)(b * nt) * 1024 + o];
  for (int t = 1; t < nt; ++t) m = fmaxf(m, part[(size_t)(b * nt + t) * 1024 + o]);
  outp[b * 1024 + o] = m;
}

// ---- block reduce helper ----
__device__ __forceinline__ float block_reduce_sum(float v, float* rbuf) {
  #pragma unroll
  for (int off = 32; off > 0; off >>= 1) v += __shfl_xor(v, off);
  const int w = threadIdx.x >> 6, lane = threadIdx.x & 63;
  const int nw = blockDim.x >> 6;
  if (lane == 0) rbuf[w] = v;
  __syncthreads();
  float tot = 0.f;
  for (int i = 0; i < nw; ++i) tot += rbuf[i];
  __syncthreads();
  return tot;
}

// ---- fc1: l2n -> 1024x512 (no bias) -> LN -> lrelu ----
__global__ __launch_bounds__(256)
void fc1_kernel(const float* __restrict__ gin_g, const float* __restrict__ Wt,
                const float* __restrict__ gam, const float* __restrict__ bet,
                float* __restrict__ outp) {
  __shared__ __align__(16) float gin[1024];
  __shared__ float hbuf[512];
  __shared__ float rbuf[8];
  const int b = blockIdx.x, tid = threadIdx.x;
  for (int e = tid; e < 1024; e += 256) gin[e] = gin_g[b * 1024 + e];
  __syncthreads();
  float ps = 0.f;
  for (int e = tid; e < 1024; e += 256) ps = fmaf(gin[e], gin[e], ps);
  float ss = block_reduce_sum(ps, rbuf);
  float rinv = 1.0f / sqrtf(ss);
  #pragma unroll
  for (int r = 0; r < 2; ++r) {
    int o = tid + r * 256;
    const float* wrow = Wt + (size_t)o * 1024;
    float a = 0.f;
    for (int c4 = 0; c4 < 256; ++c4) {
      float4 wv = *reinterpret_cast<const float4*>(wrow + c4 * 4);
      float4 gv = *reinterpret_cast<const float4*>(&gin[c4 * 4]);
      a = fmaf(wv.x, gv.x, a); a = fmaf(wv.y, gv.y, a);
      a = fmaf(wv.z, gv.z, a); a = fmaf(wv.w, gv.w, a);
    }
    hbuf[o] = a * rinv;
  }
  __syncthreads();
  float pm = hbuf[tid] + hbuf[tid + 256];
  float mean = block_reduce_sum(pm, rbuf) * (1.f / 512.f);
  float d0 = hbuf[tid] - mean, d1 = hbuf[tid + 256] - mean;
  float var = block_reduce_sum(d0 * d0 + d1 * d1, rbuf) * (1.f / 512.f);
  float rs = 1.0f / sqrtf(var + 1e-5f);
  #pragma unroll
  for (int r = 0; r < 2; ++r) {
    int o = tid + r * 256;
    float yv = (hbuf[o] - mean) * rs * gam[o] + bet[o];
    outp[b * 512 + o] = lrelu(yv);
  }
}

// ---- fc2: l2n -> 512x256 (+bias) -> LN -> lrelu ----
__global__ __launch_bounds__(256)
void fc2_kernel(const float* __restrict__ inp, const float* __restrict__ Wt,
                const float* __restrict__ bias, const float* __restrict__ gam,
                const float* __restrict__ bet, float* __restrict__ outp) {
  __shared__ __align__(16) float gin[512];
  __shared__ float rbuf[8];
  const int b = blockIdx.x, tid = threadIdx.x;
  for (int e = tid; e < 512; e += 256) gin[e] = inp[b * 512 + e];
  __syncthreads();
  float ps = 0.f;
  for (int e = tid; e < 512; e += 256) ps = fmaf(gin[e], gin[e], ps);
  float ss = block_reduce_sum(ps, rbuf);
  float rinv = 1.0f / sqrtf(ss);
  const float* wrow = Wt + (size_t)tid * 512;
  float a = 0.f;
  for (int c4 = 0; c4 < 128; ++c4) {
    float4 wv = *reinterpret_cast<const float4*>(wrow + c4 * 4);
    float4 gv = *reinterpret_cast<const float4*>(&gin[c4 * 4]);
    a = fmaf(wv.x, gv.x, a); a = fmaf(wv.y, gv.y, a);
    a = fmaf(wv.z, gv.z, a); a = fmaf(wv.w, gv.w, a);
  }
  a = a * rinv + bias[tid];
  float mean = block_reduce_sum(a, rbuf) * (1.f / 256.f);
  float d = a - mean;
  float var = block_reduce_sum(d * d, rbuf) * (1.f / 256.f);
  float rs = 1.0f / sqrtf(var + 1e-5f);
  float yv = (a - mean) * rs * gam[tid] + bet[tid];
  outp[b * 256 + tid] = lrelu(yv);
}

// ---- fc3 + identity ----
__global__ __launch_bounds__(64)
void fc3_kernel(const float* __restrict__ inp, const float* __restrict__ Wt,
                const float* __restrict__ bias, float* __restrict__ tmat) {
  __shared__ float gin[256];
  const int b = blockIdx.x, tid = threadIdx.x;
  for (int e = tid; e < 256; e += 64) gin[e] = inp[b * 256 + e];
  __syncthreads();
  if (tid < 9) {
    const float* wrow = Wt + tid * 256;
    float a = 0.f;
    for (int c = 0; c < 256; ++c) a = fmaf(wrow[c], gin[c], a);
    a += bias[tid];
    if (tid == 0 || tid == 4 || tid == 8) a += 1.f;
    tmat[b * 9 + tid] = a;
  }
}

// ---- apply 3x3 transform ----
__global__ __launch_bounds__(256)
void xform_kernel(const float* __restrict__ x, const float* __restrict__ tmat,
                  float* __restrict__ xt) {
  const int b = blockIdx.y;
  const int n = blockIdx.x * 256 + threadIdx.x;
  const float* xb = x + (size_t)b * 3 * NPTS;
  const float x0 = xb[n], x1 = xb[NPTS + n], x2 = xb[2 * NPTS + n];
  const float* t = tmat + b * 9;
  float* ob = xt + (size_t)b * 3 * NPTS;
  #pragma unroll
  for (int i = 0; i < 3; ++i)
    ob[i * NPTS + n] = fmaf(t[3 * i], x0, fmaf(t[3 * i + 1], x1, t[3 * i + 2] * x2));
}

extern "C" void kernel_launch(void* const* d_in, const int* in_sizes, int n_in,
                              void* d_out, int out_size, void* d_ws, size_t ws_size,
                              hipStream_t stream) {
  (void)in_sizes; (void)n_in; (void)out_size; (void)ws_size;
  const float* x       = (const float*)d_in[0];
  const float* tw1     = (const float*)d_in[1];
  const float* tw2     = (const float*)d_in[2];
  const float* tw3     = (const float*)d_in[3];
  const float* tfc1_w  = (const float*)d_in[4];
  const float* tfc1_g  = (const float*)d_in[5];
  const float* tfc1_b  = (const float*)d_in[6];
  const float* tfc2_w  = (const float*)d_in[7];
  const float* tfc2_bias = (const float*)d_in[8];
  const float* tfc2_g  = (const float*)d_in[9];
  const float* tfc2_b  = (const float*)d_in[10];
  const float* tfc3_w  = (const float*)d_in[11];
  const float* tfc3_b  = (const float*)d_in[12];
  const float* w1      = (const float*)d_in[13];
  const float* w2      = (const float*)d_in[14];
  const float* w3      = (const float*)d_in[15];
  const float* w4      = (const float*)d_in[16];
  const float* w5      = (const float*)d_in[17];
  float* out = (float*)d_out;

  char* wsb = (char*)d_ws;
  size_t off = 0;
  auto alloc = [&](size_t bytes) -> void* {
    void* p = wsb + off;
    off += (bytes + 255) & ~(size_t)255;
    return p;
  };
  float* ybuf = (float*)alloc((size_t)BATCH * NPTS * 256 * 4);
  float* zbuf = (float*)alloc((size_t)BATCH * NPTS * 256 * 4);
  float* xcT  = (float*)alloc((size_t)BATCH * 512 * NPTS * 4);   // channel-major x1..x4
  float* h2m  = (float*)alloc((size_t)BATCH * 128 * NPTS * 4);   // channel-major
  float* part = (float*)alloc((size_t)BATCH * 16 * 1024 * 4);
  int*   idxb = (int*)alloc((size_t)BATCH * NPTS * KNN * 4);
  float* xxb  = (float*)alloc((size_t)BATCH * NPTS * 4);
  float* xt   = (float*)alloc((size_t)BATCH * 3 * NPTS * 4);
  float* gbuf = (float*)alloc((size_t)BATCH * 1024 * 4);
  float* f1o  = (float*)alloc((size_t)BATCH * 512 * 4);
  float* f2o  = (float*)alloc((size_t)BATCH * 256 * 4);
  float* tmat = (float*)alloc((size_t)BATCH * 9 * 4);
  float* tw1aT = (float*)alloc(3 * 64 * 4);
  float* tw1dT = (float*)alloc(3 * 64 * 4);
  float* w1aT  = (float*)alloc(3 * 64 * 4);
  float* w1dT  = (float*)alloc(3 * 64 * 4);
  float* w2aT  = (float*)alloc(64 * 64 * 4);
  float* w2dT  = (float*)alloc(64 * 64 * 4);
  float* w3aT  = (float*)alloc(64 * 128 * 4);
  float* w3dT  = (float*)alloc(64 * 128 * 4);
  float* w4aT  = (float*)alloc(128 * 256 * 4);
  float* w4dT  = (float*)alloc(128 * 256 * 4);
  float* tw2T  = (float*)alloc(64 * 128 * 4);
  float* tw3T  = (float*)alloc(128 * 1024 * 4);
  float* w5T   = (float*)alloc(512 * 1024 * 4);

  // weight prep
  wsplit_t_kernel<<<1, 256, 0, stream>>>(tw1, tw1aT, tw1dT, 64, 3);
  wsplit_t_kernel<<<1, 256, 0, stream>>>(w1, w1aT, w1dT, 64, 3);
  wsplit_t_kernel<<<16, 256, 0, stream>>>(w2, w2aT, w2dT, 64, 64);
  wsplit_t_kernel<<<32, 256, 0, stream>>>(w3, w3aT, w3dT, 128, 64);
  wsplit_t_kernel<<<128, 256, 0, stream>>>(w4, w4aT, w4dT, 256, 128);
  wtrans_kernel<<<32, 256, 0, stream>>>(tw2, tw2T, 128, 64);
  wtrans_kernel<<<512, 256, 0, stream>>>(tw3, tw3T, 1024, 128);
  wtrans_kernel<<<2048, 256, 0, stream>>>(w5, w5T, 1024, 512);

  // ---- transform net ----
  xx3_kernel<<<dim3(4, 16), 256, 0, stream>>>(x, xxb);
  knn_cn_kernel<3><<<dim3(64, 16), 256, 0, stream>>>(x, 3 * NPTS, xxb, idxb);
  gemm_kernel<<<dim3(16, 1, 16), 256, 0, stream>>>(x, 3 * NPTS, 1, NPTS, tw1aT, 64, 3,
                                                   ybuf, NPTS * 64, 64);
  gemm_kernel<<<dim3(16, 1, 16), 256, 0, stream>>>(x, 3 * NPTS, 1, NPTS, tw1dT, 64, 3,
                                                   zbuf, NPTS * 64, 64);
  h12_gemm_kernel<<<dim3(256, 16), 256, 0, stream>>>(ybuf, zbuf, idxb, tw2T, h2m);
  gemm128_kernel<1><<<dim3(8, 8, 16), 256, 0, stream>>>(h2m, 128 * NPTS, NPTS, tw3T, 1024, 128,
                                                        part, 8 * 1024, 0, 1024);
  reduce_max_kernel<<<dim3(4, 16), 256, 0, stream>>>(part, gbuf, 8);
  fc1_kernel<<<16, 256, 0, stream>>>(gbuf, tfc1_w, tfc1_g, tfc1_b, f1o);
  fc2_kernel<<<16, 256, 0, stream>>>(f1o, tfc2_w, tfc2_bias, tfc2_g, tfc2_b, f2o);
  fc3_kernel<<<16, 64, 0, stream>>>(f2o, tfc3_w, tfc3_b, tmat);
  xform_kernel<<<dim3(4, 16), 256, 0, stream>>>(x, tmat, xt);

  // ---- EdgeConv 1 (C=3 -> O=64) on xt ----
  xx3_kernel<<<dim3(4, 16), 256, 0, stream>>>(xt, xxb);
  knn_cn_kernel<3><<<dim3(64, 16), 256, 0, stream>>>(xt, 3 * NPTS, xxb, idxb);
  gemm_kernel<<<dim3(16, 1, 16), 256, 0, stream>>>(xt, 3 * NPTS, 1, NPTS, w1aT, 64, 3,
                                                   ybuf, NPTS * 64, 64);
  gemm_kernel<<<dim3(16, 1, 16), 256, 0, stream>>>(xt, 3 * NPTS, 1, NPTS, w1dT, 64, 3,
                                                   zbuf, NPTS * 64, 64);
  edge_max_cn_kernel<64, 64><<<dim3(16, 16), 256, 0, stream>>>(ybuf, zbuf, idxb, xcT, xxb);

  // ---- EdgeConv 2 (C=64 -> O=64), input xcT ch 0..63 ----
  knn_cn_kernel<64><<<dim3(64, 16), 256, 0, stream>>>(xcT, 512 * NPTS, xxb, idxb);
  gemm_kernel<<<dim3(16, 1, 16), 256, 0, stream>>>(xcT, 512 * NPTS, 1, NPTS, w2aT, 64, 64,
                                                   ybuf, NPTS * 64, 64);
  gemm_kernel<<<dim3(16, 1, 16), 256, 0, stream>>>(xcT, 512 * NPTS, 1, NPTS, w2dT, 64, 64,
                                                   zbuf, NPTS * 64, 64);
  edge_max_cn_kernel<64, 64><<<dim3(16, 16), 256, 0, stream>>>(ybuf, zbuf, idxb,
                                                               xcT + 64 * NPTS, xxb);

  // ---- EdgeConv 3 (C=64 -> O=128), input xcT ch 64..127 ----
  knn_cn_kernel<64><<<dim3(64, 16), 256, 0, stream>>>(xcT + 64 * NPTS, 512 * NPTS, xxb, idxb);
  gemm_kernel<<<dim3(16, 2, 16), 256, 0, stream>>>(xcT + 64 * NPTS, 512 * NPTS, 1, NPTS,
                                                   w3aT, 128, 64, ybuf, NPTS * 128, 128);
  gemm_kernel<<<dim3(16, 2, 16), 256, 0, stream>>>(xcT + 64 * NPTS, 512 * NPTS, 1, NPTS,
                                                   w3dT, 128, 64, zbuf, NPTS * 128, 128);
  edge_max_cn_kernel<128, 64><<<dim3(16, 16), 256, 0, stream>>>(ybuf, zbuf, idxb,
                                                                xcT + 128 * NPTS, xxb);

  // ---- EdgeConv 4 (C=128 -> O=256), input xcT ch 128..255 ----
  knn_cn_kernel<128><<<dim3(64, 16), 256, 0, stream>>>(xcT + 128 * NPTS, 512 * NPTS, xxb, idxb);
  gemm128_kernel<0><<<dim3(8, 2, 16), 256, 0, stream>>>(xcT + 128 * NPTS, 512 * NPTS, NPTS,
                                                        w4aT, 256, 128, ybuf, NPTS * 256, 256, 0);
  gemm128_kernel<0><<<dim3(8, 2, 16), 256, 0, stream>>>(xcT + 128 * NPTS, 512 * NPTS, NPTS,
                                                        w4dT, 256, 128, zbuf, NPTS * 256, 256, 0);
  edge_max_cn_kernel<256, 32><<<dim3(32, 16), 256, 0, stream>>>(ybuf, zbuf, idxb,
                                                                xcT + 256 * NPTS, nullptr);

  // ---- final: x5 = lrelu(w5 @ xc) with max over n ----
  gemm128_kernel<1><<<dim3(8, 8, 16), 256, 0, stream>>>(xcT, 512 * NPTS, NPTS, w5T, 1024, 512,
                                                        part, 8 * 1024, 0, 1024);
  reduce_max_kernel<<<dim3(4, 16), 256, 0, stream>>>(part, out, 8);
}

// Round 5
// 1068.824 us; speedup vs baseline: 3.8060x; 1.3509x over previous
//
#include <hip/hip_runtime.h>
#include <math.h>

#define BATCH 16
#define NPTS 1024
#define KNN 20

__device__ __forceinline__ float lrelu(float v) { return v >= 0.f ? v : 0.2f * v; }

// ---- weight prep: W[O][2C] -> WaT[C][O] = W[:, :C]^T ; WdT[C][O] = (W[:,C:]-W[:,:C])^T ----
__global__ __launch_bounds__(256)
void wsplit_t_kernel(const float* __restrict__ W, float* __restrict__ waT,
                     float* __restrict__ wdT, int O, int Cc) {
  int e = blockIdx.x * 256 + threadIdx.x;
  if (e < O * Cc) {
    int c = e / O, o = e - c * O;
    float a = W[o * 2 * Cc + c], bb = W[o * 2 * Cc + Cc + c];
    waT[e] = a; wdT[e] = bb - a;
  }
}

// ---- weight transpose: W[O][C] -> wT[C][O] ----
__global__ __launch_bounds__(256)
void wtrans_kernel(const float* __restrict__ W, float* __restrict__ wT, int O, int Cc) {
  int e = blockIdx.x * 256 + threadIdx.x;
  if (e < O * Cc) {
    int c = e / O, o = e - c * O;
    wT[e] = W[(size_t)o * Cc + c];
  }
}

// ---- xx[b][n] = sum_c x[b][c][n]^2 for C=3 CN input ----
__global__ __launch_bounds__(256)
void xx3_kernel(const float* __restrict__ x, float* __restrict__ xx) {
  const int b = blockIdx.y;
  const int n = blockIdx.x * 256 + threadIdx.x;
  const float* xb = x + (size_t)b * 3 * NPTS;
  float a = xb[n], bb = xb[NPTS + n], c = xb[2 * NPTS + n];
  xx[b * NPTS + n] = a * a + bb * bb + c * c;
}

// ---- knn on channel-major features: Xt[b][c][n], batch stride sb ----
// 8 queries/block (32 KB LDS -> 5 blocks/CU); wave owns 2 queries, extracts interleaved.
template<int C>
__global__ __launch_bounds__(256)
void knn_cn_kernel(const float* __restrict__ Xt, long sb,
                   const float* __restrict__ xx, int* __restrict__ idxout) {
  __shared__ float sc[8][NPTS];   // 32 KB
  const int b = blockIdx.y, i0 = blockIdx.x * 8;
  const int tid = threadIdx.x;
  const float* Xb = Xt + (size_t)b * sb;
  const int j0 = tid * 4;
  float acc[8][4];
  #pragma unroll
  for (int q = 0; q < 8; ++q)
    #pragma unroll
    for (int u = 0; u < 4; ++u) acc[q][u] = 0.f;
  for (int c = 0; c < C; ++c) {
    const float4 xv = *reinterpret_cast<const float4*>(Xb + (size_t)c * NPTS + j0);
    const float* xr = Xb + (size_t)c * NPTS + i0;   // uniform addresses -> scalar loads
    #pragma unroll
    for (int q = 0; q < 8; ++q) {
      const float xiq = xr[q];
      acc[q][0] = fmaf(xiq, xv.x, acc[q][0]);
      acc[q][1] = fmaf(xiq, xv.y, acc[q][1]);
      acc[q][2] = fmaf(xiq, xv.z, acc[q][2]);
      acc[q][3] = fmaf(xiq, xv.w, acc[q][3]);
    }
  }
  const float4 xxj = *reinterpret_cast<const float4*>(xx + b * NPTS + j0);
  #pragma unroll
  for (int q = 0; q < 8; ++q) {
    float4 st;
    st.x = fmaf(-2.f, acc[q][0], xxj.x);
    st.y = fmaf(-2.f, acc[q][1], xxj.y);
    st.z = fmaf(-2.f, acc[q][2], xxj.z);
    st.w = fmaf(-2.f, acc[q][3], xxj.w);
    *reinterpret_cast<float4*>(&sc[q][j0]) = st;
  }
  __syncthreads();

  // selection: wave wv owns queries 2wv, 2wv+1; fully branchless, 2-way interleaved
  const int wv = tid >> 6, lane = tid & 63;
  const int q0 = wv * 2, q1 = q0 + 1;
  float v0[16], v1[16];
  #pragma unroll
  for (int s = 0; s < 16; ++s) {
    v0[s] = sc[q0][lane + 64 * s];
    v1[s] = sc[q1][lane + 64 * s];
  }
  int my0 = 0, my1 = 0;
  for (int t = 0; t < KNN; ++t) {
    float bv0 = v0[0], bv1 = v1[0];
    int bs0 = 0, bs1 = 0;
    #pragma unroll
    for (int s = 1; s < 16; ++s) {
      if (v0[s] < bv0) { bv0 = v0[s]; bs0 = s; }
      if (v1[s] < bv1) { bv1 = v1[s]; bs1 = s; }
    }
    int bj0 = lane + (bs0 << 6), bj1 = lane + (bs1 << 6);
    #pragma unroll
    for (int off = 32; off > 0; off >>= 1) {
      const float ov0 = __shfl_xor(bv0, off); const int oj0 = __shfl_xor(bj0, off);
      const float ov1 = __shfl_xor(bv1, off); const int oj1 = __shfl_xor(bj1, off);
      const bool c0 = (ov0 < bv0) || (ov0 == bv0 && oj0 < bj0);
      const bool c1 = (ov1 < bv1) || (ov1 == bv1 && oj1 < bj1);
      bv0 = c0 ? ov0 : bv0; bj0 = c0 ? oj0 : bj0;
      bv1 = c1 ? ov1 : bv1; bj1 = c1 ? oj1 : bj1;
    }
    if (lane == t) { my0 = bj0; my1 = bj1; }
    const int ks0 = bj0 - lane, ks1 = bj1 - lane;   // == 64*s only on the winner lane
    #pragma unroll
    for (int s = 0; s < 16; ++s) {
      if (ks0 == (s << 6)) v0[s] = 3.4e38f;
      if (ks1 == (s << 6)) v1[s] = 3.4e38f;
    }
  }
  if (lane < KNN) {
    idxout[(size_t)(b * NPTS + i0 + q0) * KNN + lane] = my0;
    idxout[(size_t)(b * NPTS + i0 + q1) * KNN + lane] = my1;
  }
}

// ---- 64-tile GEMM: out[b,n,o] = sum_c X[b,n,c]*W[o,c], W passed TRANSPOSED WT[c][o] ----
__global__ __launch_bounds__(256)
void gemm_kernel(const float* __restrict__ X, long sxb, int sxn, int sxc,
                 const float* __restrict__ WT, int ldW, int C,
                 float* __restrict__ out, int sob, int son) {
  __shared__ __align__(16) float Xs[16][64];
  __shared__ __align__(16) float Ws[16][64];
  const int b = blockIdx.z;
  const int n0 = blockIdx.x * 64, o0 = blockIdx.y * 64;
  const int tid = threadIdx.x;
  const int lr = tid & 63;
  const int c4 = (tid >> 6) * 4;
  const int tn = tid & 15, to = tid >> 4;
  float acc[4][4];
  #pragma unroll
  for (int i = 0; i < 4; ++i)
    #pragma unroll
    for (int j = 0; j < 4; ++j) acc[i][j] = 0.f;

  const size_t xbase = (size_t)b * sxb;
  for (int k0 = 0; k0 < C; k0 += 16) {
    #pragma unroll
    for (int u = 0; u < 4; ++u) {
      int c = k0 + c4 + u;
      float xv = 0.f, wv = 0.f;
      if (c < C) {
        xv = X[xbase + (size_t)(n0 + lr) * sxn + (size_t)c * sxc];
        wv = WT[(size_t)c * ldW + o0 + lr];
      }
      Xs[c4 + u][lr] = xv;
      Ws[c4 + u][lr] = wv;
    }
    __syncthreads();
    #pragma unroll
    for (int kk = 0; kk < 16; ++kk) {
      const float4 xa = *reinterpret_cast<const float4*>(&Xs[kk][tn * 4]);
      const float4 wb = *reinterpret_cast<const float4*>(&Ws[kk][to * 4]);
      const float xr[4] = {xa.x, xa.y, xa.z, xa.w};
      const float wr[4] = {wb.x, wb.y, wb.z, wb.w};
      #pragma unroll
      for (int i = 0; i < 4; ++i)
        #pragma unroll
        for (int j = 0; j < 4; ++j) acc[i][j] = fmaf(xr[i], wr[j], acc[i][j]);
    }
    __syncthreads();
  }
  #pragma unroll
  for (int i = 0; i < 4; ++i) {
    float4 st = make_float4(acc[i][0], acc[i][1], acc[i][2], acc[i][3]);
    *reinterpret_cast<float4*>(&out[(size_t)b * sob + (size_t)(n0 + tn * 4 + i) * son + o0 + to * 4]) = st;
  }
}

// ---- 128x128-tile GEMM; X channel-major X[b][c][n] (stride scN along c) ----
template<int EPI>
__global__ __launch_bounds__(256)
void gemm128_kernel(const float* __restrict__ X, long sxb, int scN,
                    const float* __restrict__ WT, int ldW, int C,
                    float* __restrict__ out, int sob, int son, int snb) {
  __shared__ __align__(16) float Xs[16][128];
  __shared__ __align__(16) float Ws[16][128];
  __shared__ __align__(16) float red[16][128];
  const int b = blockIdx.z;
  const int n0 = blockIdx.x * 128, o0 = blockIdx.y * 128;
  const int tid = threadIdx.x;
  const int tn = tid & 15, to = tid >> 4;
  float acc[8][8];
  #pragma unroll
  for (int i = 0; i < 8; ++i)
    #pragma unroll
    for (int j = 0; j < 8; ++j) acc[i][j] = 0.f;

  const size_t xbase = (size_t)b * sxb;
  for (int c0 = 0; c0 < C; c0 += 16) {
    #pragma unroll
    for (int it = 0; it < 2; ++it) {
      const int task = tid + it * 256;
      const int kk = task >> 5, n4 = (task & 31) * 4;
      *reinterpret_cast<float4*>(&Xs[kk][n4]) =
        *reinterpret_cast<const float4*>(&X[xbase + (size_t)(c0 + kk) * scN + n0 + n4]);
      *reinterpret_cast<float4*>(&Ws[kk][n4]) =
        *reinterpret_cast<const float4*>(&WT[(size_t)(c0 + kk) * ldW + o0 + n4]);
    }
    __syncthreads();
    #pragma unroll
    for (int kk = 0; kk < 16; ++kk) {
      const float4 xa0 = *reinterpret_cast<const float4*>(&Xs[kk][tn * 4]);
      const float4 xa1 = *reinterpret_cast<const float4*>(&Xs[kk][64 + tn * 4]);
      const float4 wb0 = *reinterpret_cast<const float4*>(&Ws[kk][to * 4]);
      const float4 wb1 = *reinterpret_cast<const float4*>(&Ws[kk][64 + to * 4]);
      const float xr[8] = {xa0.x, xa0.y, xa0.z, xa0.w, xa1.x, xa1.y, xa1.z, xa1.w};
      const float wr[8] = {wb0.x, wb0.y, wb0.z, wb0.w, wb1.x, wb1.y, wb1.z, wb1.w};
      #pragma unroll
      for (int i = 0; i < 8; ++i)
        #pragma unroll
        for (int j = 0; j < 8; ++j) acc[i][j] = fmaf(xr[i], wr[j], acc[i][j]);
    }
    __syncthreads();
  }

  if (EPI == 0) {
    #pragma unroll
    for (int i = 0; i < 8; ++i) {
      const int n = n0 + (i >> 2) * 64 + tn * 4 + (i & 3);
      float4 s0 = make_float4(acc[i][0], acc[i][1], acc[i][2], acc[i][3]);
      float4 s1 = make_float4(acc[i][4], acc[i][5], acc[i][6], acc[i][7]);
      *reinterpret_cast<float4*>(&out[(size_t)b * sob + (size_t)n * son + o0 + to * 4]) = s0;
      *reinterpret_cast<float4*>(&out[(size_t)b * sob + (size_t)n * son + o0 + 64 + to * 4]) = s1;
    }
  } else {
    #pragma unroll
    for (int j = 0; j < 8; ++j) {
      float m = lrelu(acc[0][j]);
      #pragma unroll
      for (int i = 1; i < 8; ++i) m = fmaxf(m, lrelu(acc[i][j]));
      red[tn][(j >> 2) * 64 + to * 4 + (j & 3)] = m;
    }
    __syncthreads();
    if (tid < 128) {
      float m = red[0][tid];
      #pragma unroll
      for (int t = 1; t < 16; ++t) m = fmaxf(m, red[t][tid]);
      out[(size_t)b * sob + (size_t)blockIdx.x * snb + o0 + tid] = m;
    }
  }
}

// ---- edge max, channel-major output via LDS transpose tile ----
template<int O, int TI>
__global__ __launch_bounds__(256)
void edge_max_cn_kernel(const float* __restrict__ y, const float* __restrict__ z,
                        const int* __restrict__ idx, float* __restrict__ outCN,
                        float* __restrict__ xx) {
  __shared__ float tile[TI][O + 1];
  const int b = blockIdx.y;
  const int i0 = blockIdx.x * TI;
  const int wv = threadIdx.x >> 6, lane = threadIdx.x & 63;
  constexpr int OSEG = O / 64;
  constexpr int ROUNDS = TI * OSEG / 4;
  for (int r = 0; r < ROUNDS; ++r) {
    const int item = r * 4 + wv;
    const int il = item / OSEG, os = item - il * OSEG;
    const int i = i0 + il, o = os * 64 + lane;
    const int* ip = idx + (size_t)(b * NPTS + i) * KNN;
    const float zv = z[(size_t)(b * NPTS + i) * O + o];
    float m = -3.4e38f;
    #pragma unroll
    for (int t = 0; t < KNN; ++t) {
      int j = ip[t];
      float v = y[(size_t)(b * NPTS + j) * O + o] + zv;
      m = fmaxf(m, lrelu(v));
    }
    tile[il][o] = m;
  }
  __syncthreads();
  if (xx != nullptr && threadIdx.x < TI) {
    const int il = threadIdx.x;
    float s = 0.f;
    #pragma unroll
    for (int o = 0; o < O; ++o) { float v = tile[il][o]; s = fmaf(v, v, s); }
    xx[b * NPTS + i0 + il] = s;
  }
  for (int e = threadIdx.x; e < TI * O; e += 256) {
    const int o = e / TI, il = e - o * TI;
    outCN[(size_t)b * 512 * NPTS + (size_t)o * NPTS + i0 + il] = tile[il][o];
  }
}

// ---- h12 as edge-GEMM: 4 points/block, 80 edges x 64k x 128out, max over k in-wave ----
__global__ __launch_bounds__(256)
void h12_gemm_kernel(const float* __restrict__ ya, const float* __restrict__ zb,
                     const int* __restrict__ idx, const float* __restrict__ tw2T,
                     float* __restrict__ h2m) {
  __shared__ __align__(16) float h1s[80][68];
  __shared__ __align__(16) float ws[64][128];
  __shared__ __align__(16) float zbs[4][64];
  __shared__ float ot[128][4];
  __shared__ int idxs[4][KNN];
  const int b = blockIdx.y;
  const int i0 = blockIdx.x * 4;
  const int tid = threadIdx.x;

  #pragma unroll
  for (int it = 0; it < 8; ++it) {
    const int f = tid + it * 256;
    *reinterpret_cast<float4*>(&ws[0][0] + f * 4) =
      *reinterpret_cast<const float4*>(tw2T + (size_t)f * 4);
  }
  if (tid < 64) {
    const int p = tid >> 4, cq = (tid & 15) * 4;
    *reinterpret_cast<float4*>(&zbs[p][cq]) =
      *reinterpret_cast<const float4*>(&zb[(size_t)(b * NPTS + i0 + p) * 64 + cq]);
  }
  if (tid >= 64 && tid < 64 + 4 * KNN) {
    const int e = tid - 64;
    idxs[e / KNN][e % KNN] = idx[(size_t)(b * NPTS + i0) * KNN + e];
  }
  __syncthreads();

  #pragma unroll
  for (int it = 0; it < 5; ++it) {
    const int task = tid + it * 256;
    const int e = task >> 4, cq = (task & 15) * 4;
    const int p = e / KNN, t = e - p * KNN;
    const int j = idxs[p][t];
    const float4 yv = *reinterpret_cast<const float4*>(&ya[(size_t)(b * NPTS + j) * 64 + cq]);
    const float4 zv = *reinterpret_cast<const float4*>(&zbs[p][cq]);
    float4 hv;
    hv.x = lrelu(yv.x + zv.x); hv.y = lrelu(yv.y + zv.y);
    hv.z = lrelu(yv.z + zv.z); hv.w = lrelu(yv.w + zv.w);
    *reinterpret_cast<float4*>(&h1s[e][cq]) = hv;
  }
  __syncthreads();

  const int eg = tid >> 4, og = tid & 15;
  float acc[5][8];
  #pragma unroll
  for (int u = 0; u < 5; ++u)
    #pragma unroll
    for (int v = 0; v < 8; ++v) acc[u][v] = 0.f;
  #pragma unroll 4
  for (int kk = 0; kk < 64; ++kk) {
    float hv[5];
    #pragma unroll
    for (int u = 0; u < 5; ++u) hv[u] = h1s[eg * 5 + u][kk];
    const float4 w0 = *reinterpret_cast<const float4*>(&ws[kk][og * 4]);
    const float4 w1 = *reinterpret_cast<const float4*>(&ws[kk][64 + og * 4]);
    const float wr[8] = {w0.x, w0.y, w0.z, w0.w, w1.x, w1.y, w1.z, w1.w};
    #pragma unroll
    for (int u = 0; u < 5; ++u)
      #pragma unroll
      for (int v = 0; v < 8; ++v) acc[u][v] = fmaf(hv[u], wr[v], acc[u][v]);
  }

  const int p = eg >> 2, d = eg & 3;
  float m[8];
  #pragma unroll
  for (int v = 0; v < 8; ++v) {
    float mm = lrelu(acc[0][v]);
    #pragma unroll
    for (int u = 1; u < 5; ++u) mm = fmaxf(mm, lrelu(acc[u][v]));
    mm = fmaxf(mm, __shfl_xor(mm, 16));
    mm = fmaxf(mm, __shfl_xor(mm, 32));
    m[v] = mm;
  }
  if (d == 0) {
    #pragma unroll
    for (int v = 0; v < 8; ++v) {
      const int o = og * 4 + (v & 3) + (v >> 2) * 64;
      ot[o][p] = m[v];
    }
  }
  __syncthreads();
  if (tid < 128) {
    float4 st = make_float4(ot[tid][0], ot[tid][1], ot[tid][2], ot[tid][3]);
    *reinterpret_cast<float4*>(&h2m[(size_t)(b * 128 + tid) * NPTS + i0]) = st;
  }
}

// ---- reduce partial max over nt n-tiles ----
__global__ __launch_bounds__(256)
void reduce_max_kernel(const float* __restrict__ part, float* __restrict__ outp, int nt) {
  const int b = blockIdx.y;
  const int o = blockIdx.x * 256 + threadIdx.x;
  float m = part[(size_t)(b * nt) * 1024 + o];
  for (int t = 1; t < nt; ++t) m = fmaxf(m, part[(size_t)(b * nt + t) * 1024 + o]);
  outp[b * 1024 + o] = m;
}

// ---- block reduce helper ----
__device__ __forceinline__ float block_reduce_sum(float v, float* rbuf) {
  #pragma unroll
  for (int off = 32; off > 0; off >>= 1) v += __shfl_xor(v, off);
  const int w = threadIdx.x >> 6, lane = threadIdx.x & 63;
  const int nw = blockDim.x >> 6;
  if (lane == 0) rbuf[w] = v;
  __syncthreads();
  float tot = 0.f;
  for (int i = 0; i < nw; ++i) tot += rbuf[i];
  __syncthreads();
  return tot;
}

// ---- fc1: l2n -> 1024x512 (no bias) -> LN -> lrelu ----
__global__ __launch_bounds__(256)
void fc1_kernel(const float* __restrict__ gin_g, const float* __restrict__ Wt,
                const float* __restrict__ gam, const float* __restrict__ bet,
                float* __restrict__ outp) {
  __shared__ __align__(16) float gin[1024];
  __shared__ float hbuf[512];
  __shared__ float rbuf[8];
  const int b = blockIdx.x, tid = threadIdx.x;
  for (int e = tid; e < 1024; e += 256) gin[e] = gin_g[b * 1024 + e];
  __syncthreads();
  float ps = 0.f;
  for (int e = tid; e < 1024; e += 256) ps = fmaf(gin[e], gin[e], ps);
  float ss = block_reduce_sum(ps, rbuf);
  float rinv = 1.0f / sqrtf(ss);
  #pragma unroll
  for (int r = 0; r < 2; ++r) {
    int o = tid + r * 256;
    const float* wrow = Wt + (size_t)o * 1024;
    float a = 0.f;
    for (int c4 = 0; c4 < 256; ++c4) {
      float4 wv = *reinterpret_cast<const float4*>(wrow + c4 * 4);
      float4 gv = *reinterpret_cast<const float4*>(&gin[c4 * 4]);
      a = fmaf(wv.x, gv.x, a); a = fmaf(wv.y, gv.y, a);
      a = fmaf(wv.z, gv.z, a); a = fmaf(wv.w, gv.w, a);
    }
    hbuf[o] = a * rinv;
  }
  __syncthreads();
  float pm = hbuf[tid] + hbuf[tid + 256];
  float mean = block_reduce_sum(pm, rbuf) * (1.f / 512.f);
  float d0 = hbuf[tid] - mean, d1 = hbuf[tid + 256] - mean;
  float var = block_reduce_sum(d0 * d0 + d1 * d1, rbuf) * (1.f / 512.f);
  float rs = 1.0f / sqrtf(var + 1e-5f);
  #pragma unroll
  for (int r = 0; r < 2; ++r) {
    int o = tid + r * 256;
    float yv = (hbuf[o] - mean) * rs * gam[o] + bet[o];
    outp[b * 512 + o] = lrelu(yv);
  }
}

// ---- fc2: l2n -> 512x256 (+bias) -> LN -> lrelu ----
__global__ __launch_bounds__(256)
void fc2_kernel(const float* __restrict__ inp, const float* __restrict__ Wt,
                const float* __restrict__ bias, const float* __restrict__ gam,
                const float* __restrict__ bet, float* __restrict__ outp) {
  __shared__ __align__(16) float gin[512];
  __shared__ float rbuf[8];
  const int b = blockIdx.x, tid = threadIdx.x;
  for (int e = tid; e < 512; e += 256) gin[e] = inp[b * 512 + e];
  __syncthreads();
  float ps = 0.f;
  for (int e = tid; e < 512; e += 256) ps = fmaf(gin[e], gin[e], ps);
  float ss = block_reduce_sum(ps, rbuf);
  float rinv = 1.0f / sqrtf(ss);
  const float* wrow = Wt + (size_t)tid * 512;
  float a = 0.f;
  for (int c4 = 0; c4 < 128; ++c4) {
    float4 wv = *reinterpret_cast<const float4*>(wrow + c4 * 4);
    float4 gv = *reinterpret_cast<const float4*>(&gin[c4 * 4]);
    a = fmaf(wv.x, gv.x, a); a = fmaf(wv.y, gv.y, a);
    a = fmaf(wv.z, gv.z, a); a = fmaf(wv.w, gv.w, a);
  }
  a = a * rinv + bias[tid];
  float mean = block_reduce_sum(a, rbuf) * (1.f / 256.f);
  float d = a - mean;
  float var = block_reduce_sum(d * d, rbuf) * (1.f / 256.f);
  float rs = 1.0f / sqrtf(var + 1e-5f);
  float yv = (a - mean) * rs * gam[tid] + bet[tid];
  outp[b * 256 + tid] = lrelu(yv);
}

// ---- fc3 + identity ----
__global__ __launch_bounds__(64)
void fc3_kernel(const float* __restrict__ inp, const float* __restrict__ Wt,
                const float* __restrict__ bias, float* __restrict__ tmat) {
  __shared__ float gin[256];
  const int b = blockIdx.x, tid = threadIdx.x;
  for (int e = tid; e < 256; e += 64) gin[e] = inp[b * 256 + e];
  __syncthreads();
  if (tid < 9) {
    const float* wrow = Wt + tid * 256;
    float a = 0.f;
    for (int c = 0; c < 256; ++c) a = fmaf(wrow[c], gin[c], a);
    a += bias[tid];
    if (tid == 0 || tid == 4 || tid == 8) a += 1.f;
    tmat[b * 9 + tid] = a;
  }
}

// ---- apply 3x3 transform ----
__global__ __launch_bounds__(256)
void xform_kernel(const float* __restrict__ x, const float* __restrict__ tmat,
                  float* __restrict__ xt) {
  const int b = blockIdx.y;
  const int n = blockIdx.x * 256 + threadIdx.x;
  const float* xb = x + (size_t)b * 3 * NPTS;
  const float x0 = xb[n], x1 = xb[NPTS + n], x2 = xb[2 * NPTS + n];
  const float* t = tmat + b * 9;
  float* ob = xt + (size_t)b * 3 * NPTS;
  #pragma unroll
  for (int i = 0; i < 3; ++i)
    ob[i * NPTS + n] = fmaf(t[3 * i], x0, fmaf(t[3 * i + 1], x1, t[3 * i + 2] * x2));
}

extern "C" void kernel_launch(void* const* d_in, const int* in_sizes, int n_in,
                              void* d_out, int out_size, void* d_ws, size_t ws_size,
                              hipStream_t stream) {
  (void)in_sizes; (void)n_in; (void)out_size; (void)ws_size;
  const float* x       = (const float*)d_in[0];
  const float* tw1     = (const float*)d_in[1];
  const float* tw2     = (const float*)d_in[2];
  const float* tw3     = (const float*)d_in[3];
  const float* tfc1_w  = (const float*)d_in[4];
  const float* tfc1_g  = (const float*)d_in[5];
  const float* tfc1_b  = (const float*)d_in[6];
  const float* tfc2_w  = (const float*)d_in[7];
  const float* tfc2_bias = (const float*)d_in[8];
  const float* tfc2_g  = (const float*)d_in[9];
  const float* tfc2_b  = (const float*)d_in[10];
  const float* tfc3_w  = (const float*)d_in[11];
  const float* tfc3_b  = (const float*)d_in[12];
  const float* w1      = (const float*)d_in[13];
  const float* w2      = (const float*)d_in[14];
  const float* w3      = (const float*)d_in[15];
  const float* w4      = (const float*)d_in[16];
  const float* w5      = (const float*)d_in[17];
  float* out = (float*)d_out;

  char* wsb = (char*)d_ws;
  size_t off = 0;
  auto alloc = [&](size_t bytes) -> void* {
    void* p = wsb + off;
    off += (bytes + 255) & ~(size_t)255;
    return p;
  };
  float* ybuf = (float*)alloc((size_t)BATCH * NPTS * 256 * 4);
  float* zbuf = (float*)alloc((size_t)BATCH * NPTS * 256 * 4);
  float* xcT  = (float*)alloc((size_t)BATCH * 512 * NPTS * 4);   // channel-major x1..x4
  float* h2m  = (float*)alloc((size_t)BATCH * 128 * NPTS * 4);   // channel-major
  float* part = (float*)alloc((size_t)BATCH * 16 * 1024 * 4);
  int*   idxb = (int*)alloc((size_t)BATCH * NPTS * KNN * 4);
  float* xxb  = (float*)alloc((size_t)BATCH * NPTS * 4);
  float* xt   = (float*)alloc((size_t)BATCH * 3 * NPTS * 4);
  float* gbuf = (float*)alloc((size_t)BATCH * 1024 * 4);
  float* f1o  = (float*)alloc((size_t)BATCH * 512 * 4);
  float* f2o  = (float*)alloc((size_t)BATCH * 256 * 4);
  float* tmat = (float*)alloc((size_t)BATCH * 9 * 4);
  float* tw1aT = (float*)alloc(3 * 64 * 4);
  float* tw1dT = (float*)alloc(3 * 64 * 4);
  float* w1aT  = (float*)alloc(3 * 64 * 4);
  float* w1dT  = (float*)alloc(3 * 64 * 4);
  float* w2aT  = (float*)alloc(64 * 64 * 4);
  float* w2dT  = (float*)alloc(64 * 64 * 4);
  float* w3aT  = (float*)alloc(64 * 128 * 4);
  float* w3dT  = (float*)alloc(64 * 128 * 4);
  float* w4aT  = (float*)alloc(128 * 256 * 4);
  float* w4dT  = (float*)alloc(128 * 256 * 4);
  float* tw2T  = (float*)alloc(64 * 128 * 4);
  float* tw3T  = (float*)alloc(128 * 1024 * 4);
  float* w5T   = (float*)alloc(512 * 1024 * 4);

  // weight prep
  wsplit_t_kernel<<<1, 256, 0, stream>>>(tw1, tw1aT, tw1dT, 64, 3);
  wsplit_t_kernel<<<1, 256, 0, stream>>>(w1, w1aT, w1dT, 64, 3);
  wsplit_t_kernel<<<16, 256, 0, stream>>>(w2, w2aT, w2dT, 64, 64);
  wsplit_t_kernel<<<32, 256, 0, stream>>>(w3, w3aT, w3dT, 128, 64);
  wsplit_t_kernel<<<128, 256, 0, stream>>>(w4, w4aT, w4dT, 256, 128);
  wtrans_kernel<<<32, 256, 0, stream>>>(tw2, tw2T, 128, 64);
  wtrans_kernel<<<512, 256, 0, stream>>>(tw3, tw3T, 1024, 128);
  wtrans_kernel<<<2048, 256, 0, stream>>>(w5, w5T, 1024, 512);

  // ---- transform net ----
  xx3_kernel<<<dim3(4, 16), 256, 0, stream>>>(x, xxb);
  knn_cn_kernel<3><<<dim3(128, 16), 256, 0, stream>>>(x, 3 * NPTS, xxb, idxb);
  gemm_kernel<<<dim3(16, 1, 16), 256, 0, stream>>>(x, 3 * NPTS, 1, NPTS, tw1aT, 64, 3,
                                                   ybuf, NPTS * 64, 64);
  gemm_kernel<<<dim3(16, 1, 16), 256, 0, stream>>>(x, 3 * NPTS, 1, NPTS, tw1dT, 64, 3,
                                                   zbuf, NPTS * 64, 64);
  h12_gemm_kernel<<<dim3(256, 16), 256, 0, stream>>>(ybuf, zbuf, idxb, tw2T, h2m);
  gemm128_kernel<1><<<dim3(8, 8, 16), 256, 0, stream>>>(h2m, 128 * NPTS, NPTS, tw3T, 1024, 128,
                                                        part, 8 * 1024, 0, 1024);
  reduce_max_kernel<<<dim3(4, 16), 256, 0, stream>>>(part, gbuf, 8);
  fc1_kernel<<<16, 256, 0, stream>>>(gbuf, tfc1_w, tfc1_g, tfc1_b, f1o);
  fc2_kernel<<<16, 256, 0, stream>>>(f1o, tfc2_w, tfc2_bias, tfc2_g, tfc2_b, f2o);
  fc3_kernel<<<16, 64, 0, stream>>>(f2o, tfc3_w, tfc3_b, tmat);
  xform_kernel<<<dim3(4, 16), 256, 0, stream>>>(x, tmat, xt);

  // ---- EdgeConv 1 (C=3 -> O=64) on xt ----
  xx3_kernel<<<dim3(4, 16), 256, 0, stream>>>(xt, xxb);
  knn_cn_kernel<3><<<dim3(128, 16), 256, 0, stream>>>(xt, 3 * NPTS, xxb, idxb);
  gemm_kernel<<<dim3(16, 1, 16), 256, 0, stream>>>(xt, 3 * NPTS, 1, NPTS, w1aT, 64, 3,
                                                   ybuf, NPTS * 64, 64);
  gemm_kernel<<<dim3(16, 1, 16), 256, 0, stream>>>(xt, 3 * NPTS, 1, NPTS, w1dT, 64, 3,
                                                   zbuf, NPTS * 64, 64);
  edge_max_cn_kernel<64, 64><<<dim3(16, 16), 256, 0, stream>>>(ybuf, zbuf, idxb, xcT, xxb);

  // ---- EdgeConv 2 (C=64 -> O=64), input xcT ch 0..63 ----
  knn_cn_kernel<64><<<dim3(128, 16), 256, 0, stream>>>(xcT, 512 * NPTS, xxb, idxb);
  gemm_kernel<<<dim3(16, 1, 16), 256, 0, stream>>>(xcT, 512 * NPTS, 1, NPTS, w2aT, 64, 64,
                                                   ybuf, NPTS * 64, 64);
  gemm_kernel<<<dim3(16, 1, 16), 256, 0, stream>>>(xcT, 512 * NPTS, 1, NPTS, w2dT, 64, 64,
                                                   zbuf, NPTS * 64, 64);
  edge_max_cn_kernel<64, 64><<<dim3(16, 16), 256, 0, stream>>>(ybuf, zbuf, idxb,
                                                               xcT + 64 * NPTS, xxb);

  // ---- EdgeConv 3 (C=64 -> O=128), input xcT ch 64..127 ----
  knn_cn_kernel<64><<<dim3(128, 16), 256, 0, stream>>>(xcT + 64 * NPTS, 512 * NPTS, xxb, idxb);
  gemm_kernel<<<dim3(16, 2, 16), 256, 0, stream>>>(xcT + 64 * NPTS, 512 * NPTS, 1, NPTS,
                                                   w3aT, 128, 64, ybuf, NPTS * 128, 128);
  gemm_kernel<<<dim3(16, 2, 16), 256, 0, stream>>>(xcT + 64 * NPTS, 512 * NPTS, 1, NPTS,
                                                   w3dT, 128, 64, zbuf, NPTS * 128, 128);
  edge_max_cn_kernel<128, 64><<<dim3(16, 16), 256, 0, stream>>>(ybuf, zbuf, idxb,
                                                                xcT + 128 * NPTS, xxb);

  // ---- EdgeConv 4 (C=128 -> O=256), input xcT ch 128..255 ----
  knn_cn_kernel<128><<<dim3(128, 16), 256, 0, stream>>>(xcT + 128 * NPTS, 512 * NPTS, xxb, idxb);
  gemm128_kernel<0><<<dim3(8, 2, 16), 256, 0, stream>>>(xcT + 128 * NPTS, 512 * NPTS, NPTS,
                                                        w4aT, 256, 128, ybuf, NPTS * 256, 256, 0);
  gemm128_kernel<0><<<dim3(8, 2, 16), 256, 0, stream>>>(xcT + 128 * NPTS, 512 * NPTS, NPTS,
                                                        w4dT, 256, 128, zbuf, NPTS * 256, 256, 0);
  edge_max_cn_kernel<256, 32><<<dim3(32, 16), 256, 0, stream>>>(ybuf, zbuf, idxb,
                                                                xcT + 256 * NPTS, nullptr);

  // ---- final: x5 = lrelu(w5 @ xc) with max over n ----
  gemm128_kernel<1><<<dim3(8, 8, 16), 256, 0, stream>>>(xcT, 512 * NPTS, NPTS, w5T, 1024, 512,
                                                        part, 8 * 1024, 0, 1024);
  reduce_max_kernel<<<dim3(4, 16), 256, 0, stream>>>(part, out, 8);
}

// Round 6
// 1064.150 us; speedup vs baseline: 3.8227x; 1.0044x over previous
//
#include <hip/hip_runtime.h>
#include <math.h>

#define BATCH 16
#define NPTS 1024
#define KNN 20

__device__ __forceinline__ float lrelu(float v) { return v >= 0.f ? v : 0.2f * v; }

// ---- weight prep: W[O][2C] -> WaT[C][O] = W[:, :C]^T ; WdT[C][O] = (W[:,C:]-W[:,:C])^T ----
__global__ __launch_bounds__(256)
void wsplit_t_kernel(const float* __restrict__ W, float* __restrict__ waT,
                     float* __restrict__ wdT, int O, int Cc) {
  int e = blockIdx.x * 256 + threadIdx.x;
  if (e < O * Cc) {
    int c = e / O, o = e - c * O;
    float a = W[o * 2 * Cc + c], bb = W[o * 2 * Cc + Cc + c];
    waT[e] = a; wdT[e] = bb - a;
  }
}

// ---- weight transpose: W[O][C] -> wT[C][O] ----
__global__ __launch_bounds__(256)
void wtrans_kernel(const float* __restrict__ W, float* __restrict__ wT, int O, int Cc) {
  int e = blockIdx.x * 256 + threadIdx.x;
  if (e < O * Cc) {
    int c = e / O, o = e - c * O;
    wT[e] = W[(size_t)o * Cc + c];
  }
}

// ---- xx[b][n] = sum_c x[b][c][n]^2 for C=3 CN input ----
__global__ __launch_bounds__(256)
void xx3_kernel(const float* __restrict__ x, float* __restrict__ xx) {
  const int b = blockIdx.y;
  const int n = blockIdx.x * 256 + threadIdx.x;
  const float* xb = x + (size_t)b * 3 * NPTS;
  float a = xb[n], bb = xb[NPTS + n], c = xb[2 * NPTS + n];
  xx[b * NPTS + n] = a * a + bb * bb + c * c;
}

// ---- knn on channel-major features: Xt[b][c][n], batch stride sb ----
// 8 queries/block (32 KB LDS -> 5 blocks/CU); wave owns 2 queries, extracts interleaved.
template<int C>
__global__ __launch_bounds__(256)
void knn_cn_kernel(const float* __restrict__ Xt, long sb,
                   const float* __restrict__ xx, int* __restrict__ idxout) {
  __shared__ float sc[8][NPTS];   // 32 KB
  const int b = blockIdx.y, i0 = blockIdx.x * 8;
  const int tid = threadIdx.x;
  const float* Xb = Xt + (size_t)b * sb;
  const int j0 = tid * 4;
  float acc[8][4];
  #pragma unroll
  for (int q = 0; q < 8; ++q)
    #pragma unroll
    for (int u = 0; u < 4; ++u) acc[q][u] = 0.f;
  for (int c = 0; c < C; ++c) {
    const float4 xv = *reinterpret_cast<const float4*>(Xb + (size_t)c * NPTS + j0);
    const float* xr = Xb + (size_t)c * NPTS + i0;   // uniform addresses -> scalar loads
    #pragma unroll
    for (int q = 0; q < 8; ++q) {
      const float xiq = xr[q];
      acc[q][0] = fmaf(xiq, xv.x, acc[q][0]);
      acc[q][1] = fmaf(xiq, xv.y, acc[q][1]);
      acc[q][2] = fmaf(xiq, xv.z, acc[q][2]);
      acc[q][3] = fmaf(xiq, xv.w, acc[q][3]);
    }
  }
  const float4 xxj = *reinterpret_cast<const float4*>(xx + b * NPTS + j0);
  #pragma unroll
  for (int q = 0; q < 8; ++q) {
    float4 st;
    st.x = fmaf(-2.f, acc[q][0], xxj.x);
    st.y = fmaf(-2.f, acc[q][1], xxj.y);
    st.z = fmaf(-2.f, acc[q][2], xxj.z);
    st.w = fmaf(-2.f, acc[q][3], xxj.w);
    *reinterpret_cast<float4*>(&sc[q][j0]) = st;
  }
  __syncthreads();

  // selection: wave wv owns queries 2wv, 2wv+1; fully branchless, 2-way interleaved
  const int wv = tid >> 6, lane = tid & 63;
  const int q0 = wv * 2, q1 = q0 + 1;
  float v0[16], v1[16];
  #pragma unroll
  for (int s = 0; s < 16; ++s) {
    v0[s] = sc[q0][lane + 64 * s];
    v1[s] = sc[q1][lane + 64 * s];
  }
  int my0 = 0, my1 = 0;
  for (int t = 0; t < KNN; ++t) {
    float bv0 = v0[0], bv1 = v1[0];
    int bs0 = 0, bs1 = 0;
    #pragma unroll
    for (int s = 1; s < 16; ++s) {
      if (v0[s] < bv0) { bv0 = v0[s]; bs0 = s; }
      if (v1[s] < bv1) { bv1 = v1[s]; bs1 = s; }
    }
    int bj0 = lane + (bs0 << 6), bj1 = lane + (bs1 << 6);
    #pragma unroll
    for (int off = 32; off > 0; off >>= 1) {
      const float ov0 = __shfl_xor(bv0, off); const int oj0 = __shfl_xor(bj0, off);
      const float ov1 = __shfl_xor(bv1, off); const int oj1 = __shfl_xor(bj1, off);
      const bool c0 = (ov0 < bv0) || (ov0 == bv0 && oj0 < bj0);
      const bool c1 = (ov1 < bv1) || (ov1 == bv1 && oj1 < bj1);
      bv0 = c0 ? ov0 : bv0; bj0 = c0 ? oj0 : bj0;
      bv1 = c1 ? ov1 : bv1; bj1 = c1 ? oj1 : bj1;
    }
    if (lane == t) { my0 = bj0; my1 = bj1; }
    const int ks0 = bj0 - lane, ks1 = bj1 - lane;   // == 64*s only on the winner lane
    #pragma unroll
    for (int s = 0; s < 16; ++s) {
      if (ks0 == (s << 6)) v0[s] = 3.4e38f;
      if (ks1 == (s << 6)) v1[s] = 3.4e38f;
    }
  }
  if (lane < KNN) {
    idxout[(size_t)(b * NPTS + i0 + q0) * KNN + lane] = my0;
    idxout[(size_t)(b * NPTS + i0 + q1) * KNN + lane] = my1;
  }
}

// ---- 64-tile GEMM: out[b,n,o] = sum_c X[b,n,c]*W[o,c], W passed TRANSPOSED WT[c][o] ----
__global__ __launch_bounds__(256)
void gemm_kernel(const float* __restrict__ X, long sxb, int sxn, int sxc,
                 const float* __restrict__ WT, int ldW, int C,
                 float* __restrict__ out, int sob, int son) {
  __shared__ __align__(16) float Xs[16][64];
  __shared__ __align__(16) float Ws[16][64];
  const int b = blockIdx.z;
  const int n0 = blockIdx.x * 64, o0 = blockIdx.y * 64;
  const int tid = threadIdx.x;
  const int lr = tid & 63;
  const int c4 = (tid >> 6) * 4;
  const int tn = tid & 15, to = tid >> 4;
  float acc[4][4];
  #pragma unroll
  for (int i = 0; i < 4; ++i)
    #pragma unroll
    for (int j = 0; j < 4; ++j) acc[i][j] = 0.f;

  const size_t xbase = (size_t)b * sxb;
  for (int k0 = 0; k0 < C; k0 += 16) {
    #pragma unroll
    for (int u = 0; u < 4; ++u) {
      int c = k0 + c4 + u;
      float xv = 0.f, wv = 0.f;
      if (c < C) {
        xv = X[xbase + (size_t)(n0 + lr) * sxn + (size_t)c * sxc];
        wv = WT[(size_t)c * ldW + o0 + lr];
      }
      Xs[c4 + u][lr] = xv;
      Ws[c4 + u][lr] = wv;
    }
    __syncthreads();
    #pragma unroll
    for (int kk = 0; kk < 16; ++kk) {
      const float4 xa = *reinterpret_cast<const float4*>(&Xs[kk][tn * 4]);
      const float4 wb = *reinterpret_cast<const float4*>(&Ws[kk][to * 4]);
      const float xr[4] = {xa.x, xa.y, xa.z, xa.w};
      const float wr[4] = {wb.x, wb.y, wb.z, wb.w};
      #pragma unroll
      for (int i = 0; i < 4; ++i)
        #pragma unroll
        for (int j = 0; j < 4; ++j) acc[i][j] = fmaf(xr[i], wr[j], acc[i][j]);
    }
    __syncthreads();
  }
  #pragma unroll
  for (int i = 0; i < 4; ++i) {
    float4 st = make_float4(acc[i][0], acc[i][1], acc[i][2], acc[i][3]);
    *reinterpret_cast<float4*>(&out[(size_t)b * sob + (size_t)(n0 + tn * 4 + i) * son + o0 + to * 4]) = st;
  }
}

// ---- 128x128-tile GEMM; X channel-major X[b][c][n] (stride scN along c) ----
// Register-prefetch double buffering: next K-tile's global loads issue before the
// FMA loop (latency hides under 1024 FMA insts); LDS written after post-compute barrier.
// red padded to 132 to kill the 16-way epilogue bank conflict (512B row stride -> same bank).
template<int EPI>
__global__ __launch_bounds__(256)
void gemm128_kernel(const float* __restrict__ X, long sxb, int scN,
                    const float* __restrict__ WT, int ldW, int C,
                    float* __restrict__ out, int sob, int son, int snb) {
  __shared__ __align__(16) float Xs[16][128];
  __shared__ __align__(16) float Ws[16][128];
  __shared__ __align__(16) float red[16][132];
  const int b = blockIdx.z;
  const int n0 = blockIdx.x * 128, o0 = blockIdx.y * 128;
  const int tid = threadIdx.x;
  const int tn = tid & 15, to = tid >> 4;
  float acc[8][8];
  #pragma unroll
  for (int i = 0; i < 8; ++i)
    #pragma unroll
    for (int j = 0; j < 8; ++j) acc[i][j] = 0.f;

  const size_t xbase = (size_t)b * sxb;
  // staging addresses for this thread's two tasks
  const int kk0 = tid >> 5, n40 = (tid & 31) * 4;              // task = tid
  const int kk1 = (tid + 256) >> 5, n41 = ((tid + 256) & 31) * 4;
  float4 px0, px1, pw0, pw1;
  // initial prefetch (c0 = 0)
  px0 = *reinterpret_cast<const float4*>(&X[xbase + (size_t)kk0 * scN + n0 + n40]);
  px1 = *reinterpret_cast<const float4*>(&X[xbase + (size_t)kk1 * scN + n0 + n41]);
  pw0 = *reinterpret_cast<const float4*>(&WT[(size_t)kk0 * ldW + o0 + n40]);
  pw1 = *reinterpret_cast<const float4*>(&WT[(size_t)kk1 * ldW + o0 + n41]);

  for (int c0 = 0; c0 < C; c0 += 16) {
    // write staged registers to LDS
    *reinterpret_cast<float4*>(&Xs[kk0][n40]) = px0;
    *reinterpret_cast<float4*>(&Xs[kk1][n41]) = px1;
    *reinterpret_cast<float4*>(&Ws[kk0][n40]) = pw0;
    *reinterpret_cast<float4*>(&Ws[kk1][n41]) = pw1;
    __syncthreads();
    // prefetch next K-tile (loads in flight during compute)
    if (c0 + 16 < C) {
      const int cn = c0 + 16;
      px0 = *reinterpret_cast<const float4*>(&X[xbase + (size_t)(cn + kk0) * scN + n0 + n40]);
      px1 = *reinterpret_cast<const float4*>(&X[xbase + (size_t)(cn + kk1) * scN + n0 + n41]);
      pw0 = *reinterpret_cast<const float4*>(&WT[(size_t)(cn + kk0) * ldW + o0 + n40]);
      pw1 = *reinterpret_cast<const float4*>(&WT[(size_t)(cn + kk1) * ldW + o0 + n41]);
    }
    #pragma unroll
    for (int kk = 0; kk < 16; ++kk) {
      const float4 xa0 = *reinterpret_cast<const float4*>(&Xs[kk][tn * 4]);
      const float4 xa1 = *reinterpret_cast<const float4*>(&Xs[kk][64 + tn * 4]);
      const float4 wb0 = *reinterpret_cast<const float4*>(&Ws[kk][to * 4]);
      const float4 wb1 = *reinterpret_cast<const float4*>(&Ws[kk][64 + to * 4]);
      const float xr[8] = {xa0.x, xa0.y, xa0.z, xa0.w, xa1.x, xa1.y, xa1.z, xa1.w};
      const float wr[8] = {wb0.x, wb0.y, wb0.z, wb0.w, wb1.x, wb1.y, wb1.z, wb1.w};
      #pragma unroll
      for (int i = 0; i < 8; ++i)
        #pragma unroll
        for (int j = 0; j < 8; ++j) acc[i][j] = fmaf(xr[i], wr[j], acc[i][j]);
    }
    __syncthreads();
  }

  if (EPI == 0) {
    #pragma unroll
    for (int i = 0; i < 8; ++i) {
      const int n = n0 + (i >> 2) * 64 + tn * 4 + (i & 3);
      float4 s0 = make_float4(acc[i][0], acc[i][1], acc[i][2], acc[i][3]);
      float4 s1 = make_float4(acc[i][4], acc[i][5], acc[i][6], acc[i][7]);
      *reinterpret_cast<float4*>(&out[(size_t)b * sob + (size_t)n * son + o0 + to * 4]) = s0;
      *reinterpret_cast<float4*>(&out[(size_t)b * sob + (size_t)n * son + o0 + 64 + to * 4]) = s1;
    }
  } else {
    #pragma unroll
    for (int j = 0; j < 8; ++j) {
      float m = lrelu(acc[0][j]);
      #pragma unroll
      for (int i = 1; i < 8; ++i) m = fmaxf(m, lrelu(acc[i][j]));
      red[tn][(j >> 2) * 64 + to * 4 + (j & 3)] = m;
    }
    __syncthreads();
    if (tid < 128) {
      float m = red[0][tid];
      #pragma unroll
      for (int t = 1; t < 16; ++t) m = fmaxf(m, red[t][tid]);
      out[(size_t)b * sob + (size_t)blockIdx.x * snb + o0 + tid] = m;
    }
  }
}

// ---- edge max, channel-major output via LDS transpose tile ----
template<int O, int TI>
__global__ __launch_bounds__(256)
void edge_max_cn_kernel(const float* __restrict__ y, const float* __restrict__ z,
                        const int* __restrict__ idx, float* __restrict__ outCN,
                        float* __restrict__ xx) {
  __shared__ float tile[TI][O + 1];
  const int b = blockIdx.y;
  const int i0 = blockIdx.x * TI;
  const int wv = threadIdx.x >> 6, lane = threadIdx.x & 63;
  constexpr int OSEG = O / 64;
  constexpr int ROUNDS = TI * OSEG / 4;
  for (int r = 0; r < ROUNDS; ++r) {
    const int item = r * 4 + wv;
    const int il = item / OSEG, os = item - il * OSEG;
    const int i = i0 + il, o = os * 64 + lane;
    const int* ip = idx + (size_t)(b * NPTS + i) * KNN;
    const float zv = z[(size_t)(b * NPTS + i) * O + o];
    float m = -3.4e38f;
    #pragma unroll
    for (int t = 0; t < KNN; ++t) {
      int j = ip[t];
      float v = y[(size_t)(b * NPTS + j) * O + o] + zv;
      m = fmaxf(m, lrelu(v));
    }
    tile[il][o] = m;
  }
  __syncthreads();
  if (xx != nullptr && threadIdx.x < TI) {
    const int il = threadIdx.x;
    float s = 0.f;
    #pragma unroll
    for (int o = 0; o < O; ++o) { float v = tile[il][o]; s = fmaf(v, v, s); }
    xx[b * NPTS + i0 + il] = s;
  }
  for (int e = threadIdx.x; e < TI * O; e += 256) {
    const int o = e / TI, il = e - o * TI;
    outCN[(size_t)b * 512 * NPTS + (size_t)o * NPTS + i0 + il] = tile[il][o];
  }
}

// ---- h12 as edge-GEMM: 4 points/block, 80 edges x 64k x 128out, max over k in-wave ----
__global__ __launch_bounds__(256)
void h12_gemm_kernel(const float* __restrict__ ya, const float* __restrict__ zb,
                     const int* __restrict__ idx, const float* __restrict__ tw2T,
                     float* __restrict__ h2m) {
  __shared__ __align__(16) float h1s[80][68];
  __shared__ __align__(16) float ws[64][128];
  __shared__ __align__(16) float zbs[4][64];
  __shared__ float ot[128][4];
  __shared__ int idxs[4][KNN];
  const int b = blockIdx.y;
  const int i0 = blockIdx.x * 4;
  const int tid = threadIdx.x;

  #pragma unroll
  for (int it = 0; it < 8; ++it) {
    const int f = tid + it * 256;
    *reinterpret_cast<float4*>(&ws[0][0] + f * 4) =
      *reinterpret_cast<const float4*>(tw2T + (size_t)f * 4);
  }
  if (tid < 64) {
    const int p = tid >> 4, cq = (tid & 15) * 4;
    *reinterpret_cast<float4*>(&zbs[p][cq]) =
      *reinterpret_cast<const float4*>(&zb[(size_t)(b * NPTS + i0 + p) * 64 + cq]);
  }
  if (tid >= 64 && tid < 64 + 4 * KNN) {
    const int e = tid - 64;
    idxs[e / KNN][e % KNN] = idx[(size_t)(b * NPTS + i0) * KNN + e];
  }
  __syncthreads();

  #pragma unroll
  for (int it = 0; it < 5; ++it) {
    const int task = tid + it * 256;
    const int e = task >> 4, cq = (task & 15) * 4;
    const int p = e / KNN, t = e - p * KNN;
    const int j = idxs[p][t];
    const float4 yv = *reinterpret_cast<const float4*>(&ya[(size_t)(b * NPTS + j) * 64 + cq]);
    const float4 zv = *reinterpret_cast<const float4*>(&zbs[p][cq]);
    float4 hv;
    hv.x = lrelu(yv.x + zv.x); hv.y = lrelu(yv.y + zv.y);
    hv.z = lrelu(yv.z + zv.z); hv.w = lrelu(yv.w + zv.w);
    *reinterpret_cast<float4*>(&h1s[e][cq]) = hv;
  }
  __syncthreads();

  const int eg = tid >> 4, og = tid & 15;
  float acc[5][8];
  #pragma unroll
  for (int u = 0; u < 5; ++u)
    #pragma unroll
    for (int v = 0; v < 8; ++v) acc[u][v] = 0.f;
  #pragma unroll 4
  for (int kk = 0; kk < 64; ++kk) {
    float hv[5];
    #pragma unroll
    for (int u = 0; u < 5; ++u) hv[u] = h1s[eg * 5 + u][kk];
    const float4 w0 = *reinterpret_cast<const float4*>(&ws[kk][og * 4]);
    const float4 w1 = *reinterpret_cast<const float4*>(&ws[kk][64 + og * 4]);
    const float wr[8] = {w0.x, w0.y, w0.z, w0.w, w1.x, w1.y, w1.z, w1.w};
    #pragma unroll
    for (int u = 0; u < 5; ++u)
      #pragma unroll
      for (int v = 0; v < 8; ++v) acc[u][v] = fmaf(hv[u], wr[v], acc[u][v]);
  }

  const int p = eg >> 2, d = eg & 3;
  float m[8];
  #pragma unroll
  for (int v = 0; v < 8; ++v) {
    float mm = lrelu(acc[0][v]);
    #pragma unroll
    for (int u = 1; u < 5; ++u) mm = fmaxf(mm, lrelu(acc[u][v]));
    mm = fmaxf(mm, __shfl_xor(mm, 16));
    mm = fmaxf(mm, __shfl_xor(mm, 32));
    m[v] = mm;
  }
  if (d == 0) {
    #pragma unroll
    for (int v = 0; v < 8; ++v) {
      const int o = og * 4 + (v & 3) + (v >> 2) * 64;
      ot[o][p] = m[v];
    }
  }
  __syncthreads();
  if (tid < 128) {
    float4 st = make_float4(ot[tid][0], ot[tid][1], ot[tid][2], ot[tid][3]);
    *reinterpret_cast<float4*>(&h2m[(size_t)(b * 128 + tid) * NPTS + i0]) = st;
  }
}

// ---- reduce partial max over nt n-tiles ----
__global__ __launch_bounds__(256)
void reduce_max_kernel(const float* __restrict__ part, float* __restrict__ outp, int nt) {
  const int b = blockIdx.y;
  const int o = blockIdx.x * 256 + threadIdx.x;
  float m = part[(size_t)(b * nt) * 1024 + o];
  for (int t = 1; t < nt; ++t) m = fmaxf(m, part[(size_t)(b * nt + t) * 1024 + o]);
  outp[b * 1024 + o] = m;
}

// ---- block reduce helper ----
__device__ __forceinline__ float block_reduce_sum(float v, float* rbuf) {
  #pragma unroll
  for (int off = 32; off > 0; off >>= 1) v += __shfl_xor(v, off);
  const int w = threadIdx.x >> 6, lane = threadIdx.x & 63;
  const int nw = blockDim.x >> 6;
  if (lane == 0) rbuf[w] = v;
  __syncthreads();
  float tot = 0.f;
  for (int i = 0; i < nw; ++i) tot += rbuf[i];
  __syncthreads();
  return tot;
}

// ---- fc1: l2n -> 1024x512 (no bias) -> LN -> lrelu ----
__global__ __launch_bounds__(256)
void fc1_kernel(const float* __restrict__ gin_g, const float* __restrict__ Wt,
                const float* __restrict__ gam, const float* __restrict__ bet,
                float* __restrict__ outp) {
  __shared__ __align__(16) float gin[1024];
  __shared__ float hbuf[512];
  __shared__ float rbuf[8];
  const int b = blockIdx.x, tid = threadIdx.x;
  for (int e = tid; e < 1024; e += 256) gin[e] = gin_g[b * 1024 + e];
  __syncthreads();
  float ps = 0.f;
  for (int e = tid; e < 1024; e += 256) ps = fmaf(gin[e], gin[e], ps);
  float ss = block_reduce_sum(ps, rbuf);
  float rinv = 1.0f / sqrtf(ss);
  #pragma unroll
  for (int r = 0; r < 2; ++r) {
    int o = tid + r * 256;
    const float* wrow = Wt + (size_t)o * 1024;
    float a = 0.f;
    for (int c4 = 0; c4 < 256; ++c4) {
      float4 wv = *reinterpret_cast<const float4*>(wrow + c4 * 4);
      float4 gv = *reinterpret_cast<const float4*>(&gin[c4 * 4]);
      a = fmaf(wv.x, gv.x, a); a = fmaf(wv.y, gv.y, a);
      a = fmaf(wv.z, gv.z, a); a = fmaf(wv.w, gv.w, a);
    }
    hbuf[o] = a * rinv;
  }
  __syncthreads();
  float pm = hbuf[tid] + hbuf[tid + 256];
  float mean = block_reduce_sum(pm, rbuf) * (1.f / 512.f);
  float d0 = hbuf[tid] - mean, d1 = hbuf[tid + 256] - mean;
  float var = block_reduce_sum(d0 * d0 + d1 * d1, rbuf) * (1.f / 512.f);
  float rs = 1.0f / sqrtf(var + 1e-5f);
  #pragma unroll
  for (int r = 0; r < 2; ++r) {
    int o = tid + r * 256;
    float yv = (hbuf[o] - mean) * rs * gam[o] + bet[o];
    outp[b * 512 + o] = lrelu(yv);
  }
}

// ---- fc2: l2n -> 512x256 (+bias) -> LN -> lrelu ----
__global__ __launch_bounds__(256)
void fc2_kernel(const float* __restrict__ inp, const float* __restrict__ Wt,
                const float* __restrict__ bias, const float* __restrict__ gam,
                const float* __restrict__ bet, float* __restrict__ outp) {
  __shared__ __align__(16) float gin[512];
  __shared__ float rbuf[8];
  const int b = blockIdx.x, tid = threadIdx.x;
  for (int e = tid; e < 512; e += 256) gin[e] = inp[b * 512 + e];
  __syncthreads();
  float ps = 0.f;
  for (int e = tid; e < 512; e += 256) ps = fmaf(gin[e], gin[e], ps);
  float ss = block_reduce_sum(ps, rbuf);
  float rinv = 1.0f / sqrtf(ss);
  const float* wrow = Wt + (size_t)tid * 512;
  float a = 0.f;
  for (int c4 = 0; c4 < 128; ++c4) {
    float4 wv = *reinterpret_cast<const float4*>(wrow + c4 * 4);
    float4 gv = *reinterpret_cast<const float4*>(&gin[c4 * 4]);
    a = fmaf(wv.x, gv.x, a); a = fmaf(wv.y, gv.y, a);
    a = fmaf(wv.z, gv.z, a); a = fmaf(wv.w, gv.w, a);
  }
  a = a * rinv + bias[tid];
  float mean = block_reduce_sum(a, rbuf) * (1.f / 256.f);
  float d = a - mean;
  float var = block_reduce_sum(d * d, rbuf) * (1.f / 256.f);
  float rs = 1.0f / sqrtf(var + 1e-5f);
  float yv = (a - mean) * rs * gam[tid] + bet[tid];
  outp[b * 256 + tid] = lrelu(yv);
}

// ---- fc3 + identity ----
__global__ __launch_bounds__(64)
void fc3_kernel(const float* __restrict__ inp, const float* __restrict__ Wt,
                const float* __restrict__ bias, float* __restrict__ tmat) {
  __shared__ float gin[256];
  const int b = blockIdx.x, tid = threadIdx.x;
  for (int e = tid; e < 256; e += 64) gin[e] = inp[b * 256 + e];
  __syncthreads();
  if (tid < 9) {
    const float* wrow = Wt + tid * 256;
    float a = 0.f;
    for (int c = 0; c < 256; ++c) a = fmaf(wrow[c], gin[c], a);
    a += bias[tid];
    if (tid == 0 || tid == 4 || tid == 8) a += 1.f;
    tmat[b * 9 + tid] = a;
  }
}

// ---- apply 3x3 transform ----
__global__ __launch_bounds__(256)
void xform_kernel(const float* __restrict__ x, const float* __restrict__ tmat,
                  float* __restrict__ xt) {
  const int b = blockIdx.y;
  const int n = blockIdx.x * 256 + threadIdx.x;
  const float* xb = x + (size_t)b * 3 * NPTS;
  const float x0 = xb[n], x1 = xb[NPTS + n], x2 = xb[2 * NPTS + n];
  const float* t = tmat + b * 9;
  float* ob = xt + (size_t)b * 3 * NPTS;
  #pragma unroll
  for (int i = 0; i < 3; ++i)
    ob[i * NPTS + n] = fmaf(t[3 * i], x0, fmaf(t[3 * i + 1], x1, t[3 * i + 2] * x2));
}

extern "C" void kernel_launch(void* const* d_in, const int* in_sizes, int n_in,
                              void* d_out, int out_size, void* d_ws, size_t ws_size,
                              hipStream_t stream) {
  (void)in_sizes; (void)n_in; (void)out_size; (void)ws_size;
  const float* x       = (const float*)d_in[0];
  const float* tw1     = (const float*)d_in[1];
  const float* tw2     = (const float*)d_in[2];
  const float* tw3     = (const float*)d_in[3];
  const float* tfc1_w  = (const float*)d_in[4];
  const float* tfc1_g  = (const float*)d_in[5];
  const float* tfc1_b  = (const float*)d_in[6];
  const float* tfc2_w  = (const float*)d_in[7];
  const float* tfc2_bias = (const float*)d_in[8];
  const float* tfc2_g  = (const float*)d_in[9];
  const float* tfc2_b  = (const float*)d_in[10];
  const float* tfc3_w  = (const float*)d_in[11];
  const float* tfc3_b  = (const float*)d_in[12];
  const float* w1      = (const float*)d_in[13];
  const float* w2      = (const float*)d_in[14];
  const float* w3      = (const float*)d_in[15];
  const float* w4      = (const float*)d_in[16];
  const float* w5      = (const float*)d_in[17];
  float* out = (float*)d_out;

  char* wsb = (char*)d_ws;
  size_t off = 0;
  auto alloc = [&](size_t bytes) -> void* {
    void* p = wsb + off;
    off += (bytes + 255) & ~(size_t)255;
    return p;
  };
  float* ybuf = (float*)alloc((size_t)BATCH * NPTS * 256 * 4);
  float* zbuf = (float*)alloc((size_t)BATCH * NPTS * 256 * 4);
  float* xcT  = (float*)alloc((size_t)BATCH * 512 * NPTS * 4);   // channel-major x1..x4
  float* h2m  = (float*)alloc((size_t)BATCH * 128 * NPTS * 4);   // channel-major
  float* part = (float*)alloc((size_t)BATCH * 16 * 1024 * 4);
  int*   idxb = (int*)alloc((size_t)BATCH * NPTS * KNN * 4);
  float* xxb  = (float*)alloc((size_t)BATCH * NPTS * 4);
  float* xt   = (float*)alloc((size_t)BATCH * 3 * NPTS * 4);
  float* gbuf = (float*)alloc((size_t)BATCH * 1024 * 4);
  float* f1o  = (float*)alloc((size_t)BATCH * 512 * 4);
  float* f2o  = (float*)alloc((size_t)BATCH * 256 * 4);
  float* tmat = (float*)alloc((size_t)BATCH * 9 * 4);
  float* tw1aT = (float*)alloc(3 * 64 * 4);
  float* tw1dT = (float*)alloc(3 * 64 * 4);
  float* w1aT  = (float*)alloc(3 * 64 * 4);
  float* w1dT  = (float*)alloc(3 * 64 * 4);
  float* w2aT  = (float*)alloc(64 * 64 * 4);
  float* w2dT  = (float*)alloc(64 * 64 * 4);
  float* w3aT  = (float*)alloc(64 * 128 * 4);
  float* w3dT  = (float*)alloc(64 * 128 * 4);
  float* w4aT  = (float*)alloc(128 * 256 * 4);
  float* w4dT  = (float*)alloc(128 * 256 * 4);
  float* tw2T  = (float*)alloc(64 * 128 * 4);
  float* tw3T  = (float*)alloc(128 * 1024 * 4);
  float* w5T   = (float*)alloc(512 * 1024 * 4);

  // weight prep
  wsplit_t_kernel<<<1, 256, 0, stream>>>(tw1, tw1aT, tw1dT, 64, 3);
  wsplit_t_kernel<<<1, 256, 0, stream>>>(w1, w1aT, w1dT, 64, 3);
  wsplit_t_kernel<<<16, 256, 0, stream>>>(w2, w2aT, w2dT, 64, 64);
  wsplit_t_kernel<<<32, 256, 0, stream>>>(w3, w3aT, w3dT, 128, 64);
  wsplit_t_kernel<<<128, 256, 0, stream>>>(w4, w4aT, w4dT, 256, 128);
  wtrans_kernel<<<32, 256, 0, stream>>>(tw2, tw2T, 128, 64);
  wtrans_kernel<<<512, 256, 0, stream>>>(tw3, tw3T, 1024, 128);
  wtrans_kernel<<<2048, 256, 0, stream>>>(w5, w5T, 1024, 512);

  // ---- transform net ----
  xx3_kernel<<<dim3(4, 16), 256, 0, stream>>>(x, xxb);
  knn_cn_kernel<3><<<dim3(128, 16), 256, 0, stream>>>(x, 3 * NPTS, xxb, idxb);
  gemm_kernel<<<dim3(16, 1, 16), 256, 0, stream>>>(x, 3 * NPTS, 1, NPTS, tw1aT, 64, 3,
                                                   ybuf, NPTS * 64, 64);
  gemm_kernel<<<dim3(16, 1, 16), 256, 0, stream>>>(x, 3 * NPTS, 1, NPTS, tw1dT, 64, 3,
                                                   zbuf, NPTS * 64, 64);
  h12_gemm_kernel<<<dim3(256, 16), 256, 0, stream>>>(ybuf, zbuf, idxb, tw2T, h2m);
  gemm128_kernel<1><<<dim3(8, 8, 16), 256, 0, stream>>>(h2m, 128 * NPTS, NPTS, tw3T, 1024, 128,
                                                        part, 8 * 1024, 0, 1024);
  reduce_max_kernel<<<dim3(4, 16), 256, 0, stream>>>(part, gbuf, 8);
  fc1_kernel<<<16, 256, 0, stream>>>(gbuf, tfc1_w, tfc1_g, tfc1_b, f1o);
  fc2_kernel<<<16, 256, 0, stream>>>(f1o, tfc2_w, tfc2_bias, tfc2_g, tfc2_b, f2o);
  fc3_kernel<<<16, 64, 0, stream>>>(f2o, tfc3_w, tfc3_b, tmat);
  xform_kernel<<<dim3(4, 16), 256, 0, stream>>>(x, tmat, xt);

  // ---- EdgeConv 1 (C=3 -> O=64) on xt ----
  xx3_kernel<<<dim3(4, 16), 256, 0, stream>>>(xt, xxb);
  knn_cn_kernel<3><<<dim3(128, 16), 256, 0, stream>>>(xt, 3 * NPTS, xxb, idxb);
  gemm_kernel<<<dim3(16, 1, 16), 256, 0, stream>>>(xt, 3 * NPTS, 1, NPTS, w1aT, 64, 3,
                                                   ybuf, NPTS * 64, 64);
  gemm_kernel<<<dim3(16, 1, 16), 256, 0, stream>>>(xt, 3 * NPTS, 1, NPTS, w1dT, 64, 3,
                                                   zbuf, NPTS * 64, 64);
  edge_max_cn_kernel<64, 64><<<dim3(16, 16), 256, 0, stream>>>(ybuf, zbuf, idxb, xcT, xxb);

  // ---- EdgeConv 2 (C=64 -> O=64), input xcT ch 0..63 ----
  knn_cn_kernel<64><<<dim3(128, 16), 256, 0, stream>>>(xcT, 512 * NPTS, xxb, idxb);
  gemm_kernel<<<dim3(16, 1, 16), 256, 0, stream>>>(xcT, 512 * NPTS, 1, NPTS, w2aT, 64, 64,
                                                   ybuf, NPTS * 64, 64);
  gemm_kernel<<<dim3(16, 1, 16), 256, 0, stream>>>(xcT, 512 * NPTS, 1, NPTS, w2dT, 64, 64,
                                                   zbuf, NPTS * 64, 64);
  edge_max_cn_kernel<64, 64><<<dim3(16, 16), 256, 0, stream>>>(ybuf, zbuf, idxb,
                                                               xcT + 64 * NPTS, xxb);

  // ---- EdgeConv 3 (C=64 -> O=128), input xcT ch 64..127 ----
  knn_cn_kernel<64><<<dim3(128, 16), 256, 0, stream>>>(xcT + 64 * NPTS, 512 * NPTS, xxb, idxb);
  gemm_kernel<<<dim3(16, 2, 16), 256, 0, stream>>>(xcT + 64 * NPTS, 512 * NPTS, 1, NPTS,
                                                   w3aT, 128, 64, ybuf, NPTS * 128, 128);
  gemm_kernel<<<dim3(16, 2, 16), 256, 0, stream>>>(xcT + 64 * NPTS, 512 * NPTS, 1, NPTS,
                                                   w3dT, 128, 64, zbuf, NPTS * 128, 128);
  edge_max_cn_kernel<128, 64><<<dim3(16, 16), 256, 0, stream>>>(ybuf, zbuf, idxb,
                                                                xcT + 128 * NPTS, xxb);

  // ---- EdgeConv 4 (C=128 -> O=256), input xcT ch 128..255 ----
  knn_cn_kernel<128><<<dim3(128, 16), 256, 0, stream>>>(xcT + 128 * NPTS, 512 * NPTS, xxb, idxb);
  gemm128_kernel<0><<<dim3(8, 2, 16), 256, 0, stream>>>(xcT + 128 * NPTS, 512 * NPTS, NPTS,
                                                        w4aT, 256, 128, ybuf, NPTS * 256, 256, 0);
  gemm128_kernel<0><<<dim3(8, 2, 16), 256, 0, stream>>>(xcT + 128 * NPTS, 512 * NPTS, NPTS,
                                                        w4dT, 256, 128, zbuf, NPTS * 256, 256, 0);
  edge_max_cn_kernel<256, 32><<<dim3(32, 16), 256, 0, stream>>>(ybuf, zbuf, idxb,
                                                                xcT + 256 * NPTS, nullptr);

  // ---- final: x5 = lrelu(w5 @ xc) with max over n ----
  gemm128_kernel<1><<<dim3(8, 8, 16), 256, 0, stream>>>(xcT, 512 * NPTS, NPTS, w5T, 1024, 512,
                                                        part, 8 * 1024, 0, 1024);
  reduce_max_kernel<<<dim3(4, 16), 256, 0, stream>>>(part, out, 8);
}

// Round 7
// 941.471 us; speedup vs baseline: 4.3208x; 1.1303x over previous
//
#include <hip/hip_runtime.h>
#include <math.h>

#define BATCH 16
#define NPTS 1024
#define KNN 20

__device__ __forceinline__ float lrelu(float v) { return v >= 0.f ? v : 0.2f * v; }

typedef __attribute__((ext_vector_type(8))) short bf16x8;
typedef __attribute__((ext_vector_type(4))) float f32x4;

__device__ __forceinline__ ushort f2bf(float f) {
  union { float f; unsigned u; } v; v.f = f;
  unsigned r = (v.u + 0x7FFFu + ((v.u >> 16) & 1u)) >> 16;  // RNE
  return (ushort)r;
}

// ---- weight prep: W[O][2C] -> WaT[C][O] fp32 ; WdT[C][O] fp32 (for fp32 gemms) ----
__global__ __launch_bounds__(256)
void wsplit_t_kernel(const float* __restrict__ W, float* __restrict__ waT,
                     float* __restrict__ wdT, int O, int Cc) {
  int e = blockIdx.x * 256 + threadIdx.x;
  if (e < O * Cc) {
    int c = e / O, o = e - c * O;
    float a = W[o * 2 * Cc + c], bb = W[o * 2 * Cc + Cc + c];
    waT[e] = a; wdT[e] = bb - a;
  }
}

// ---- weight prep bf16, NON-transposed [o][c]: wa_bf = W[:, :C]; wd_bf = W[:,C:]-W[:,:C] ----
__global__ __launch_bounds__(256)
void wsplit_bf_kernel(const float* __restrict__ W, ushort* __restrict__ wa_bf,
                      ushort* __restrict__ wd_bf, int O, int Cc) {
  int e = blockIdx.x * 256 + threadIdx.x;
  if (e < O * Cc) {
    int o = e / Cc, c = e - o * Cc;
    float a = W[o * 2 * Cc + c], bb = W[o * 2 * Cc + Cc + c];
    wa_bf[e] = f2bf(a); wd_bf[e] = f2bf(bb - a);
  }
}

// ---- fp32 -> bf16 elementwise ----
__global__ __launch_bounds__(256)
void cvt_bf16_kernel(const float* __restrict__ in, ushort* __restrict__ outp, int n) {
  int e = blockIdx.x * 256 + threadIdx.x;
  if (e < n) outp[e] = f2bf(in[e]);
}

// ---- weight transpose: W[O][C] -> wT[C][O] ----
__global__ __launch_bounds__(256)
void wtrans_kernel(const float* __restrict__ W, float* __restrict__ wT, int O, int Cc) {
  int e = blockIdx.x * 256 + threadIdx.x;
  if (e < O * Cc) {
    int c = e / O, o = e - c * O;
    wT[e] = W[(size_t)o * Cc + c];
  }
}

// ---- xx[b][n] = sum_c x[b][c][n]^2 for C=3 CN input ----
__global__ __launch_bounds__(256)
void xx3_kernel(const float* __restrict__ x, float* __restrict__ xx) {
  const int b = blockIdx.y;
  const int n = blockIdx.x * 256 + threadIdx.x;
  const float* xb = x + (size_t)b * 3 * NPTS;
  float a = xb[n], bb = xb[NPTS + n], c = xb[2 * NPTS + n];
  xx[b * NPTS + n] = a * a + bb * bb + c * c;
}

// ---- knn on channel-major features ----
template<int C>
__global__ __launch_bounds__(256)
void knn_cn_kernel(const float* __restrict__ Xt, long sb,
                   const float* __restrict__ xx, int* __restrict__ idxout) {
  __shared__ float sc[8][NPTS];   // 32 KB
  const int b = blockIdx.y, i0 = blockIdx.x * 8;
  const int tid = threadIdx.x;
  const float* Xb = Xt + (size_t)b * sb;
  const int j0 = tid * 4;
  float acc[8][4];
  #pragma unroll
  for (int q = 0; q < 8; ++q)
    #pragma unroll
    for (int u = 0; u < 4; ++u) acc[q][u] = 0.f;
  for (int c = 0; c < C; ++c) {
    const float4 xv = *reinterpret_cast<const float4*>(Xb + (size_t)c * NPTS + j0);
    const float* xr = Xb + (size_t)c * NPTS + i0;
    #pragma unroll
    for (int q = 0; q < 8; ++q) {
      const float xiq = xr[q];
      acc[q][0] = fmaf(xiq, xv.x, acc[q][0]);
      acc[q][1] = fmaf(xiq, xv.y, acc[q][1]);
      acc[q][2] = fmaf(xiq, xv.z, acc[q][2]);
      acc[q][3] = fmaf(xiq, xv.w, acc[q][3]);
    }
  }
  const float4 xxj = *reinterpret_cast<const float4*>(xx + b * NPTS + j0);
  #pragma unroll
  for (int q = 0; q < 8; ++q) {
    float4 st;
    st.x = fmaf(-2.f, acc[q][0], xxj.x);
    st.y = fmaf(-2.f, acc[q][1], xxj.y);
    st.z = fmaf(-2.f, acc[q][2], xxj.z);
    st.w = fmaf(-2.f, acc[q][3], xxj.w);
    *reinterpret_cast<float4*>(&sc[q][j0]) = st;
  }
  __syncthreads();

  const int wv = tid >> 6, lane = tid & 63;
  const int q0 = wv * 2, q1 = q0 + 1;
  float v0[16], v1[16];
  #pragma unroll
  for (int s = 0; s < 16; ++s) {
    v0[s] = sc[q0][lane + 64 * s];
    v1[s] = sc[q1][lane + 64 * s];
  }
  int my0 = 0, my1 = 0;
  for (int t = 0; t < KNN; ++t) {
    float bv0 = v0[0], bv1 = v1[0];
    int bs0 = 0, bs1 = 0;
    #pragma unroll
    for (int s = 1; s < 16; ++s) {
      if (v0[s] < bv0) { bv0 = v0[s]; bs0 = s; }
      if (v1[s] < bv1) { bv1 = v1[s]; bs1 = s; }
    }
    int bj0 = lane + (bs0 << 6), bj1 = lane + (bs1 << 6);
    #pragma unroll
    for (int off = 32; off > 0; off >>= 1) {
      const float ov0 = __shfl_xor(bv0, off); const int oj0 = __shfl_xor(bj0, off);
      const float ov1 = __shfl_xor(bv1, off); const int oj1 = __shfl_xor(bj1, off);
      const bool c0 = (ov0 < bv0) || (ov0 == bv0 && oj0 < bj0);
      const bool c1 = (ov1 < bv1) || (ov1 == bv1 && oj1 < bj1);
      bv0 = c0 ? ov0 : bv0; bj0 = c0 ? oj0 : bj0;
      bv1 = c1 ? ov1 : bv1; bj1 = c1 ? oj1 : bj1;
    }
    if (lane == t) { my0 = bj0; my1 = bj1; }
    const int ks0 = bj0 - lane, ks1 = bj1 - lane;
    #pragma unroll
    for (int s = 0; s < 16; ++s) {
      if (ks0 == (s << 6)) v0[s] = 3.4e38f;
      if (ks1 == (s << 6)) v1[s] = 3.4e38f;
    }
  }
  if (lane < KNN) {
    idxout[(size_t)(b * NPTS + i0 + q0) * KNN + lane] = my0;
    idxout[(size_t)(b * NPTS + i0 + q1) * KNN + lane] = my1;
  }
}

// ---- 64-tile fp32 GEMM (small conv layers feeding knn paths) ----
__global__ __launch_bounds__(256)
void gemm_kernel(const float* __restrict__ X, long sxb, int sxn, int sxc,
                 const float* __restrict__ WT, int ldW, int C,
                 float* __restrict__ out, int sob, int son) {
  __shared__ __align__(16) float Xs[16][64];
  __shared__ __align__(16) float Ws[16][64];
  const int b = blockIdx.z;
  const int n0 = blockIdx.x * 64, o0 = blockIdx.y * 64;
  const int tid = threadIdx.x;
  const int lr = tid & 63;
  const int c4 = (tid >> 6) * 4;
  const int tn = tid & 15, to = tid >> 4;
  float acc[4][4];
  #pragma unroll
  for (int i = 0; i < 4; ++i)
    #pragma unroll
    for (int j = 0; j < 4; ++j) acc[i][j] = 0.f;

  const size_t xbase = (size_t)b * sxb;
  for (int k0 = 0; k0 < C; k0 += 16) {
    #pragma unroll
    for (int u = 0; u < 4; ++u) {
      int c = k0 + c4 + u;
      float xv = 0.f, wv = 0.f;
      if (c < C) {
        xv = X[xbase + (size_t)(n0 + lr) * sxn + (size_t)c * sxc];
        wv = WT[(size_t)c * ldW + o0 + lr];
      }
      Xs[c4 + u][lr] = xv;
      Ws[c4 + u][lr] = wv;
    }
    __syncthreads();
    #pragma unroll
    for (int kk = 0; kk < 16; ++kk) {
      const float4 xa = *reinterpret_cast<const float4*>(&Xs[kk][tn * 4]);
      const float4 wb = *reinterpret_cast<const float4*>(&Ws[kk][to * 4]);
      const float xr[4] = {xa.x, xa.y, xa.z, xa.w};
      const float wr[4] = {wb.x, wb.y, wb.z, wb.w};
      #pragma unroll
      for (int i = 0; i < 4; ++i)
        #pragma unroll
        for (int j = 0; j < 4; ++j) acc[i][j] = fmaf(xr[i], wr[j], acc[i][j]);
    }
    __syncthreads();
  }
  #pragma unroll
  for (int i = 0; i < 4; ++i) {
    float4 st = make_float4(acc[i][0], acc[i][1], acc[i][2], acc[i][3]);
    *reinterpret_cast<float4*>(&out[(size_t)b * sob + (size_t)(n0 + tn * 4 + i) * son + o0 + to * 4]) = st;
  }
}

// ---- 128x128 fp32 GEMM (tw3 path only; X channel-major) ----
template<int EPI>
__global__ __launch_bounds__(256)
void gemm128_kernel(const float* __restrict__ X, long sxb, int scN,
                    const float* __restrict__ WT, int ldW, int C,
                    float* __restrict__ out, int sob, int son, int snb) {
  __shared__ __align__(16) float Xs[16][128];
  __shared__ __align__(16) float Ws[16][128];
  __shared__ __align__(16) float red[16][132];
  const int b = blockIdx.z;
  const int n0 = blockIdx.x * 128, o0 = blockIdx.y * 128;
  const int tid = threadIdx.x;
  const int tn = tid & 15, to = tid >> 4;
  float acc[8][8];
  #pragma unroll
  for (int i = 0; i < 8; ++i)
    #pragma unroll
    for (int j = 0; j < 8; ++j) acc[i][j] = 0.f;

  const size_t xbase = (size_t)b * sxb;
  for (int c0 = 0; c0 < C; c0 += 16) {
    #pragma unroll
    for (int it = 0; it < 2; ++it) {
      const int task = tid + it * 256;
      const int kk = task >> 5, n4 = (task & 31) * 4;
      *reinterpret_cast<float4*>(&Xs[kk][n4]) =
        *reinterpret_cast<const float4*>(&X[xbase + (size_t)(c0 + kk) * scN + n0 + n4]);
      *reinterpret_cast<float4*>(&Ws[kk][n4]) =
        *reinterpret_cast<const float4*>(&WT[(size_t)(c0 + kk) * ldW + o0 + n4]);
    }
    __syncthreads();
    #pragma unroll
    for (int kk = 0; kk < 16; ++kk) {
      const float4 xa0 = *reinterpret_cast<const float4*>(&Xs[kk][tn * 4]);
      const float4 xa1 = *reinterpret_cast<const float4*>(&Xs[kk][64 + tn * 4]);
      const float4 wb0 = *reinterpret_cast<const float4*>(&Ws[kk][to * 4]);
      const float4 wb1 = *reinterpret_cast<const float4*>(&Ws[kk][64 + to * 4]);
      const float xr[8] = {xa0.x, xa0.y, xa0.z, xa0.w, xa1.x, xa1.y, xa1.z, xa1.w};
      const float wr[8] = {wb0.x, wb0.y, wb0.z, wb0.w, wb1.x, wb1.y, wb1.z, wb1.w};
      #pragma unroll
      for (int i = 0; i < 8; ++i)
        #pragma unroll
        for (int j = 0; j < 8; ++j) acc[i][j] = fmaf(xr[i], wr[j], acc[i][j]);
    }
    __syncthreads();
  }

  if (EPI == 0) {
    #pragma unroll
    for (int i = 0; i < 8; ++i) {
      const int n = n0 + (i >> 2) * 64 + tn * 4 + (i & 3);
      float4 s0 = make_float4(acc[i][0], acc[i][1], acc[i][2], acc[i][3]);
      float4 s1 = make_float4(acc[i][4], acc[i][5], acc[i][6], acc[i][7]);
      *reinterpret_cast<float4*>(&out[(size_t)b * sob + (size_t)n * son + o0 + to * 4]) = s0;
      *reinterpret_cast<float4*>(&out[(size_t)b * sob + (size_t)n * son + o0 + 64 + to * 4]) = s1;
    }
  } else {
    #pragma unroll
    for (int j = 0; j < 8; ++j) {
      float m = lrelu(acc[0][j]);
      #pragma unroll
      for (int i = 1; i < 8; ++i) m = fmaxf(m, lrelu(acc[i][j]));
      red[tn][(j >> 2) * 64 + to * 4 + (j & 3)] = m;
    }
    __syncthreads();
    if (tid < 128) {
      float m = red[0][tid];
      #pragma unroll
      for (int t = 1; t < 16; ++t) m = fmaxf(m, red[t][tid]);
      out[(size_t)b * sob + (size_t)blockIdx.x * snb + o0 + tid] = m;
    }
  }
}

// ---- bf16 MFMA GEMM: out[b][n][o] = sum_k X[n][k]*W[o][k] (X,W bf16 K-contiguous) ----
// 128x128 tile, 4 waves (2x2), BK=64, XOR-swizzled LDS (byte ^= (row&7)<<4).
// A-frag: row=lane&15, k=8*(lane>>4)+j. C/D: col=lane&15, row=4*(lane>>4)+reg.
// EPI=0: fp32 NC store; EPI=1: lrelu + max over tile n -> part[b][bx][o]
template<int EPI>
__global__ __launch_bounds__(256)
void gemm_mfma_kernel(const ushort* __restrict__ Xg, long sxb, int ldX,
                      const ushort* __restrict__ Wg, int ldW, int K,
                      float* __restrict__ out, long sob, int son, int snb) {
  __shared__ __align__(16) ushort As[128 * 64];
  __shared__ __align__(16) ushort Bs[128 * 64];
  __shared__ float red[2][128];
  const int b = blockIdx.z;
  const int n0 = blockIdx.x * 128, o0 = blockIdx.y * 128;
  const int tid = threadIdx.x;
  const int lane = tid & 63;
  const int wrow = (tid >> 6) >> 1, wcol = (tid >> 6) & 1;
  f32x4 acc[4][4];
  #pragma unroll
  for (int i = 0; i < 4; ++i)
    #pragma unroll
    for (int j = 0; j < 4; ++j)
      #pragma unroll
      for (int r = 0; r < 4; ++r) acc[i][j][r] = 0.f;

  const ushort* Xb = Xg + (size_t)b * sxb;
  for (int kb = 0; kb < K; kb += 64) {
    #pragma unroll
    for (int i = 0; i < 4; ++i) {
      const int idx = i * 256 + tid;
      const int n = idx >> 3, kc = idx & 7;
      const bf16x8 xv = *reinterpret_cast<const bf16x8*>(&Xb[(size_t)(n0 + n) * ldX + kb + kc * 8]);
      const bf16x8 wv = *reinterpret_cast<const bf16x8*>(&Wg[(size_t)(o0 + n) * ldW + kb + kc * 8]);
      const int ad = n * 128 + ((kc * 16) ^ ((n & 7) << 4));
      *reinterpret_cast<bf16x8*>((char*)As + ad) = xv;
      *reinterpret_cast<bf16x8*>((char*)Bs + ad) = wv;
    }
    __syncthreads();
    #pragma unroll
    for (int s = 0; s < 2; ++s) {
      bf16x8 af[4], bfr[4];
      const int klane = (s * 64 + ((lane >> 4) << 4));
      #pragma unroll
      for (int f = 0; f < 4; ++f) {
        const int nl = wrow * 64 + f * 16 + (lane & 15);
        af[f] = *reinterpret_cast<const bf16x8*>((char*)As + nl * 128 + (klane ^ ((nl & 7) << 4)));
        const int ol = wcol * 64 + f * 16 + (lane & 15);
        bfr[f] = *reinterpret_cast<const bf16x8*>((char*)Bs + ol * 128 + (klane ^ ((ol & 7) << 4)));
      }
      #pragma unroll
      for (int i = 0; i < 4; ++i)
        #pragma unroll
        for (int j = 0; j < 4; ++j)
          acc[i][j] = __builtin_amdgcn_mfma_f32_16x16x32_bf16(af[i], bfr[j], acc[i][j], 0, 0, 0);
    }
    __syncthreads();
  }

  if (EPI == 0) {
    #pragma unroll
    for (int i = 0; i < 4; ++i)
      #pragma unroll
      for (int r = 0; r < 4; ++r) {
        const int n = n0 + wrow * 64 + i * 16 + ((lane >> 4) << 2) + r;
        #pragma unroll
        for (int j = 0; j < 4; ++j) {
          const int o = o0 + wcol * 64 + j * 16 + (lane & 15);
          out[(size_t)b * sob + (size_t)n * son + o] = acc[i][j][r];
        }
      }
  } else {
    #pragma unroll
    for (int j = 0; j < 4; ++j) {
      float m = -3.4e38f;
      #pragma unroll
      for (int i = 0; i < 4; ++i)
        #pragma unroll
        for (int r = 0; r < 4; ++r) m = fmaxf(m, lrelu(acc[i][j][r]));
      m = fmaxf(m, __shfl_xor(m, 16));
      m = fmaxf(m, __shfl_xor(m, 32));
      if (lane < 16) red[wrow][wcol * 64 + j * 16 + lane] = m;
    }
    __syncthreads();
    if (tid < 128) {
      float m = fmaxf(red[0][tid], red[1][tid]);
      out[(size_t)b * sob + (size_t)blockIdx.x * snb + o0 + tid] = m;
    }
  }
}

// ---- edge max, channel-major fp32 output + NC bf16 copy for MFMA consumers ----
template<int O, int TI>
__global__ __launch_bounds__(256)
void edge_max_cn_kernel(const float* __restrict__ y, const float* __restrict__ z,
                        const int* __restrict__ idx, float* __restrict__ outCN,
                        float* __restrict__ xx, ushort* __restrict__ xbf, int choff) {
  __shared__ float tile[TI][O + 1];
  const int b = blockIdx.y;
  const int i0 = blockIdx.x * TI;
  const int wv = threadIdx.x >> 6, lane = threadIdx.x & 63;
  constexpr int OSEG = O / 64;
  constexpr int ROUNDS = TI * OSEG / 4;
  for (int r = 0; r < ROUNDS; ++r) {
    const int item = r * 4 + wv;
    const int il = item / OSEG, os = item - il * OSEG;
    const int i = i0 + il, o = os * 64 + lane;
    const int* ip = idx + (size_t)(b * NPTS + i) * KNN;
    const float zv = z[(size_t)(b * NPTS + i) * O + o];
    float m = -3.4e38f;
    #pragma unroll
    for (int t = 0; t < KNN; ++t) {
      int j = ip[t];
      float v = y[(size_t)(b * NPTS + j) * O + o] + zv;
      m = fmaxf(m, lrelu(v));
    }
    tile[il][o] = m;
    xbf[(size_t)(b * NPTS + i) * 512 + choff + o] = f2bf(m);
  }
  __syncthreads();
  if (xx != nullptr && threadIdx.x < TI) {
    const int il = threadIdx.x;
    float s = 0.f;
    #pragma unroll
    for (int o = 0; o < O; ++o) { float v = tile[il][o]; s = fmaf(v, v, s); }
    xx[b * NPTS + i0 + il] = s;
  }
  for (int e = threadIdx.x; e < TI * O; e += 256) {
    const int o = e / TI, il = e - o * TI;
    outCN[(size_t)b * 512 * NPTS + (size_t)o * NPTS + i0 + il] = tile[il][o];
  }
}

// ---- h12 as edge-GEMM ----
__global__ __launch_bounds__(256)
void h12_gemm_kernel(const float* __restrict__ ya, const float* __restrict__ zb,
                     const int* __restrict__ idx, const float* __restrict__ tw2T,
                     float* __restrict__ h2m) {
  __shared__ __align__(16) float h1s[80][68];
  __shared__ __align__(16) float ws[64][128];
  __shared__ __align__(16) float zbs[4][64];
  __shared__ float ot[128][4];
  __shared__ int idxs[4][KNN];
  const int b = blockIdx.y;
  const int i0 = blockIdx.x * 4;
  const int tid = threadIdx.x;

  #pragma unroll
  for (int it = 0; it < 8; ++it) {
    const int f = tid + it * 256;
    *reinterpret_cast<float4*>(&ws[0][0] + f * 4) =
      *reinterpret_cast<const float4*>(tw2T + (size_t)f * 4);
  }
  if (tid < 64) {
    const int p = tid >> 4, cq = (tid & 15) * 4;
    *reinterpret_cast<float4*>(&zbs[p][cq]) =
      *reinterpret_cast<const float4*>(&zb[(size_t)(b * NPTS + i0 + p) * 64 + cq]);
  }
  if (tid >= 64 && tid < 64 + 4 * KNN) {
    const int e = tid - 64;
    idxs[e / KNN][e % KNN] = idx[(size_t)(b * NPTS + i0) * KNN + e];
  }
  __syncthreads();

  #pragma unroll
  for (int it = 0; it < 5; ++it) {
    const int task = tid + it * 256;
    const int e = task >> 4, cq = (task & 15) * 4;
    const int p = e / KNN, t = e - p * KNN;
    const int j = idxs[p][t];
    const float4 yv = *reinterpret_cast<const float4*>(&ya[(size_t)(b * NPTS + j) * 64 + cq]);
    const float4 zv = *reinterpret_cast<const float4*>(&zbs[p][cq]);
    float4 hv;
    hv.x = lrelu(yv.x + zv.x); hv.y = lrelu(yv.y + zv.y);
    hv.z = lrelu(yv.z + zv.z); hv.w = lrelu(yv.w + zv.w);
    *reinterpret_cast<float4*>(&h1s[e][cq]) = hv;
  }
  __syncthreads();

  const int eg = tid >> 4, og = tid & 15;
  float acc[5][8];
  #pragma unroll
  for (int u = 0; u < 5; ++u)
    #pragma unroll
    for (int v = 0; v < 8; ++v) acc[u][v] = 0.f;
  #pragma unroll 4
  for (int kk = 0; kk < 64; ++kk) {
    float hv[5];
    #pragma unroll
    for (int u = 0; u < 5; ++u) hv[u] = h1s[eg * 5 + u][kk];
    const float4 w0 = *reinterpret_cast<const float4*>(&ws[kk][og * 4]);
    const float4 w1 = *reinterpret_cast<const float4*>(&ws[kk][64 + og * 4]);
    const float wr[8] = {w0.x, w0.y, w0.z, w0.w, w1.x, w1.y, w1.z, w1.w};
    #pragma unroll
    for (int u = 0; u < 5; ++u)
      #pragma unroll
      for (int v = 0; v < 8; ++v) acc[u][v] = fmaf(hv[u], wr[v], acc[u][v]);
  }

  const int p = eg >> 2, d = eg & 3;
  float m[8];
  #pragma unroll
  for (int v = 0; v < 8; ++v) {
    float mm = lrelu(acc[0][v]);
    #pragma unroll
    for (int u = 1; u < 5; ++u) mm = fmaxf(mm, lrelu(acc[u][v]));
    mm = fmaxf(mm, __shfl_xor(mm, 16));
    mm = fmaxf(mm, __shfl_xor(mm, 32));
    m[v] = mm;
  }
  if (d == 0) {
    #pragma unroll
    for (int v = 0; v < 8; ++v) {
      const int o = og * 4 + (v & 3) + (v >> 2) * 64;
      ot[o][p] = m[v];
    }
  }
  __syncthreads();
  if (tid < 128) {
    float4 st = make_float4(ot[tid][0], ot[tid][1], ot[tid][2], ot[tid][3]);
    *reinterpret_cast<float4*>(&h2m[(size_t)(b * 128 + tid) * NPTS + i0]) = st;
  }
}

// ---- reduce partial max over nt n-tiles ----
__global__ __launch_bounds__(256)
void reduce_max_kernel(const float* __restrict__ part, float* __restrict__ outp, int nt) {
  const int b = blockIdx.y;
  const int o = blockIdx.x * 256 + threadIdx.x;
  float m = part[(size_t)(b * nt) * 1024 + o];
  for (int t = 1; t < nt; ++t) m = fmaxf(m, part[(size_t)(b * nt + t) * 1024 + o]);
  outp[b * 1024 + o] = m;
}

// ---- block reduce helper ----
__device__ __forceinline__ float block_reduce_sum(float v, float* rbuf) {
  #pragma unroll
  for (int off = 32; off > 0; off >>= 1) v += __shfl_xor(v, off);
  const int w = threadIdx.x >> 6, lane = threadIdx.x & 63;
  const int nw = blockDim.x >> 6;
  if (lane == 0) rbuf[w] = v;
  __syncthreads();
  float tot = 0.f;
  for (int i = 0; i < nw; ++i) tot += rbuf[i];
  __syncthreads();
  return tot;
}

// ---- fc1 ----
__global__ __launch_bounds__(256)
void fc1_kernel(const float* __restrict__ gin_g, const float* __restrict__ Wt,
                const float* __restrict__ gam, const float* __restrict__ bet,
                float* __restrict__ outp) {
  __shared__ __align__(16) float gin[1024];
  __shared__ float hbuf[512];
  __shared__ float rbuf[8];
  const int b = blockIdx.x, tid = threadIdx.x;
  for (int e = tid; e < 1024; e += 256) gin[e] = gin_g[b * 1024 + e];
  __syncthreads();
  float ps = 0.f;
  for (int e = tid; e < 1024; e += 256) ps = fmaf(gin[e], gin[e], ps);
  float ss = block_reduce_sum(ps, rbuf);
  float rinv = 1.0f / sqrtf(ss);
  #pragma unroll
  for (int r = 0; r < 2; ++r) {
    int o = tid + r * 256;
    const float* wrow = Wt + (size_t)o * 1024;
    float a = 0.f;
    for (int c4 = 0; c4 < 256; ++c4) {
      float4 wv = *reinterpret_cast<const float4*>(wrow + c4 * 4);
      float4 gv = *reinterpret_cast<const float4*>(&gin[c4 * 4]);
      a = fmaf(wv.x, gv.x, a); a = fmaf(wv.y, gv.y, a);
      a = fmaf(wv.z, gv.z, a); a = fmaf(wv.w, gv.w, a);
    }
    hbuf[o] = a * rinv;
  }
  __syncthreads();
  float pm = hbuf[tid] + hbuf[tid + 256];
  float mean = block_reduce_sum(pm, rbuf) * (1.f / 512.f);
  float d0 = hbuf[tid] - mean, d1 = hbuf[tid + 256] - mean;
  float var = block_reduce_sum(d0 * d0 + d1 * d1, rbuf) * (1.f / 512.f);
  float rs = 1.0f / sqrtf(var + 1e-5f);
  #pragma unroll
  for (int r = 0; r < 2; ++r) {
    int o = tid + r * 256;
    float yv = (hbuf[o] - mean) * rs * gam[o] + bet[o];
    outp[b * 512 + o] = lrelu(yv);
  }
}

// ---- fc2 ----
__global__ __launch_bounds__(256)
void fc2_kernel(const float* __restrict__ inp, const float* __restrict__ Wt,
                const float* __restrict__ bias, const float* __restrict__ gam,
                const float* __restrict__ bet, float* __restrict__ outp) {
  __shared__ __align__(16) float gin[512];
  __shared__ float rbuf[8];
  const int b = blockIdx.x, tid = threadIdx.x;
  for (int e = tid; e < 512; e += 256) gin[e] = inp[b * 512 + e];
  __syncthreads();
  float ps = 0.f;
  for (int e = tid; e < 512; e += 256) ps = fmaf(gin[e], gin[e], ps);
  float ss = block_reduce_sum(ps, rbuf);
  float rinv = 1.0f / sqrtf(ss);
  const float* wrow = Wt + (size_t)tid * 512;
  float a = 0.f;
  for (int c4 = 0; c4 < 128; ++c4) {
    float4 wv = *reinterpret_cast<const float4*>(wrow + c4 * 4);
    float4 gv = *reinterpret_cast<const float4*>(&gin[c4 * 4]);
    a = fmaf(wv.x, gv.x, a); a = fmaf(wv.y, gv.y, a);
    a = fmaf(wv.z, gv.z, a); a = fmaf(wv.w, gv.w, a);
  }
  a = a * rinv + bias[tid];
  float mean = block_reduce_sum(a, rbuf) * (1.f / 256.f);
  float d = a - mean;
  float var = block_reduce_sum(d * d, rbuf) * (1.f / 256.f);
  float rs = 1.0f / sqrtf(var + 1e-5f);
  float yv = (a - mean) * rs * gam[tid] + bet[tid];
  outp[b * 256 + tid] = lrelu(yv);
}

// ---- fc3 + identity ----
__global__ __launch_bounds__(64)
void fc3_kernel(const float* __restrict__ inp, const float* __restrict__ Wt,
                const float* __restrict__ bias, float* __restrict__ tmat) {
  __shared__ float gin[256];
  const int b = blockIdx.x, tid = threadIdx.x;
  for (int e = tid; e < 256; e += 64) gin[e] = inp[b * 256 + e];
  __syncthreads();
  if (tid < 9) {
    const float* wrow = Wt + tid * 256;
    float a = 0.f;
    for (int c = 0; c < 256; ++c) a = fmaf(wrow[c], gin[c], a);
    a += bias[tid];
    if (tid == 0 || tid == 4 || tid == 8) a += 1.f;
    tmat[b * 9 + tid] = a;
  }
}

// ---- apply 3x3 transform ----
__global__ __launch_bounds__(256)
void xform_kernel(const float* __restrict__ x, const float* __restrict__ tmat,
                  float* __restrict__ xt) {
  const int b = blockIdx.y;
  const int n = blockIdx.x * 256 + threadIdx.x;
  const float* xb = x + (size_t)b * 3 * NPTS;
  const float x0 = xb[n], x1 = xb[NPTS + n], x2 = xb[2 * NPTS + n];
  const float* t = tmat + b * 9;
  float* ob = xt + (size_t)b * 3 * NPTS;
  #pragma unroll
  for (int i = 0; i < 3; ++i)
    ob[i * NPTS + n] = fmaf(t[3 * i], x0, fmaf(t[3 * i + 1], x1, t[3 * i + 2] * x2));
}

extern "C" void kernel_launch(void* const* d_in, const int* in_sizes, int n_in,
                              void* d_out, int out_size, void* d_ws, size_t ws_size,
                              hipStream_t stream) {
  (void)in_sizes; (void)n_in; (void)out_size; (void)ws_size;
  const float* x       = (const float*)d_in[0];
  const float* tw1     = (const float*)d_in[1];
  const float* tw2     = (const float*)d_in[2];
  const float* tw3     = (const float*)d_in[3];
  const float* tfc1_w  = (const float*)d_in[4];
  const float* tfc1_g  = (const float*)d_in[5];
  const float* tfc1_b  = (const float*)d_in[6];
  const float* tfc2_w  = (const float*)d_in[7];
  const float* tfc2_bias = (const float*)d_in[8];
  const float* tfc2_g  = (const float*)d_in[9];
  const float* tfc2_b  = (const float*)d_in[10];
  const float* tfc3_w  = (const float*)d_in[11];
  const float* tfc3_b  = (const float*)d_in[12];
  const float* w1      = (const float*)d_in[13];
  const float* w2      = (const float*)d_in[14];
  const float* w3      = (const float*)d_in[15];
  const float* w4      = (const float*)d_in[16];
  const float* w5      = (const float*)d_in[17];
  float* out = (float*)d_out;

  char* wsb = (char*)d_ws;
  size_t off = 0;
  auto alloc = [&](size_t bytes) -> void* {
    void* p = wsb + off;
    off += (bytes + 255) & ~(size_t)255;
    return p;
  };
  float* ybuf = (float*)alloc((size_t)BATCH * NPTS * 256 * 4);
  float* zbuf = (float*)alloc((size_t)BATCH * NPTS * 256 * 4);
  float* xcT  = (float*)alloc((size_t)BATCH * 512 * NPTS * 4);   // channel-major fp32 (knn)
  ushort* xc_bf = (ushort*)alloc((size_t)BATCH * NPTS * 512 * 2); // NC bf16 (MFMA)
  float* h2m  = (float*)alloc((size_t)BATCH * 128 * NPTS * 4);
  float* part = (float*)alloc((size_t)BATCH * 16 * 1024 * 4);
  int*   idxb = (int*)alloc((size_t)BATCH * NPTS * KNN * 4);
  float* xxb  = (float*)alloc((size_t)BATCH * NPTS * 4);
  float* xt   = (float*)alloc((size_t)BATCH * 3 * NPTS * 4);
  float* gbuf = (float*)alloc((size_t)BATCH * 1024 * 4);
  float* f1o  = (float*)alloc((size_t)BATCH * 512 * 4);
  float* f2o  = (float*)alloc((size_t)BATCH * 256 * 4);
  float* tmat = (float*)alloc((size_t)BATCH * 9 * 4);
  float* tw1aT = (float*)alloc(3 * 64 * 4);
  float* tw1dT = (float*)alloc(3 * 64 * 4);
  float* w1aT  = (float*)alloc(3 * 64 * 4);
  float* w1dT  = (float*)alloc(3 * 64 * 4);
  float* w2aT  = (float*)alloc(64 * 64 * 4);
  float* w2dT  = (float*)alloc(64 * 64 * 4);
  float* w3aT  = (float*)alloc(64 * 128 * 4);
  float* w3dT  = (float*)alloc(64 * 128 * 4);
  ushort* w4a_bf = (ushort*)alloc(256 * 128 * 2);
  ushort* w4d_bf = (ushort*)alloc(256 * 128 * 2);
  ushort* w5_bf  = (ushort*)alloc(1024 * 512 * 2);
  float* tw2T  = (float*)alloc(64 * 128 * 4);
  float* tw3T  = (float*)alloc(128 * 1024 * 4);

  // weight prep
  wsplit_t_kernel<<<1, 256, 0, stream>>>(tw1, tw1aT, tw1dT, 64, 3);
  wsplit_t_kernel<<<1, 256, 0, stream>>>(w1, w1aT, w1dT, 64, 3);
  wsplit_t_kernel<<<16, 256, 0, stream>>>(w2, w2aT, w2dT, 64, 64);
  wsplit_t_kernel<<<32, 256, 0, stream>>>(w3, w3aT, w3dT, 128, 64);
  wsplit_bf_kernel<<<128, 256, 0, stream>>>(w4, w4a_bf, w4d_bf, 256, 128);
  cvt_bf16_kernel<<<2048, 256, 0, stream>>>(w5, w5_bf, 1024 * 512);
  wtrans_kernel<<<32, 256, 0, stream>>>(tw2, tw2T, 128, 64);
  wtrans_kernel<<<512, 256, 0, stream>>>(tw3, tw3T, 1024, 128);

  // ---- transform net ----
  xx3_kernel<<<dim3(4, 16), 256, 0, stream>>>(x, xxb);
  knn_cn_kernel<3><<<dim3(128, 16), 256, 0, stream>>>(x, 3 * NPTS, xxb, idxb);
  gemm_kernel<<<dim3(16, 1, 16), 256, 0, stream>>>(x, 3 * NPTS, 1, NPTS, tw1aT, 64, 3,
                                                   ybuf, NPTS * 64, 64);
  gemm_kernel<<<dim3(16, 1, 16), 256, 0, stream>>>(x, 3 * NPTS, 1, NPTS, tw1dT, 64, 3,
                                                   zbuf, NPTS * 64, 64);
  h12_gemm_kernel<<<dim3(256, 16), 256, 0, stream>>>(ybuf, zbuf, idxb, tw2T, h2m);
  gemm128_kernel<1><<<dim3(8, 8, 16), 256, 0, stream>>>(h2m, 128 * NPTS, NPTS, tw3T, 1024, 128,
                                                        part, 8 * 1024, 0, 1024);
  reduce_max_kernel<<<dim3(4, 16), 256, 0, stream>>>(part, gbuf, 8);
  fc1_kernel<<<16, 256, 0, stream>>>(gbuf, tfc1_w, tfc1_g, tfc1_b, f1o);
  fc2_kernel<<<16, 256, 0, stream>>>(f1o, tfc2_w, tfc2_bias, tfc2_g, tfc2_b, f2o);
  fc3_kernel<<<16, 64, 0, stream>>>(f2o, tfc3_w, tfc3_b, tmat);
  xform_kernel<<<dim3(4, 16), 256, 0, stream>>>(x, tmat, xt);

  // ---- EdgeConv 1 (C=3 -> O=64) on xt ----
  xx3_kernel<<<dim3(4, 16), 256, 0, stream>>>(xt, xxb);
  knn_cn_kernel<3><<<dim3(128, 16), 256, 0, stream>>>(xt, 3 * NPTS, xxb, idxb);
  gemm_kernel<<<dim3(16, 1, 16), 256, 0, stream>>>(xt, 3 * NPTS, 1, NPTS, w1aT, 64, 3,
                                                   ybuf, NPTS * 64, 64);
  gemm_kernel<<<dim3(16, 1, 16), 256, 0, stream>>>(xt, 3 * NPTS, 1, NPTS, w1dT, 64, 3,
                                                   zbuf, NPTS * 64, 64);
  edge_max_cn_kernel<64, 64><<<dim3(16, 16), 256, 0, stream>>>(ybuf, zbuf, idxb, xcT, xxb,
                                                               xc_bf, 0);

  // ---- EdgeConv 2 (C=64 -> O=64) ----
  knn_cn_kernel<64><<<dim3(128, 16), 256, 0, stream>>>(xcT, 512 * NPTS, xxb, idxb);
  gemm_kernel<<<dim3(16, 1, 16), 256, 0, stream>>>(xcT, 512 * NPTS, 1, NPTS, w2aT, 64, 64,
                                                   ybuf, NPTS * 64, 64);
  gemm_kernel<<<dim3(16, 1, 16), 256, 0, stream>>>(xcT, 512 * NPTS, 1, NPTS, w2dT, 64, 64,
                                                   zbuf, NPTS * 64, 64);
  edge_max_cn_kernel<64, 64><<<dim3(16, 16), 256, 0, stream>>>(ybuf, zbuf, idxb,
                                                               xcT + 64 * NPTS, xxb, xc_bf, 64);

  // ---- EdgeConv 3 (C=64 -> O=128) ----
  knn_cn_kernel<64><<<dim3(128, 16), 256, 0, stream>>>(xcT + 64 * NPTS, 512 * NPTS, xxb, idxb);
  gemm_kernel<<<dim3(16, 2, 16), 256, 0, stream>>>(xcT + 64 * NPTS, 512 * NPTS, 1, NPTS,
                                                   w3aT, 128, 64, ybuf, NPTS * 128, 128);
  gemm_kernel<<<dim3(16, 2, 16), 256, 0, stream>>>(xcT + 64 * NPTS, 512 * NPTS, 1, NPTS,
                                                   w3dT, 128, 64, zbuf, NPTS * 128, 128);
  edge_max_cn_kernel<128, 64><<<dim3(16, 16), 256, 0, stream>>>(ybuf, zbuf, idxb,
                                                                xcT + 128 * NPTS, xxb, xc_bf, 128);

  // ---- EdgeConv 4 (C=128 -> O=256): bf16 MFMA GEMMs on x3 slice (knn-safe) ----
  knn_cn_kernel<128><<<dim3(128, 16), 256, 0, stream>>>(xcT + 128 * NPTS, 512 * NPTS, xxb, idxb);
  gemm_mfma_kernel<0><<<dim3(8, 2, 16), 256, 0, stream>>>(xc_bf + 128, (long)NPTS * 512, 512,
                                                          w4a_bf, 128, 128,
                                                          ybuf, (long)NPTS * 256, 256, 0);
  gemm_mfma_kernel<0><<<dim3(8, 2, 16), 256, 0, stream>>>(xc_bf + 128, (long)NPTS * 512, 512,
                                                          w4d_bf, 128, 128,
                                                          zbuf, (long)NPTS * 256, 256, 0);
  edge_max_cn_kernel<256, 32><<<dim3(32, 16), 256, 0, stream>>>(ybuf, zbuf, idxb,
                                                                xcT + 256 * NPTS, nullptr,
                                                                xc_bf, 256);

  // ---- final: x5 = lrelu(w5 @ xc) with max over n — bf16 MFMA (knn-safe) ----
  gemm_mfma_kernel<1><<<dim3(8, 8, 16), 256, 0, stream>>>(xc_bf, (long)NPTS * 512, 512,
                                                          w5_bf, 512, 512,
                                                          part, 8 * 1024, 0, 1024);
  reduce_max_kernel<<<dim3(4, 16), 256, 0, stream>>>(part, out, 8);
}

// Round 8
// 929.729 us; speedup vs baseline: 4.3754x; 1.0126x over previous
//
#include <hip/hip_runtime.h>
#include <math.h>

#define BATCH 16
#define NPTS 1024
#define KNN 20

__device__ __forceinline__ float lrelu(float v) { return v >= 0.f ? v : 0.2f * v; }

typedef __attribute__((ext_vector_type(8))) short bf16x8;
typedef __attribute__((ext_vector_type(4))) float f32x4;

__device__ __forceinline__ ushort f2bf(float f) {
  union { float f; unsigned u; } v; v.f = f;
  unsigned r = (v.u + 0x7FFFu + ((v.u >> 16) & 1u)) >> 16;  // RNE
  return (ushort)r;
}

// ---- weight prep: W[O][2C] -> WaT[C][O] fp32 ; WdT[C][O] fp32 (for fp32 gemms) ----
__global__ __launch_bounds__(256)
void wsplit_t_kernel(const float* __restrict__ W, float* __restrict__ waT,
                     float* __restrict__ wdT, int O, int Cc) {
  int e = blockIdx.x * 256 + threadIdx.x;
  if (e < O * Cc) {
    int c = e / O, o = e - c * O;
    float a = W[o * 2 * Cc + c], bb = W[o * 2 * Cc + Cc + c];
    waT[e] = a; wdT[e] = bb - a;
  }
}

// ---- weight prep bf16, NON-transposed [o][c] ----
__global__ __launch_bounds__(256)
void wsplit_bf_kernel(const float* __restrict__ W, ushort* __restrict__ wa_bf,
                      ushort* __restrict__ wd_bf, int O, int Cc) {
  int e = blockIdx.x * 256 + threadIdx.x;
  if (e < O * Cc) {
    int o = e / Cc, c = e - o * Cc;
    float a = W[o * 2 * Cc + c], bb = W[o * 2 * Cc + Cc + c];
    wa_bf[e] = f2bf(a); wd_bf[e] = f2bf(bb - a);
  }
}

// ---- fp32 -> bf16 elementwise ----
__global__ __launch_bounds__(256)
void cvt_bf16_kernel(const float* __restrict__ in, ushort* __restrict__ outp, int n) {
  int e = blockIdx.x * 256 + threadIdx.x;
  if (e < n) outp[e] = f2bf(in[e]);
}

// ---- weight transpose: W[O][C] -> wT[C][O] ----
__global__ __launch_bounds__(256)
void wtrans_kernel(const float* __restrict__ W, float* __restrict__ wT, int O, int Cc) {
  int e = blockIdx.x * 256 + threadIdx.x;
  if (e < O * Cc) {
    int c = e / O, o = e - c * O;
    wT[e] = W[(size_t)o * Cc + c];
  }
}

// ---- xx[b][n] = sum_c x[b][c][n]^2 for C=3 CN input ----
__global__ __launch_bounds__(256)
void xx3_kernel(const float* __restrict__ x, float* __restrict__ xx) {
  const int b = blockIdx.y;
  const int n = blockIdx.x * 256 + threadIdx.x;
  const float* xb = x + (size_t)b * 3 * NPTS;
  float a = xb[n], bb = xb[NPTS + n], c = xb[2 * NPTS + n];
  xx[b * NPTS + n] = a * a + bb * bb + c * c;
}

// ---- knn on channel-major features: 8 queries/block, 16 KB LDS (two-round handoff) ----
// Wave wv owns queries (i0+wv) and (i0+wv+4); 2 interleaved extraction chains.
template<int C>
__global__ __launch_bounds__(256)
void knn_cn_kernel(const float* __restrict__ Xt, long sb,
                   const float* __restrict__ xx, int* __restrict__ idxout) {
  __shared__ float sc4[4][NPTS];   // 16 KB
  const int b = blockIdx.y, i0 = blockIdx.x * 8;
  const int tid = threadIdx.x;
  const float* Xb = Xt + (size_t)b * sb;
  const int j0 = tid * 4;
  float acc[8][4];
  #pragma unroll
  for (int q = 0; q < 8; ++q)
    #pragma unroll
    for (int u = 0; u < 4; ++u) acc[q][u] = 0.f;
  for (int c = 0; c < C; ++c) {
    const float4 xv = *reinterpret_cast<const float4*>(Xb + (size_t)c * NPTS + j0);
    const float* xr = Xb + (size_t)c * NPTS + i0;   // uniform addresses -> scalar loads
    #pragma unroll
    for (int q = 0; q < 8; ++q) {
      const float xiq = xr[q];
      acc[q][0] = fmaf(xiq, xv.x, acc[q][0]);
      acc[q][1] = fmaf(xiq, xv.y, acc[q][1]);
      acc[q][2] = fmaf(xiq, xv.z, acc[q][2]);
      acc[q][3] = fmaf(xiq, xv.w, acc[q][3]);
    }
  }
  const float4 xxj = *reinterpret_cast<const float4*>(xx + b * NPTS + j0);
  const int wv = tid >> 6, lane = tid & 63;
  float v0[16], v1[16];

  // round A: queries 0..3
  #pragma unroll
  for (int q = 0; q < 4; ++q) {
    float4 st;
    st.x = fmaf(-2.f, acc[q][0], xxj.x);
    st.y = fmaf(-2.f, acc[q][1], xxj.y);
    st.z = fmaf(-2.f, acc[q][2], xxj.z);
    st.w = fmaf(-2.f, acc[q][3], xxj.w);
    *reinterpret_cast<float4*>(&sc4[q][j0]) = st;
  }
  __syncthreads();
  #pragma unroll
  for (int s = 0; s < 16; ++s) v0[s] = sc4[wv][lane + 64 * s];
  __syncthreads();
  // round B: queries 4..7 reuse the same LDS
  #pragma unroll
  for (int q = 4; q < 8; ++q) {
    float4 st;
    st.x = fmaf(-2.f, acc[q][0], xxj.x);
    st.y = fmaf(-2.f, acc[q][1], xxj.y);
    st.z = fmaf(-2.f, acc[q][2], xxj.z);
    st.w = fmaf(-2.f, acc[q][3], xxj.w);
    *reinterpret_cast<float4*>(&sc4[q - 4][j0]) = st;
  }
  __syncthreads();
  #pragma unroll
  for (int s = 0; s < 16; ++s) v1[s] = sc4[wv][lane + 64 * s];

  int my0 = 0, my1 = 0;
  for (int t = 0; t < KNN; ++t) {
    float bv0 = v0[0], bv1 = v1[0];
    int bs0 = 0, bs1 = 0;
    #pragma unroll
    for (int s = 1; s < 16; ++s) {
      if (v0[s] < bv0) { bv0 = v0[s]; bs0 = s; }
      if (v1[s] < bv1) { bv1 = v1[s]; bs1 = s; }
    }
    int bj0 = lane + (bs0 << 6), bj1 = lane + (bs1 << 6);
    #pragma unroll
    for (int off = 32; off > 0; off >>= 1) {
      const float ov0 = __shfl_xor(bv0, off); const int oj0 = __shfl_xor(bj0, off);
      const float ov1 = __shfl_xor(bv1, off); const int oj1 = __shfl_xor(bj1, off);
      const bool c0 = (ov0 < bv0) || (ov0 == bv0 && oj0 < bj0);
      const bool c1 = (ov1 < bv1) || (ov1 == bv1 && oj1 < bj1);
      bv0 = c0 ? ov0 : bv0; bj0 = c0 ? oj0 : bj0;
      bv1 = c1 ? ov1 : bv1; bj1 = c1 ? oj1 : bj1;
    }
    if (lane == t) { my0 = bj0; my1 = bj1; }
    const int ks0 = bj0 - lane, ks1 = bj1 - lane;   // == 64*s only on the winner lane
    #pragma unroll
    for (int s = 0; s < 16; ++s) {
      if (ks0 == (s << 6)) v0[s] = 3.4e38f;
      if (ks1 == (s << 6)) v1[s] = 3.4e38f;
    }
  }
  if (lane < KNN) {
    idxout[(size_t)(b * NPTS + i0 + wv) * KNN + lane] = my0;
    idxout[(size_t)(b * NPTS + i0 + wv + 4) * KNN + lane] = my1;
  }
}

// ---- 64-tile fp32 GEMM (small conv layers feeding knn paths) ----
__global__ __launch_bounds__(256)
void gemm_kernel(const float* __restrict__ X, long sxb, int sxn, int sxc,
                 const float* __restrict__ WT, int ldW, int C,
                 float* __restrict__ out, int sob, int son) {
  __shared__ __align__(16) float Xs[16][64];
  __shared__ __align__(16) float Ws[16][64];
  const int b = blockIdx.z;
  const int n0 = blockIdx.x * 64, o0 = blockIdx.y * 64;
  const int tid = threadIdx.x;
  const int lr = tid & 63;
  const int c4 = (tid >> 6) * 4;
  const int tn = tid & 15, to = tid >> 4;
  float acc[4][4];
  #pragma unroll
  for (int i = 0; i < 4; ++i)
    #pragma unroll
    for (int j = 0; j < 4; ++j) acc[i][j] = 0.f;

  const size_t xbase = (size_t)b * sxb;
  for (int k0 = 0; k0 < C; k0 += 16) {
    #pragma unroll
    for (int u = 0; u < 4; ++u) {
      int c = k0 + c4 + u;
      float xv = 0.f, wv = 0.f;
      if (c < C) {
        xv = X[xbase + (size_t)(n0 + lr) * sxn + (size_t)c * sxc];
        wv = WT[(size_t)c * ldW + o0 + lr];
      }
      Xs[c4 + u][lr] = xv;
      Ws[c4 + u][lr] = wv;
    }
    __syncthreads();
    #pragma unroll
    for (int kk = 0; kk < 16; ++kk) {
      const float4 xa = *reinterpret_cast<const float4*>(&Xs[kk][tn * 4]);
      const float4 wb = *reinterpret_cast<const float4*>(&Ws[kk][to * 4]);
      const float xr[4] = {xa.x, xa.y, xa.z, xa.w};
      const float wr[4] = {wb.x, wb.y, wb.z, wb.w};
      #pragma unroll
      for (int i = 0; i < 4; ++i)
        #pragma unroll
        for (int j = 0; j < 4; ++j) acc[i][j] = fmaf(xr[i], wr[j], acc[i][j]);
    }
    __syncthreads();
  }
  #pragma unroll
  for (int i = 0; i < 4; ++i) {
    float4 st = make_float4(acc[i][0], acc[i][1], acc[i][2], acc[i][3]);
    *reinterpret_cast<float4*>(&out[(size_t)b * sob + (size_t)(n0 + tn * 4 + i) * son + o0 + to * 4]) = st;
  }
}

// ---- 128x128 fp32 GEMM (tw3 path only; X channel-major) ----
template<int EPI>
__global__ __launch_bounds__(256)
void gemm128_kernel(const float* __restrict__ X, long sxb, int scN,
                    const float* __restrict__ WT, int ldW, int C,
                    float* __restrict__ out, int sob, int son, int snb) {
  __shared__ __align__(16) float Xs[16][128];
  __shared__ __align__(16) float Ws[16][128];
  __shared__ __align__(16) float red[16][132];
  const int b = blockIdx.z;
  const int n0 = blockIdx.x * 128, o0 = blockIdx.y * 128;
  const int tid = threadIdx.x;
  const int tn = tid & 15, to = tid >> 4;
  float acc[8][8];
  #pragma unroll
  for (int i = 0; i < 8; ++i)
    #pragma unroll
    for (int j = 0; j < 8; ++j) acc[i][j] = 0.f;

  const size_t xbase = (size_t)b * sxb;
  for (int c0 = 0; c0 < C; c0 += 16) {
    #pragma unroll
    for (int it = 0; it < 2; ++it) {
      const int task = tid + it * 256;
      const int kk = task >> 5, n4 = (task & 31) * 4;
      *reinterpret_cast<float4*>(&Xs[kk][n4]) =
        *reinterpret_cast<const float4*>(&X[xbase + (size_t)(c0 + kk) * scN + n0 + n4]);
      *reinterpret_cast<float4*>(&Ws[kk][n4]) =
        *reinterpret_cast<const float4*>(&WT[(size_t)(c0 + kk) * ldW + o0 + n4]);
    }
    __syncthreads();
    #pragma unroll
    for (int kk = 0; kk < 16; ++kk) {
      const float4 xa0 = *reinterpret_cast<const float4*>(&Xs[kk][tn * 4]);
      const float4 xa1 = *reinterpret_cast<const float4*>(&Xs[kk][64 + tn * 4]);
      const float4 wb0 = *reinterpret_cast<const float4*>(&Ws[kk][to * 4]);
      const float4 wb1 = *reinterpret_cast<const float4*>(&Ws[kk][64 + to * 4]);
      const float xr[8] = {xa0.x, xa0.y, xa0.z, xa0.w, xa1.x, xa1.y, xa1.z, xa1.w};
      const float wr[8] = {wb0.x, wb0.y, wb0.z, wb0.w, wb1.x, wb1.y, wb1.z, wb1.w};
      #pragma unroll
      for (int i = 0; i < 8; ++i)
        #pragma unroll
        for (int j = 0; j < 8; ++j) acc[i][j] = fmaf(xr[i], wr[j], acc[i][j]);
    }
    __syncthreads();
  }

  if (EPI == 0) {
    #pragma unroll
    for (int i = 0; i < 8; ++i) {
      const int n = n0 + (i >> 2) * 64 + tn * 4 + (i & 3);
      float4 s0 = make_float4(acc[i][0], acc[i][1], acc[i][2], acc[i][3]);
      float4 s1 = make_float4(acc[i][4], acc[i][5], acc[i][6], acc[i][7]);
      *reinterpret_cast<float4*>(&out[(size_t)b * sob + (size_t)n * son + o0 + to * 4]) = s0;
      *reinterpret_cast<float4*>(&out[(size_t)b * sob + (size_t)n * son + o0 + 64 + to * 4]) = s1;
    }
  } else {
    #pragma unroll
    for (int j = 0; j < 8; ++j) {
      float m = lrelu(acc[0][j]);
      #pragma unroll
      for (int i = 1; i < 8; ++i) m = fmaxf(m, lrelu(acc[i][j]));
      red[tn][(j >> 2) * 64 + to * 4 + (j & 3)] = m;
    }
    __syncthreads();
    if (tid < 128) {
      float m = red[0][tid];
      #pragma unroll
      for (int t = 1; t < 16; ++t) m = fmaxf(m, red[t][tid]);
      out[(size_t)b * sob + (size_t)blockIdx.x * snb + o0 + tid] = m;
    }
  }
}

// ---- bf16 MFMA GEMM ----
template<int EPI>
__global__ __launch_bounds__(256)
void gemm_mfma_kernel(const ushort* __restrict__ Xg, long sxb, int ldX,
                      const ushort* __restrict__ Wg, int ldW, int K,
                      float* __restrict__ out, long sob, int son, int snb) {
  __shared__ __align__(16) ushort As[128 * 64];
  __shared__ __align__(16) ushort Bs[128 * 64];
  __shared__ float red[2][128];
  const int b = blockIdx.z;
  const int n0 = blockIdx.x * 128, o0 = blockIdx.y * 128;
  const int tid = threadIdx.x;
  const int lane = tid & 63;
  const int wrow = (tid >> 6) >> 1, wcol = (tid >> 6) & 1;
  f32x4 acc[4][4];
  #pragma unroll
  for (int i = 0; i < 4; ++i)
    #pragma unroll
    for (int j = 0; j < 4; ++j)
      #pragma unroll
      for (int r = 0; r < 4; ++r) acc[i][j][r] = 0.f;

  const ushort* Xb = Xg + (size_t)b * sxb;
  for (int kb = 0; kb < K; kb += 64) {
    #pragma unroll
    for (int i = 0; i < 4; ++i) {
      const int idx = i * 256 + tid;
      const int n = idx >> 3, kc = idx & 7;
      const bf16x8 xv = *reinterpret_cast<const bf16x8*>(&Xb[(size_t)(n0 + n) * ldX + kb + kc * 8]);
      const bf16x8 wv = *reinterpret_cast<const bf16x8*>(&Wg[(size_t)(o0 + n) * ldW + kb + kc * 8]);
      const int ad = n * 128 + ((kc * 16) ^ ((n & 7) << 4));
      *reinterpret_cast<bf16x8*>((char*)As + ad) = xv;
      *reinterpret_cast<bf16x8*>((char*)Bs + ad) = wv;
    }
    __syncthreads();
    #pragma unroll
    for (int s = 0; s < 2; ++s) {
      bf16x8 af[4], bfr[4];
      const int klane = (s * 64 + ((lane >> 4) << 4));
      #pragma unroll
      for (int f = 0; f < 4; ++f) {
        const int nl = wrow * 64 + f * 16 + (lane & 15);
        af[f] = *reinterpret_cast<const bf16x8*>((char*)As + nl * 128 + (klane ^ ((nl & 7) << 4)));
        const int ol = wcol * 64 + f * 16 + (lane & 15);
        bfr[f] = *reinterpret_cast<const bf16x8*>((char*)Bs + ol * 128 + (klane ^ ((ol & 7) << 4)));
      }
      #pragma unroll
      for (int i = 0; i < 4; ++i)
        #pragma unroll
        for (int j = 0; j < 4; ++j)
          acc[i][j] = __builtin_amdgcn_mfma_f32_16x16x32_bf16(af[i], bfr[j], acc[i][j], 0, 0, 0);
    }
    __syncthreads();
  }

  if (EPI == 0) {
    #pragma unroll
    for (int i = 0; i < 4; ++i)
      #pragma unroll
      for (int r = 0; r < 4; ++r) {
        const int n = n0 + wrow * 64 + i * 16 + ((lane >> 4) << 2) + r;
        #pragma unroll
        for (int j = 0; j < 4; ++j) {
          const int o = o0 + wcol * 64 + j * 16 + (lane & 15);
          out[(size_t)b * sob + (size_t)n * son + o] = acc[i][j][r];
        }
      }
  } else {
    #pragma unroll
    for (int j = 0; j < 4; ++j) {
      float m = -3.4e38f;
      #pragma unroll
      for (int i = 0; i < 4; ++i)
        #pragma unroll
        for (int r = 0; r < 4; ++r) m = fmaxf(m, lrelu(acc[i][j][r]));
      m = fmaxf(m, __shfl_xor(m, 16));
      m = fmaxf(m, __shfl_xor(m, 32));
      if (lane < 16) red[wrow][wcol * 64 + j * 16 + lane] = m;
    }
    __syncthreads();
    if (tid < 128) {
      float m = fmaxf(red[0][tid], red[1][tid]);
      out[(size_t)b * sob + (size_t)blockIdx.x * snb + o0 + tid] = m;
    }
  }
}

// ---- edge max, channel-major fp32 output + NC bf16 copy for MFMA consumers ----
template<int O, int TI>
__global__ __launch_bounds__(256)
void edge_max_cn_kernel(const float* __restrict__ y, const float* __restrict__ z,
                        const int* __restrict__ idx, float* __restrict__ outCN,
                        float* __restrict__ xx, ushort* __restrict__ xbf, int choff) {
  __shared__ float tile[TI][O + 1];
  const int b = blockIdx.y;
  const int i0 = blockIdx.x * TI;
  const int wv = threadIdx.x >> 6, lane = threadIdx.x & 63;
  constexpr int OSEG = O / 64;
  constexpr int ROUNDS = TI * OSEG / 4;
  for (int r = 0; r < ROUNDS; ++r) {
    const int item = r * 4 + wv;
    const int il = item / OSEG, os = item - il * OSEG;
    const int i = i0 + il, o = os * 64 + lane;
    const int* ip = idx + (size_t)(b * NPTS + i) * KNN;
    const float zv = z[(size_t)(b * NPTS + i) * O + o];
    float m = -3.4e38f;
    #pragma unroll
    for (int t = 0; t < KNN; ++t) {
      int j = ip[t];
      float v = y[(size_t)(b * NPTS + j) * O + o] + zv;
      m = fmaxf(m, lrelu(v));
    }
    tile[il][o] = m;
    xbf[(size_t)(b * NPTS + i) * 512 + choff + o] = f2bf(m);
  }
  __syncthreads();
  if (xx != nullptr && threadIdx.x < TI) {
    const int il = threadIdx.x;
    float s = 0.f;
    #pragma unroll
    for (int o = 0; o < O; ++o) { float v = tile[il][o]; s = fmaf(v, v, s); }
    xx[b * NPTS + i0 + il] = s;
  }
  for (int e = threadIdx.x; e < TI * O; e += 256) {
    const int o = e / TI, il = e - o * TI;
    outCN[(size_t)b * 512 * NPTS + (size_t)o * NPTS + i0 + il] = tile[il][o];
  }
}

// ---- h12 as edge-GEMM ----
__global__ __launch_bounds__(256)
void h12_gemm_kernel(const float* __restrict__ ya, const float* __restrict__ zb,
                     const int* __restrict__ idx, const float* __restrict__ tw2T,
                     float* __restrict__ h2m) {
  __shared__ __align__(16) float h1s[80][68];
  __shared__ __align__(16) float ws[64][128];
  __shared__ __align__(16) float zbs[4][64];
  __shared__ float ot[128][4];
  __shared__ int idxs[4][KNN];
  const int b = blockIdx.y;
  const int i0 = blockIdx.x * 4;
  const int tid = threadIdx.x;

  #pragma unroll
  for (int it = 0; it < 8; ++it) {
    const int f = tid + it * 256;
    *reinterpret_cast<float4*>(&ws[0][0] + f * 4) =
      *reinterpret_cast<const float4*>(tw2T + (size_t)f * 4);
  }
  if (tid < 64) {
    const int p = tid >> 4, cq = (tid & 15) * 4;
    *reinterpret_cast<float4*>(&zbs[p][cq]) =
      *reinterpret_cast<const float4*>(&zb[(size_t)(b * NPTS + i0 + p) * 64 + cq]);
  }
  if (tid >= 64 && tid < 64 + 4 * KNN) {
    const int e = tid - 64;
    idxs[e / KNN][e % KNN] = idx[(size_t)(b * NPTS + i0) * KNN + e];
  }
  __syncthreads();

  #pragma unroll
  for (int it = 0; it < 5; ++it) {
    const int task = tid + it * 256;
    const int e = task >> 4, cq = (task & 15) * 4;
    const int p = e / KNN, t = e - p * KNN;
    const int j = idxs[p][t];
    const float4 yv = *reinterpret_cast<const float4*>(&ya[(size_t)(b * NPTS + j) * 64 + cq]);
    const float4 zv = *reinterpret_cast<const float4*>(&zbs[p][cq]);
    float4 hv;
    hv.x = lrelu(yv.x + zv.x); hv.y = lrelu(yv.y + zv.y);
    hv.z = lrelu(yv.z + zv.z); hv.w = lrelu(yv.w + zv.w);
    *reinterpret_cast<float4*>(&h1s[e][cq]) = hv;
  }
  __syncthreads();

  const int eg = tid >> 4, og = tid & 15;
  float acc[5][8];
  #pragma unroll
  for (int u = 0; u < 5; ++u)
    #pragma unroll
    for (int v = 0; v < 8; ++v) acc[u][v] = 0.f;
  #pragma unroll 4
  for (int kk = 0; kk < 64; ++kk) {
    float hv[5];
    #pragma unroll
    for (int u = 0; u < 5; ++u) hv[u] = h1s[eg * 5 + u][kk];
    const float4 w0 = *reinterpret_cast<const float4*>(&ws[kk][og * 4]);
    const float4 w1 = *reinterpret_cast<const float4*>(&ws[kk][64 + og * 4]);
    const float wr[8] = {w0.x, w0.y, w0.z, w0.w, w1.x, w1.y, w1.z, w1.w};
    #pragma unroll
    for (int u = 0; u < 5; ++u)
      #pragma unroll
      for (int v = 0; v < 8; ++v) acc[u][v] = fmaf(hv[u], wr[v], acc[u][v]);
  }

  const int p = eg >> 2, d = eg & 3;
  float m[8];
  #pragma unroll
  for (int v = 0; v < 8; ++v) {
    float mm = lrelu(acc[0][v]);
    #pragma unroll
    for (int u = 1; u < 5; ++u) mm = fmaxf(mm, lrelu(acc[u][v]));
    mm = fmaxf(mm, __shfl_xor(mm, 16));
    mm = fmaxf(mm, __shfl_xor(mm, 32));
    m[v] = mm;
  }
  if (d == 0) {
    #pragma unroll
    for (int v = 0; v < 8; ++v) {
      const int o = og * 4 + (v & 3) + (v >> 2) * 64;
      ot[o][p] = m[v];
    }
  }
  __syncthreads();
  if (tid < 128) {
    float4 st = make_float4(ot[tid][0], ot[tid][1], ot[tid][2], ot[tid][3]);
    *reinterpret_cast<float4*>(&h2m[(size_t)(b * 128 + tid) * NPTS + i0]) = st;
  }
}

// ---- reduce partial max over nt n-tiles ----
__global__ __launch_bounds__(256)
void reduce_max_kernel(const float* __restrict__ part, float* __restrict__ outp, int nt) {
  const int b = blockIdx.y;
  const int o = blockIdx.x * 256 + threadIdx.x;
  float m = part[(size_t)(b * nt) * 1024 + o];
  for (int t = 1; t < nt; ++t) m = fmaxf(m, part[(size_t)(b * nt + t) * 1024 + o]);
  outp[b * 1024 + o] = m;
}

// ---- block reduce helper ----
__device__ __forceinline__ float block_reduce_sum(float v, float* rbuf) {
  #pragma unroll
  for (int off = 32; off > 0; off >>= 1) v += __shfl_xor(v, off);
  const int w = threadIdx.x >> 6, lane = threadIdx.x & 63;
  const int nw = blockDim.x >> 6;
  if (lane == 0) rbuf[w] = v;
  __syncthreads();
  float tot = 0.f;
  for (int i = 0; i < nw; ++i) tot += rbuf[i];
  __syncthreads();
  return tot;
}

// ---- fc1 ----
__global__ __launch_bounds__(256)
void fc1_kernel(const float* __restrict__ gin_g, const float* __restrict__ Wt,
                const float* __restrict__ gam, const float* __restrict__ bet,
                float* __restrict__ outp) {
  __shared__ __align__(16) float gin[1024];
  __shared__ float hbuf[512];
  __shared__ float rbuf[8];
  const int b = blockIdx.x, tid = threadIdx.x;
  for (int e = tid; e < 1024; e += 256) gin[e] = gin_g[b * 1024 + e];
  __syncthreads();
  float ps = 0.f;
  for (int e = tid; e < 1024; e += 256) ps = fmaf(gin[e], gin[e], ps);
  float ss = block_reduce_sum(ps, rbuf);
  float rinv = 1.0f / sqrtf(ss);
  #pragma unroll
  for (int r = 0; r < 2; ++r) {
    int o = tid + r * 256;
    const float* wrow = Wt + (size_t)o * 1024;
    float a = 0.f;
    for (int c4 = 0; c4 < 256; ++c4) {
      float4 wv = *reinterpret_cast<const float4*>(wrow + c4 * 4);
      float4 gv = *reinterpret_cast<const float4*>(&gin[c4 * 4]);
      a = fmaf(wv.x, gv.x, a); a = fmaf(wv.y, gv.y, a);
      a = fmaf(wv.z, gv.z, a); a = fmaf(wv.w, gv.w, a);
    }
    hbuf[o] = a * rinv;
  }
  __syncthreads();
  float pm = hbuf[tid] + hbuf[tid + 256];
  float mean = block_reduce_sum(pm, rbuf) * (1.f / 512.f);
  float d0 = hbuf[tid] - mean, d1 = hbuf[tid + 256] - mean;
  float var = block_reduce_sum(d0 * d0 + d1 * d1, rbuf) * (1.f / 512.f);
  float rs = 1.0f / sqrtf(var + 1e-5f);
  #pragma unroll
  for (int r = 0; r < 2; ++r) {
    int o = tid + r * 256;
    float yv = (hbuf[o] - mean) * rs * gam[o] + bet[o];
    outp[b * 512 + o] = lrelu(yv);
  }
}

// ---- fc2 ----
__global__ __launch_bounds__(256)
void fc2_kernel(const float* __restrict__ inp, const float* __restrict__ Wt,
                const float* __restrict__ bias, const float* __restrict__ gam,
                const float* __restrict__ bet, float* __restrict__ outp) {
  __shared__ __align__(16) float gin[512];
  __shared__ float rbuf[8];
  const int b = blockIdx.x, tid = threadIdx.x;
  for (int e = tid; e < 512; e += 256) gin[e] = inp[b * 512 + e];
  __syncthreads();
  float ps = 0.f;
  for (int e = tid; e < 512; e += 256) ps = fmaf(gin[e], gin[e], ps);
  float ss = block_reduce_sum(ps, rbuf);
  float rinv = 1.0f / sqrtf(ss);
  const float* wrow = Wt + (size_t)tid * 512;
  float a = 0.f;
  for (int c4 = 0; c4 < 128; ++c4) {
    float4 wv = *reinterpret_cast<const float4*>(wrow + c4 * 4);
    float4 gv = *reinterpret_cast<const float4*>(&gin[c4 * 4]);
    a = fmaf(wv.x, gv.x, a); a = fmaf(wv.y, gv.y, a);
    a = fmaf(wv.z, gv.z, a); a = fmaf(wv.w, gv.w, a);
  }
  a = a * rinv + bias[tid];
  float mean = block_reduce_sum(a, rbuf) * (1.f / 256.f);
  float d = a - mean;
  float var = block_reduce_sum(d * d, rbuf) * (1.f / 256.f);
  float rs = 1.0f / sqrtf(var + 1e-5f);
  float yv = (a - mean) * rs * gam[tid] + bet[tid];
  outp[b * 256 + tid] = lrelu(yv);
}

// ---- fc3 + identity ----
__global__ __launch_bounds__(64)
void fc3_kernel(const float* __restrict__ inp, const float* __restrict__ Wt,
                const float* __restrict__ bias, float* __restrict__ tmat) {
  __shared__ float gin[256];
  const int b = blockIdx.x, tid = threadIdx.x;
  for (int e = tid; e < 256; e += 64) gin[e] = inp[b * 256 + e];
  __syncthreads();
  if (tid < 9) {
    const float* wrow = Wt + tid * 256;
    float a = 0.f;
    for (int c = 0; c < 256; ++c) a = fmaf(wrow[c], gin[c], a);
    a += bias[tid];
    if (tid == 0 || tid == 4 || tid == 8) a += 1.f;
    tmat[b * 9 + tid] = a;
  }
}

// ---- apply 3x3 transform ----
__global__ __launch_bounds__(256)
void xform_kernel(const float* __restrict__ x, const float* __restrict__ tmat,
                  float* __restrict__ xt) {
  const int b = blockIdx.y;
  const int n = blockIdx.x * 256 + threadIdx.x;
  const float* xb = x + (size_t)b * 3 * NPTS;
  const float x0 = xb[n], x1 = xb[NPTS + n], x2 = xb[2 * NPTS + n];
  const float* t = tmat + b * 9;
  float* ob = xt + (size_t)b * 3 * NPTS;
  #pragma unroll
  for (int i = 0; i < 3; ++i)
    ob[i * NPTS + n] = fmaf(t[3 * i], x0, fmaf(t[3 * i + 1], x1, t[3 * i + 2] * x2));
}

extern "C" void kernel_launch(void* const* d_in, const int* in_sizes, int n_in,
                              void* d_out, int out_size, void* d_ws, size_t ws_size,
                              hipStream_t stream) {
  (void)in_sizes; (void)n_in; (void)out_size; (void)ws_size;
  const float* x       = (const float*)d_in[0];
  const float* tw1     = (const float*)d_in[1];
  const float* tw2     = (const float*)d_in[2];
  const float* tw3     = (const float*)d_in[3];
  const float* tfc1_w  = (const float*)d_in[4];
  const float* tfc1_g  = (const float*)d_in[5];
  const float* tfc1_b  = (const float*)d_in[6];
  const float* tfc2_w  = (const float*)d_in[7];
  const float* tfc2_bias = (const float*)d_in[8];
  const float* tfc2_g  = (const float*)d_in[9];
  const float* tfc2_b  = (const float*)d_in[10];
  const float* tfc3_w  = (const float*)d_in[11];
  const float* tfc3_b  = (const float*)d_in[12];
  const float* w1      = (const float*)d_in[13];
  const float* w2      = (const float*)d_in[14];
  const float* w3      = (const float*)d_in[15];
  const float* w4      = (const float*)d_in[16];
  const float* w5      = (const float*)d_in[17];
  float* out = (float*)d_out;

  char* wsb = (char*)d_ws;
  size_t off = 0;
  auto alloc = [&](size_t bytes) -> void* {
    void* p = wsb + off;
    off += (bytes + 255) & ~(size_t)255;
    return p;
  };
  float* ybuf = (float*)alloc((size_t)BATCH * NPTS * 256 * 4);
  float* zbuf = (float*)alloc((size_t)BATCH * NPTS * 256 * 4);
  float* xcT  = (float*)alloc((size_t)BATCH * 512 * NPTS * 4);   // channel-major fp32 (knn)
  ushort* xc_bf = (ushort*)alloc((size_t)BATCH * NPTS * 512 * 2); // NC bf16 (MFMA)
  float* h2m  = (float*)alloc((size_t)BATCH * 128 * NPTS * 4);
  float* part = (float*)alloc((size_t)BATCH * 16 * 1024 * 4);
  int*   idxb = (int*)alloc((size_t)BATCH * NPTS * KNN * 4);
  float* xxb  = (float*)alloc((size_t)BATCH * NPTS * 4);
  float* xt   = (float*)alloc((size_t)BATCH * 3 * NPTS * 4);
  float* gbuf = (float*)alloc((size_t)BATCH * 1024 * 4);
  float* f1o  = (float*)alloc((size_t)BATCH * 512 * 4);
  float* f2o  = (float*)alloc((size_t)BATCH * 256 * 4);
  float* tmat = (float*)alloc((size_t)BATCH * 9 * 4);
  float* tw1aT = (float*)alloc(3 * 64 * 4);
  float* tw1dT = (float*)alloc(3 * 64 * 4);
  float* w1aT  = (float*)alloc(3 * 64 * 4);
  float* w1dT  = (float*)alloc(3 * 64 * 4);
  float* w2aT  = (float*)alloc(64 * 64 * 4);
  float* w2dT  = (float*)alloc(64 * 64 * 4);
  float* w3aT  = (float*)alloc(64 * 128 * 4);
  float* w3dT  = (float*)alloc(64 * 128 * 4);
  ushort* w4a_bf = (ushort*)alloc(256 * 128 * 2);
  ushort* w4d_bf = (ushort*)alloc(256 * 128 * 2);
  ushort* w5_bf  = (ushort*)alloc(1024 * 512 * 2);
  float* tw2T  = (float*)alloc(64 * 128 * 4);
  float* tw3T  = (float*)alloc(128 * 1024 * 4);

  // weight prep
  wsplit_t_kernel<<<1, 256, 0, stream>>>(tw1, tw1aT, tw1dT, 64, 3);
  wsplit_t_kernel<<<1, 256, 0, stream>>>(w1, w1aT, w1dT, 64, 3);
  wsplit_t_kernel<<<16, 256, 0, stream>>>(w2, w2aT, w2dT, 64, 64);
  wsplit_t_kernel<<<32, 256, 0, stream>>>(w3, w3aT, w3dT, 128, 64);
  wsplit_bf_kernel<<<128, 256, 0, stream>>>(w4, w4a_bf, w4d_bf, 256, 128);
  cvt_bf16_kernel<<<2048, 256, 0, stream>>>(w5, w5_bf, 1024 * 512);
  wtrans_kernel<<<32, 256, 0, stream>>>(tw2, tw2T, 128, 64);
  wtrans_kernel<<<512, 256, 0, stream>>>(tw3, tw3T, 1024, 128);

  // ---- transform net ----
  xx3_kernel<<<dim3(4, 16), 256, 0, stream>>>(x, xxb);
  knn_cn_kernel<3><<<dim3(128, 16), 256, 0, stream>>>(x, 3 * NPTS, xxb, idxb);
  gemm_kernel<<<dim3(16, 1, 16), 256, 0, stream>>>(x, 3 * NPTS, 1, NPTS, tw1aT, 64, 3,
                                                   ybuf, NPTS * 64, 64);
  gemm_kernel<<<dim3(16, 1, 16), 256, 0, stream>>>(x, 3 * NPTS, 1, NPTS, tw1dT, 64, 3,
                                                   zbuf, NPTS * 64, 64);
  h12_gemm_kernel<<<dim3(256, 16), 256, 0, stream>>>(ybuf, zbuf, idxb, tw2T, h2m);
  gemm128_kernel<1><<<dim3(8, 8, 16), 256, 0, stream>>>(h2m, 128 * NPTS, NPTS, tw3T, 1024, 128,
                                                        part, 8 * 1024, 0, 1024);
  reduce_max_kernel<<<dim3(4, 16), 256, 0, stream>>>(part, gbuf, 8);
  fc1_kernel<<<16, 256, 0, stream>>>(gbuf, tfc1_w, tfc1_g, tfc1_b, f1o);
  fc2_kernel<<<16, 256, 0, stream>>>(f1o, tfc2_w, tfc2_bias, tfc2_g, tfc2_b, f2o);
  fc3_kernel<<<16, 64, 0, stream>>>(f2o, tfc3_w, tfc3_b, tmat);
  xform_kernel<<<dim3(4, 16), 256, 0, stream>>>(x, tmat, xt);

  // ---- EdgeConv 1 (C=3 -> O=64) on xt ----
  xx3_kernel<<<dim3(4, 16), 256, 0, stream>>>(xt, xxb);
  knn_cn_kernel<3><<<dim3(128, 16), 256, 0, stream>>>(xt, 3 * NPTS, xxb, idxb);
  gemm_kernel<<<dim3(16, 1, 16), 256, 0, stream>>>(xt, 3 * NPTS, 1, NPTS, w1aT, 64, 3,
                                                   ybuf, NPTS * 64, 64);
  gemm_kernel<<<dim3(16, 1, 16), 256, 0, stream>>>(xt, 3 * NPTS, 1, NPTS, w1dT, 64, 3,
                                                   zbuf, NPTS * 64, 64);
  edge_max_cn_kernel<64, 64><<<dim3(16, 16), 256, 0, stream>>>(ybuf, zbuf, idxb, xcT, xxb,
                                                               xc_bf, 0);

  // ---- EdgeConv 2 (C=64 -> O=64) ----
  knn_cn_kernel<64><<<dim3(128, 16), 256, 0, stream>>>(xcT, 512 * NPTS, xxb, idxb);
  gemm_kernel<<<dim3(16, 1, 16), 256, 0, stream>>>(xcT, 512 * NPTS, 1, NPTS, w2aT, 64, 64,
                                                   ybuf, NPTS * 64, 64);
  gemm_kernel<<<dim3(16, 1, 16), 256, 0, stream>>>(xcT, 512 * NPTS, 1, NPTS, w2dT, 64, 64,
                                                   zbuf, NPTS * 64, 64);
  edge_max_cn_kernel<64, 64><<<dim3(16, 16), 256, 0, stream>>>(ybuf, zbuf, idxb,
                                                               xcT + 64 * NPTS, xxb, xc_bf, 64);

  // ---- EdgeConv 3 (C=64 -> O=128) ----
  knn_cn_kernel<64><<<dim3(128, 16), 256, 0, stream>>>(xcT + 64 * NPTS, 512 * NPTS, xxb, idxb);
  gemm_kernel<<<dim3(16, 2, 16), 256, 0, stream>>>(xcT + 64 * NPTS, 512 * NPTS, 1, NPTS,
                                                   w3aT, 128, 64, ybuf, NPTS * 128, 128);
  gemm_kernel<<<dim3(16, 2, 16), 256, 0, stream>>>(xcT + 64 * NPTS, 512 * NPTS, 1, NPTS,
                                                   w3dT, 128, 64, zbuf, NPTS * 128, 128);
  edge_max_cn_kernel<128, 64><<<dim3(16, 16), 256, 0, stream>>>(ybuf, zbuf, idxb,
                                                                xcT + 128 * NPTS, xxb, xc_bf, 128);

  // ---- EdgeConv 4 (C=128 -> O=256): bf16 MFMA GEMMs on x3 slice (knn-safe) ----
  knn_cn_kernel<128><<<dim3(128, 16), 256, 0, stream>>>(xcT + 128 * NPTS, 512 * NPTS, xxb, idxb);
  gemm_mfma_kernel<0><<<dim3(8, 2, 16), 256, 0, stream>>>(xc_bf + 128, (long)NPTS * 512, 512,
                                                          w4a_bf, 128, 128,
                                                          ybuf, (long)NPTS * 256, 256, 0);
  gemm_mfma_kernel<0><<<dim3(8, 2, 16), 256, 0, stream>>>(xc_bf + 128, (long)NPTS * 512, 512,
                                                          w4d_bf, 128, 128,
                                                          zbuf, (long)NPTS * 256, 256, 0);
  edge_max_cn_kernel<256, 32><<<dim3(32, 16), 256, 0, stream>>>(ybuf, zbuf, idxb,
                                                                xcT + 256 * NPTS, nullptr,
                                                                xc_bf, 256);

  // ---- final: x5 = lrelu(w5 @ xc) with max over n — bf16 MFMA (knn-safe) ----
  gemm_mfma_kernel<1><<<dim3(8, 8, 16), 256, 0, stream>>>(xc_bf, (long)NPTS * 512, 512,
                                                          w5_bf, 512, 512,
                                                          part, 8 * 1024, 0, 1024);
  reduce_max_kernel<<<dim3(4, 16), 256, 0, stream>>>(part, out, 8);
}

// Round 9
// 835.683 us; speedup vs baseline: 4.8678x; 1.1125x over previous
//
#include <hip/hip_runtime.h>
#include <math.h>

#define BATCH 16
#define NPTS 1024
#define KNN 20

__device__ __forceinline__ float lrelu(float v) { return v >= 0.f ? v : 0.2f * v; }

typedef __attribute__((ext_vector_type(8))) short bf16x8;
typedef __attribute__((ext_vector_type(4))) float f32x4;
typedef unsigned long long ull;

__device__ __forceinline__ ushort f2bf(float f) {
  union { float f; unsigned u; } v; v.f = f;
  unsigned r = (v.u + 0x7FFFu + ((v.u >> 16) & 1u)) >> 16;  // RNE
  return (ushort)r;
}

// ---- weight prep: W[O][2C] -> WaT[C][O] fp32 ; WdT[C][O] fp32 (for fp32 gemms) ----
__global__ __launch_bounds__(256)
void wsplit_t_kernel(const float* __restrict__ W, float* __restrict__ waT,
                     float* __restrict__ wdT, int O, int Cc) {
  int e = blockIdx.x * 256 + threadIdx.x;
  if (e < O * Cc) {
    int c = e / O, o = e - c * O;
    float a = W[o * 2 * Cc + c], bb = W[o * 2 * Cc + Cc + c];
    waT[e] = a; wdT[e] = bb - a;
  }
}

// ---- weight prep bf16, NON-transposed [o][c] ----
__global__ __launch_bounds__(256)
void wsplit_bf_kernel(const float* __restrict__ W, ushort* __restrict__ wa_bf,
                      ushort* __restrict__ wd_bf, int O, int Cc) {
  int e = blockIdx.x * 256 + threadIdx.x;
  if (e < O * Cc) {
    int o = e / Cc, c = e - o * Cc;
    float a = W[o * 2 * Cc + c], bb = W[o * 2 * Cc + Cc + c];
    wa_bf[e] = f2bf(a); wd_bf[e] = f2bf(bb - a);
  }
}

// ---- fp32 -> bf16 elementwise ----
__global__ __launch_bounds__(256)
void cvt_bf16_kernel(const float* __restrict__ in, ushort* __restrict__ outp, int n) {
  int e = blockIdx.x * 256 + threadIdx.x;
  if (e < n) outp[e] = f2bf(in[e]);
}

// ---- weight transpose: W[O][C] -> wT[C][O] ----
__global__ __launch_bounds__(256)
void wtrans_kernel(const float* __restrict__ W, float* __restrict__ wT, int O, int Cc) {
  int e = blockIdx.x * 256 + threadIdx.x;
  if (e < O * Cc) {
    int c = e / O, o = e - c * O;
    wT[e] = W[(size_t)o * Cc + c];
  }
}

// ---- xx[b][n] = sum_c x[b][c][n]^2 for C=3 CN input ----
__global__ __launch_bounds__(256)
void xx3_kernel(const float* __restrict__ x, float* __restrict__ xx) {
  const int b = blockIdx.y;
  const int n = blockIdx.x * 256 + threadIdx.x;
  const float* xb = x + (size_t)b * 3 * NPTS;
  float a = xb[n], bb = xb[NPTS + n], c = xb[2 * NPTS + n];
  xx[b * NPTS + n] = a * a + bb * bb + c * c;
}

// ---- knn: 8 queries/block, 16 KB LDS two-round handoff; extraction via packed
// 42-bit keys (su<<10|j), per-lane top-2 tournament + u64 min-butterfly + promote.
// Tie order (score asc, j asc) identical to lax.top_k stable semantics.
template<int C>
__global__ __launch_bounds__(256)
void knn_cn_kernel(const float* __restrict__ Xt, long sb,
                   const float* __restrict__ xx, int* __restrict__ idxout) {
  __shared__ float sc4[4][NPTS];   // 16 KB
  const int b = blockIdx.y, i0 = blockIdx.x * 8;
  const int tid = threadIdx.x;
  const float* Xb = Xt + (size_t)b * sb;
  const int j0 = tid * 4;
  float acc[8][4];
  #pragma unroll
  for (int q = 0; q < 8; ++q)
    #pragma unroll
    for (int u = 0; u < 4; ++u) acc[q][u] = 0.f;
  for (int c = 0; c < C; ++c) {
    const float4 xv = *reinterpret_cast<const float4*>(Xb + (size_t)c * NPTS + j0);
    const float* xr = Xb + (size_t)c * NPTS + i0;   // uniform addresses -> scalar loads
    #pragma unroll
    for (int q = 0; q < 8; ++q) {
      const float xiq = xr[q];
      acc[q][0] = fmaf(xiq, xv.x, acc[q][0]);
      acc[q][1] = fmaf(xiq, xv.y, acc[q][1]);
      acc[q][2] = fmaf(xiq, xv.z, acc[q][2]);
      acc[q][3] = fmaf(xiq, xv.w, acc[q][3]);
    }
  }
  const float4 xxj = *reinterpret_cast<const float4*>(xx + b * NPTS + j0);
  const int wv = tid >> 6, lane = tid & 63;
  unsigned ku0[16], ku1[16];

  // round A: queries 0..3
  #pragma unroll
  for (int q = 0; q < 4; ++q) {
    float4 st;
    st.x = fmaf(-2.f, acc[q][0], xxj.x);
    st.y = fmaf(-2.f, acc[q][1], xxj.y);
    st.z = fmaf(-2.f, acc[q][2], xxj.z);
    st.w = fmaf(-2.f, acc[q][3], xxj.w);
    *reinterpret_cast<float4*>(&sc4[q][j0]) = st;
  }
  __syncthreads();
  #pragma unroll
  for (int s = 0; s < 16; ++s) {
    const unsigned u = __float_as_uint(sc4[wv][lane + 64 * s]);
    ku0[s] = u ^ ((unsigned)((int)u >> 31) | 0x80000000u);
  }
  __syncthreads();
  // round B: queries 4..7 reuse the LDS
  #pragma unroll
  for (int q = 4; q < 8; ++q) {
    float4 st;
    st.x = fmaf(-2.f, acc[q][0], xxj.x);
    st.y = fmaf(-2.f, acc[q][1], xxj.y);
    st.z = fmaf(-2.f, acc[q][2], xxj.z);
    st.w = fmaf(-2.f, acc[q][3], xxj.w);
    *reinterpret_cast<float4*>(&sc4[q - 4][j0]) = st;
  }
  __syncthreads();
  #pragma unroll
  for (int s = 0; s < 16; ++s) {
    const unsigned u = __float_as_uint(sc4[wv][lane + 64 * s]);
    ku1[s] = u ^ ((unsigned)((int)u >> 31) | 0x80000000u);
  }

  // per-lane top-2 tournaments (value + slot), strict < keeps earlier slot on tie
  unsigned b1v0 = 0xFFFFFFFFu, b2v0 = 0xFFFFFFFFu; int b1s0 = 0, b2s0 = 0;
  unsigned b1v1 = 0xFFFFFFFFu, b2v1 = 0xFFFFFFFFu; int b1s1 = 0, b2s1 = 0;
  #pragma unroll
  for (int s = 0; s < 16; ++s) {
    const unsigned s0 = ku0[s], s1 = ku1[s];
    const bool a1 = s0 < b1v0, a2 = s0 < b2v0;
    const unsigned na1 = a1 ? s0 : b1v0;  const int nas1 = a1 ? s : b1s0;
    const unsigned na2 = a1 ? b1v0 : (a2 ? s0 : b2v0);
    const int nas2 = a1 ? b1s0 : (a2 ? s : b2s0);
    b1v0 = na1; b1s0 = nas1; b2v0 = na2; b2s0 = nas2;
    const bool c1c = s1 < b1v1, c2c = s1 < b2v1;
    const unsigned nc1 = c1c ? s1 : b1v1;  const int ncs1 = c1c ? s : b1s1;
    const unsigned nc2 = c1c ? b1v1 : (c2c ? s1 : b2v1);
    const int ncs2 = c1c ? b1s1 : (c2c ? s : b2s1);
    b1v1 = nc1; b1s1 = ncs1; b2v1 = nc2; b2s1 = ncs2;
  }
  const ull INV = ~0ull;
  ull c10 = ((ull)b1v0 << 10) | (unsigned)(lane + (b1s0 << 6));
  ull c20 = ((ull)b2v0 << 10) | (unsigned)(lane + (b2s0 << 6));
  ull c11 = ((ull)b1v1 << 10) | (unsigned)(lane + (b1s1 << 6));
  ull c21 = ((ull)b2v1 << 10) | (unsigned)(lane + (b2s1 << 6));

  int my0 = 0, my1 = 0;
  for (int t = 0; t < KNN; ++t) {
    ull w0 = c10, w1 = c11;
    #pragma unroll
    for (int off = 32; off > 0; off >>= 1) {
      const ull o0 = __shfl_xor(w0, off);
      const ull o1 = __shfl_xor(w1, off);
      w0 = o0 < w0 ? o0 : w0;
      w1 = o1 < w1 ? o1 : w1;
    }
    if (lane == t) { my0 = (int)(w0 & 1023u); my1 = (int)(w1 & 1023u); }
    const bool win0 = (c10 == w0), win1 = (c11 == w1);
    c10 = win0 ? c20 : c10;  c20 = win0 ? INV : c20;
    c11 = win1 ? c21 : c11;  c21 = win1 ? INV : c21;
    if (__any((c10 == INV) || (c11 == INV))) {
      if (c10 == INV) {   // 3rd+ win of this lane: alive == key > w0 (keys unique, W increasing)
        ull m = INV;
        #pragma unroll
        for (int s = 0; s < 16; ++s) {
          const ull kk = ((ull)ku0[s] << 10) | (unsigned)(lane + (s << 6));
          if (kk > w0 && kk < m) m = kk;
        }
        c10 = (m == INV) ? (INV - 1 - (ull)lane) : m;
      }
      if (c11 == INV) {
        ull m = INV;
        #pragma unroll
        for (int s = 0; s < 16; ++s) {
          const ull kk = ((ull)ku1[s] << 10) | (unsigned)(lane + (s << 6));
          if (kk > w1 && kk < m) m = kk;
        }
        c11 = (m == INV) ? (INV - 1 - (ull)lane) : m;
      }
    }
  }
  if (lane < KNN) {
    idxout[(size_t)(b * NPTS + i0 + wv) * KNN + lane] = my0;
    idxout[(size_t)(b * NPTS + i0 + wv + 4) * KNN + lane] = my1;
  }
}

// ---- 64-tile fp32 GEMM (small conv layers feeding knn paths) ----
__global__ __launch_bounds__(256)
void gemm_kernel(const float* __restrict__ X, long sxb, int sxn, int sxc,
                 const float* __restrict__ WT, int ldW, int C,
                 float* __restrict__ out, int sob, int son) {
  __shared__ __align__(16) float Xs[16][64];
  __shared__ __align__(16) float Ws[16][64];
  const int b = blockIdx.z;
  const int n0 = blockIdx.x * 64, o0 = blockIdx.y * 64;
  const int tid = threadIdx.x;
  const int lr = tid & 63;
  const int c4 = (tid >> 6) * 4;
  const int tn = tid & 15, to = tid >> 4;
  float acc[4][4];
  #pragma unroll
  for (int i = 0; i < 4; ++i)
    #pragma unroll
    for (int j = 0; j < 4; ++j) acc[i][j] = 0.f;

  const size_t xbase = (size_t)b * sxb;
  for (int k0 = 0; k0 < C; k0 += 16) {
    #pragma unroll
    for (int u = 0; u < 4; ++u) {
      int c = k0 + c4 + u;
      float xv = 0.f, wv = 0.f;
      if (c < C) {
        xv = X[xbase + (size_t)(n0 + lr) * sxn + (size_t)c * sxc];
        wv = WT[(size_t)c * ldW + o0 + lr];
      }
      Xs[c4 + u][lr] = xv;
      Ws[c4 + u][lr] = wv;
    }
    __syncthreads();
    #pragma unroll
    for (int kk = 0; kk < 16; ++kk) {
      const float4 xa = *reinterpret_cast<const float4*>(&Xs[kk][tn * 4]);
      const float4 wb = *reinterpret_cast<const float4*>(&Ws[kk][to * 4]);
      const float xr[4] = {xa.x, xa.y, xa.z, xa.w};
      const float wr[4] = {wb.x, wb.y, wb.z, wb.w};
      #pragma unroll
      for (int i = 0; i < 4; ++i)
        #pragma unroll
        for (int j = 0; j < 4; ++j) acc[i][j] = fmaf(xr[i], wr[j], acc[i][j]);
    }
    __syncthreads();
  }
  #pragma unroll
  for (int i = 0; i < 4; ++i) {
    float4 st = make_float4(acc[i][0], acc[i][1], acc[i][2], acc[i][3]);
    *reinterpret_cast<float4*>(&out[(size_t)b * sob + (size_t)(n0 + tn * 4 + i) * son + o0 + to * 4]) = st;
  }
}

// ---- 128x128 fp32 GEMM (tw3 path only; X channel-major) ----
template<int EPI>
__global__ __launch_bounds__(256)
void gemm128_kernel(const float* __restrict__ X, long sxb, int scN,
                    const float* __restrict__ WT, int ldW, int C,
                    float* __restrict__ out, int sob, int son, int snb) {
  __shared__ __align__(16) float Xs[16][128];
  __shared__ __align__(16) float Ws[16][128];
  __shared__ __align__(16) float red[16][132];
  const int b = blockIdx.z;
  const int n0 = blockIdx.x * 128, o0 = blockIdx.y * 128;
  const int tid = threadIdx.x;
  const int tn = tid & 15, to = tid >> 4;
  float acc[8][8];
  #pragma unroll
  for (int i = 0; i < 8; ++i)
    #pragma unroll
    for (int j = 0; j < 8; ++j) acc[i][j] = 0.f;

  const size_t xbase = (size_t)b * sxb;
  for (int c0 = 0; c0 < C; c0 += 16) {
    #pragma unroll
    for (int it = 0; it < 2; ++it) {
      const int task = tid + it * 256;
      const int kk = task >> 5, n4 = (task & 31) * 4;
      *reinterpret_cast<float4*>(&Xs[kk][n4]) =
        *reinterpret_cast<const float4*>(&X[xbase + (size_t)(c0 + kk) * scN + n0 + n4]);
      *reinterpret_cast<float4*>(&Ws[kk][n4]) =
        *reinterpret_cast<const float4*>(&WT[(size_t)(c0 + kk) * ldW + o0 + n4]);
    }
    __syncthreads();
    #pragma unroll
    for (int kk = 0; kk < 16; ++kk) {
      const float4 xa0 = *reinterpret_cast<const float4*>(&Xs[kk][tn * 4]);
      const float4 xa1 = *reinterpret_cast<const float4*>(&Xs[kk][64 + tn * 4]);
      const float4 wb0 = *reinterpret_cast<const float4*>(&Ws[kk][to * 4]);
      const float4 wb1 = *reinterpret_cast<const float4*>(&Ws[kk][64 + to * 4]);
      const float xr[8] = {xa0.x, xa0.y, xa0.z, xa0.w, xa1.x, xa1.y, xa1.z, xa1.w};
      const float wr[8] = {wb0.x, wb0.y, wb0.z, wb0.w, wb1.x, wb1.y, wb1.z, wb1.w};
      #pragma unroll
      for (int i = 0; i < 8; ++i)
        #pragma unroll
        for (int j = 0; j < 8; ++j) acc[i][j] = fmaf(xr[i], wr[j], acc[i][j]);
    }
    __syncthreads();
  }

  if (EPI == 0) {
    #pragma unroll
    for (int i = 0; i < 8; ++i) {
      const int n = n0 + (i >> 2) * 64 + tn * 4 + (i & 3);
      float4 s0 = make_float4(acc[i][0], acc[i][1], acc[i][2], acc[i][3]);
      float4 s1 = make_float4(acc[i][4], acc[i][5], acc[i][6], acc[i][7]);
      *reinterpret_cast<float4*>(&out[(size_t)b * sob + (size_t)n * son + o0 + to * 4]) = s0;
      *reinterpret_cast<float4*>(&out[(size_t)b * sob + (size_t)n * son + o0 + 64 + to * 4]) = s1;
    }
  } else {
    #pragma unroll
    for (int j = 0; j < 8; ++j) {
      float m = lrelu(acc[0][j]);
      #pragma unroll
      for (int i = 1; i < 8; ++i) m = fmaxf(m, lrelu(acc[i][j]));
      red[tn][(j >> 2) * 64 + to * 4 + (j & 3)] = m;
    }
    __syncthreads();
    if (tid < 128) {
      float m = red[0][tid];
      #pragma unroll
      for (int t = 1; t < 16; ++t) m = fmaxf(m, red[t][tid]);
      out[(size_t)b * sob + (size_t)blockIdx.x * snb + o0 + tid] = m;
    }
  }
}

// ---- bf16 MFMA GEMM ----
template<int EPI>
__global__ __launch_bounds__(256)
void gemm_mfma_kernel(const ushort* __restrict__ Xg, long sxb, int ldX,
                      const ushort* __restrict__ Wg, int ldW, int K,
                      float* __restrict__ out, long sob, int son, int snb) {
  __shared__ __align__(16) ushort As[128 * 64];
  __shared__ __align__(16) ushort Bs[128 * 64];
  __shared__ float red[2][128];
  const int b = blockIdx.z;
  const int n0 = blockIdx.x * 128, o0 = blockIdx.y * 128;
  const int tid = threadIdx.x;
  const int lane = tid & 63;
  const int wrow = (tid >> 6) >> 1, wcol = (tid >> 6) & 1;
  f32x4 acc[4][4];
  #pragma unroll
  for (int i = 0; i < 4; ++i)
    #pragma unroll
    for (int j = 0; j < 4; ++j)
      #pragma unroll
      for (int r = 0; r < 4; ++r) acc[i][j][r] = 0.f;

  const ushort* Xb = Xg + (size_t)b * sxb;
  for (int kb = 0; kb < K; kb += 64) {
    #pragma unroll
    for (int i = 0; i < 4; ++i) {
      const int idx = i * 256 + tid;
      const int n = idx >> 3, kc = idx & 7;
      const bf16x8 xv = *reinterpret_cast<const bf16x8*>(&Xb[(size_t)(n0 + n) * ldX + kb + kc * 8]);
      const bf16x8 wv = *reinterpret_cast<const bf16x8*>(&Wg[(size_t)(o0 + n) * ldW + kb + kc * 8]);
      const int ad = n * 128 + ((kc * 16) ^ ((n & 7) << 4));
      *reinterpret_cast<bf16x8*>((char*)As + ad) = xv;
      *reinterpret_cast<bf16x8*>((char*)Bs + ad) = wv;
    }
    __syncthreads();
    #pragma unroll
    for (int s = 0; s < 2; ++s) {
      bf16x8 af[4], bfr[4];
      const int klane = (s * 64 + ((lane >> 4) << 4));
      #pragma unroll
      for (int f = 0; f < 4; ++f) {
        const int nl = wrow * 64 + f * 16 + (lane & 15);
        af[f] = *reinterpret_cast<const bf16x8*>((char*)As + nl * 128 + (klane ^ ((nl & 7) << 4)));
        const int ol = wcol * 64 + f * 16 + (lane & 15);
        bfr[f] = *reinterpret_cast<const bf16x8*>((char*)Bs + ol * 128 + (klane ^ ((ol & 7) << 4)));
      }
      #pragma unroll
      for (int i = 0; i < 4; ++i)
        #pragma unroll
        for (int j = 0; j < 4; ++j)
          acc[i][j] = __builtin_amdgcn_mfma_f32_16x16x32_bf16(af[i], bfr[j], acc[i][j], 0, 0, 0);
    }
    __syncthreads();
  }

  if (EPI == 0) {
    #pragma unroll
    for (int i = 0; i < 4; ++i)
      #pragma unroll
      for (int r = 0; r < 4; ++r) {
        const int n = n0 + wrow * 64 + i * 16 + ((lane >> 4) << 2) + r;
        #pragma unroll
        for (int j = 0; j < 4; ++j) {
          const int o = o0 + wcol * 64 + j * 16 + (lane & 15);
          out[(size_t)b * sob + (size_t)n * son + o] = acc[i][j][r];
        }
      }
  } else {
    #pragma unroll
    for (int j = 0; j < 4; ++j) {
      float m = -3.4e38f;
      #pragma unroll
      for (int i = 0; i < 4; ++i)
        #pragma unroll
        for (int r = 0; r < 4; ++r) m = fmaxf(m, lrelu(acc[i][j][r]));
      m = fmaxf(m, __shfl_xor(m, 16));
      m = fmaxf(m, __shfl_xor(m, 32));
      if (lane < 16) red[wrow][wcol * 64 + j * 16 + lane] = m;
    }
    __syncthreads();
    if (tid < 128) {
      float m = fmaxf(red[0][tid], red[1][tid]);
      out[(size_t)b * sob + (size_t)blockIdx.x * snb + o0 + tid] = m;
    }
  }
}

// ---- edge max, channel-major fp32 output + NC bf16 copy for MFMA consumers ----
template<int O, int TI>
__global__ __launch_bounds__(256)
void edge_max_cn_kernel(const float* __restrict__ y, const float* __restrict__ z,
                        const int* __restrict__ idx, float* __restrict__ outCN,
                        float* __restrict__ xx, ushort* __restrict__ xbf, int choff) {
  __shared__ float tile[TI][O + 1];
  const int b = blockIdx.y;
  const int i0 = blockIdx.x * TI;
  const int wv = threadIdx.x >> 6, lane = threadIdx.x & 63;
  constexpr int OSEG = O / 64;
  constexpr int ROUNDS = TI * OSEG / 4;
  for (int r = 0; r < ROUNDS; ++r) {
    const int item = r * 4 + wv;
    const int il = item / OSEG, os = item - il * OSEG;
    const int i = i0 + il, o = os * 64 + lane;
    const int* ip = idx + (size_t)(b * NPTS + i) * KNN;
    const float zv = z[(size_t)(b * NPTS + i) * O + o];
    float m = -3.4e38f;
    #pragma unroll
    for (int t = 0; t < KNN; ++t) {
      int j = ip[t];
      float v = y[(size_t)(b * NPTS + j) * O + o] + zv;
      m = fmaxf(m, lrelu(v));
    }
    tile[il][o] = m;
    xbf[(size_t)(b * NPTS + i) * 512 + choff + o] = f2bf(m);
  }
  __syncthreads();
  if (xx != nullptr && threadIdx.x < TI) {
    const int il = threadIdx.x;
    float s = 0.f;
    #pragma unroll
    for (int o = 0; o < O; ++o) { float v = tile[il][o]; s = fmaf(v, v, s); }
    xx[b * NPTS + i0 + il] = s;
  }
  for (int e = threadIdx.x; e < TI * O; e += 256) {
    const int o = e / TI, il = e - o * TI;
    outCN[(size_t)b * 512 * NPTS + (size_t)o * NPTS + i0 + il] = tile[il][o];
  }
}

// ---- h12 as edge-GEMM ----
__global__ __launch_bounds__(256)
void h12_gemm_kernel(const float* __restrict__ ya, const float* __restrict__ zb,
                     const int* __restrict__ idx, const float* __restrict__ tw2T,
                     float* __restrict__ h2m) {
  __shared__ __align__(16) float h1s[80][68];
  __shared__ __align__(16) float ws[64][128];
  __shared__ __align__(16) float zbs[4][64];
  __shared__ float ot[128][4];
  __shared__ int idxs[4][KNN];
  const int b = blockIdx.y;
  const int i0 = blockIdx.x * 4;
  const int tid = threadIdx.x;

  #pragma unroll
  for (int it = 0; it < 8; ++it) {
    const int f = tid + it * 256;
    *reinterpret_cast<float4*>(&ws[0][0] + f * 4) =
      *reinterpret_cast<const float4*>(tw2T + (size_t)f * 4);
  }
  if (tid < 64) {
    const int p = tid >> 4, cq = (tid & 15) * 4;
    *reinterpret_cast<float4*>(&zbs[p][cq]) =
      *reinterpret_cast<const float4*>(&zb[(size_t)(b * NPTS + i0 + p) * 64 + cq]);
  }
  if (tid >= 64 && tid < 64 + 4 * KNN) {
    const int e = tid - 64;
    idxs[e / KNN][e % KNN] = idx[(size_t)(b * NPTS + i0) * KNN + e];
  }
  __syncthreads();

  #pragma unroll
  for (int it = 0; it < 5; ++it) {
    const int task = tid + it * 256;
    const int e = task >> 4, cq = (task & 15) * 4;
    const int p = e / KNN, t = e - p * KNN;
    const int j = idxs[p][t];
    const float4 yv = *reinterpret_cast<const float4*>(&ya[(size_t)(b * NPTS + j) * 64 + cq]);
    const float4 zv = *reinterpret_cast<const float4*>(&zbs[p][cq]);
    float4 hv;
    hv.x = lrelu(yv.x + zv.x); hv.y = lrelu(yv.y + zv.y);
    hv.z = lrelu(yv.z + zv.z); hv.w = lrelu(yv.w + zv.w);
    *reinterpret_cast<float4*>(&h1s[e][cq]) = hv;
  }
  __syncthreads();

  const int eg = tid >> 4, og = tid & 15;
  float acc[5][8];
  #pragma unroll
  for (int u = 0; u < 5; ++u)
    #pragma unroll
    for (int v = 0; v < 8; ++v) acc[u][v] = 0.f;
  #pragma unroll 4
  for (int kk = 0; kk < 64; ++kk) {
    float hv[5];
    #pragma unroll
    for (int u = 0; u < 5; ++u) hv[u] = h1s[eg * 5 + u][kk];
    const float4 w0 = *reinterpret_cast<const float4*>(&ws[kk][og * 4]);
    const float4 w1 = *reinterpret_cast<const float4*>(&ws[kk][64 + og * 4]);
    const float wr[8] = {w0.x, w0.y, w0.z, w0.w, w1.x, w1.y, w1.z, w1.w};
    #pragma unroll
    for (int u = 0; u < 5; ++u)
      #pragma unroll
      for (int v = 0; v < 8; ++v) acc[u][v] = fmaf(hv[u], wr[v], acc[u][v]);
  }

  const int p = eg >> 2, d = eg & 3;
  float m[8];
  #pragma unroll
  for (int v = 0; v < 8; ++v) {
    float mm = lrelu(acc[0][v]);
    #pragma unroll
    for (int u = 1; u < 5; ++u) mm = fmaxf(mm, lrelu(acc[u][v]));
    mm = fmaxf(mm, __shfl_xor(mm, 16));
    mm = fmaxf(mm, __shfl_xor(mm, 32));
    m[v] = mm;
  }
  if (d == 0) {
    #pragma unroll
    for (int v = 0; v < 8; ++v) {
      const int o = og * 4 + (v & 3) + (v >> 2) * 64;
      ot[o][p] = m[v];
    }
  }
  __syncthreads();
  if (tid < 128) {
    float4 st = make_float4(ot[tid][0], ot[tid][1], ot[tid][2], ot[tid][3]);
    *reinterpret_cast<float4*>(&h2m[(size_t)(b * 128 + tid) * NPTS + i0]) = st;
  }
}

// ---- reduce partial max over nt n-tiles ----
__global__ __launch_bounds__(256)
void reduce_max_kernel(const float* __restrict__ part, float* __restrict__ outp, int nt) {
  const int b = blockIdx.y;
  const int o = blockIdx.x * 256 + threadIdx.x;
  float m = part[(size_t)(b * nt) * 1024 + o];
  for (int t = 1; t < nt; ++t) m = fmaxf(m, part[(size_t)(b * nt + t) * 1024 + o]);
  outp[b * 1024 + o] = m;
}

// ---- block reduce helper ----
__device__ __forceinline__ float block_reduce_sum(float v, float* rbuf) {
  #pragma unroll
  for (int off = 32; off > 0; off >>= 1) v += __shfl_xor(v, off);
  const int w = threadIdx.x >> 6, lane = threadIdx.x & 63;
  const int nw = blockDim.x >> 6;
  if (lane == 0) rbuf[w] = v;
  __syncthreads();
  float tot = 0.f;
  for (int i = 0; i < nw; ++i) tot += rbuf[i];
  __syncthreads();
  return tot;
}

// ---- fc1 ----
__global__ __launch_bounds__(256)
void fc1_kernel(const float* __restrict__ gin_g, const float* __restrict__ Wt,
                const float* __restrict__ gam, const float* __restrict__ bet,
                float* __restrict__ outp) {
  __shared__ __align__(16) float gin[1024];
  __shared__ float hbuf[512];
  __shared__ float rbuf[8];
  const int b = blockIdx.x, tid = threadIdx.x;
  for (int e = tid; e < 1024; e += 256) gin[e] = gin_g[b * 1024 + e];
  __syncthreads();
  float ps = 0.f;
  for (int e = tid; e < 1024; e += 256) ps = fmaf(gin[e], gin[e], ps);
  float ss = block_reduce_sum(ps, rbuf);
  float rinv = 1.0f / sqrtf(ss);
  #pragma unroll
  for (int r = 0; r < 2; ++r) {
    int o = tid + r * 256;
    const float* wrow = Wt + (size_t)o * 1024;
    float a = 0.f;
    for (int c4 = 0; c4 < 256; ++c4) {
      float4 wv = *reinterpret_cast<const float4*>(wrow + c4 * 4);
      float4 gv = *reinterpret_cast<const float4*>(&gin[c4 * 4]);
      a = fmaf(wv.x, gv.x, a); a = fmaf(wv.y, gv.y, a);
      a = fmaf(wv.z, gv.z, a); a = fmaf(wv.w, gv.w, a);
    }
    hbuf[o] = a * rinv;
  }
  __syncthreads();
  float pm = hbuf[tid] + hbuf[tid + 256];
  float mean = block_reduce_sum(pm, rbuf) * (1.f / 512.f);
  float d0 = hbuf[tid] - mean, d1 = hbuf[tid + 256] - mean;
  float var = block_reduce_sum(d0 * d0 + d1 * d1, rbuf) * (1.f / 512.f);
  float rs = 1.0f / sqrtf(var + 1e-5f);
  #pragma unroll
  for (int r = 0; r < 2; ++r) {
    int o = tid + r * 256;
    float yv = (hbuf[o] - mean) * rs * gam[o] + bet[o];
    outp[b * 512 + o] = lrelu(yv);
  }
}

// ---- fc2 ----
__global__ __launch_bounds__(256)
void fc2_kernel(const float* __restrict__ inp, const float* __restrict__ Wt,
                const float* __restrict__ bias, const float* __restrict__ gam,
                const float* __restrict__ bet, float* __restrict__ outp) {
  __shared__ __align__(16) float gin[512];
  __shared__ float rbuf[8];
  const int b = blockIdx.x, tid = threadIdx.x;
  for (int e = tid; e < 512; e += 256) gin[e] = inp[b * 512 + e];
  __syncthreads();
  float ps = 0.f;
  for (int e = tid; e < 512; e += 256) ps = fmaf(gin[e], gin[e], ps);
  float ss = block_reduce_sum(ps, rbuf);
  float rinv = 1.0f / sqrtf(ss);
  const float* wrow = Wt + (size_t)tid * 512;
  float a = 0.f;
  for (int c4 = 0; c4 < 128; ++c4) {
    float4 wv = *reinterpret_cast<const float4*>(wrow + c4 * 4);
    float4 gv = *reinterpret_cast<const float4*>(&gin[c4 * 4]);
    a = fmaf(wv.x, gv.x, a); a = fmaf(wv.y, gv.y, a);
    a = fmaf(wv.z, gv.z, a); a = fmaf(wv.w, gv.w, a);
  }
  a = a * rinv + bias[tid];
  float mean = block_reduce_sum(a, rbuf) * (1.f / 256.f);
  float d = a - mean;
  float var = block_reduce_sum(d * d, rbuf) * (1.f / 256.f);
  float rs = 1.0f / sqrtf(var + 1e-5f);
  float yv = (a - mean) * rs * gam[tid] + bet[tid];
  outp[b * 256 + tid] = lrelu(yv);
}

// ---- fc3 + identity ----
__global__ __launch_bounds__(64)
void fc3_kernel(const float* __restrict__ inp, const float* __restrict__ Wt,
                const float* __restrict__ bias, float* __restrict__ tmat) {
  __shared__ float gin[256];
  const int b = blockIdx.x, tid = threadIdx.x;
  for (int e = tid; e < 256; e += 64) gin[e] = inp[b * 256 + e];
  __syncthreads();
  if (tid < 9) {
    const float* wrow = Wt + tid * 256;
    float a = 0.f;
    for (int c = 0; c < 256; ++c) a = fmaf(wrow[c], gin[c], a);
    a += bias[tid];
    if (tid == 0 || tid == 4 || tid == 8) a += 1.f;
    tmat[b * 9 + tid] = a;
  }
}

// ---- apply 3x3 transform ----
__global__ __launch_bounds__(256)
void xform_kernel(const float* __restrict__ x, const float* __restrict__ tmat,
                  float* __restrict__ xt) {
  const int b = blockIdx.y;
  const int n = blockIdx.x * 256 + threadIdx.x;
  const float* xb = x + (size_t)b * 3 * NPTS;
  const float x0 = xb[n], x1 = xb[NPTS + n], x2 = xb[2 * NPTS + n];
  const float* t = tmat + b * 9;
  float* ob = xt + (size_t)b * 3 * NPTS;
  #pragma unroll
  for (int i = 0; i < 3; ++i)
    ob[i * NPTS + n] = fmaf(t[3 * i], x0, fmaf(t[3 * i + 1], x1, t[3 * i + 2] * x2));
}

extern "C" void kernel_launch(void* const* d_in, const int* in_sizes, int n_in,
                              void* d_out, int out_size, void* d_ws, size_t ws_size,
                              hipStream_t stream) {
  (void)in_sizes; (void)n_in; (void)out_size; (void)ws_size;
  const float* x       = (const float*)d_in[0];
  const float* tw1     = (const float*)d_in[1];
  const float* tw2     = (const float*)d_in[2];
  const float* tw3     = (const float*)d_in[3];
  const float* tfc1_w  = (const float*)d_in[4];
  const float* tfc1_g  = (const float*)d_in[5];
  const float* tfc1_b  = (const float*)d_in[6];
  const float* tfc2_w  = (const float*)d_in[7];
  const float* tfc2_bias = (const float*)d_in[8];
  const float* tfc2_g  = (const float*)d_in[9];
  const float* tfc2_b  = (const float*)d_in[10];
  const float* tfc3_w  = (const float*)d_in[11];
  const float* tfc3_b  = (const float*)d_in[12];
  const float* w1      = (const float*)d_in[13];
  const float* w2      = (const float*)d_in[14];
  const float* w3      = (const float*)d_in[15];
  const float* w4      = (const float*)d_in[16];
  const float* w5      = (const float*)d_in[17];
  float* out = (float*)d_out;

  char* wsb = (char*)d_ws;
  size_t off = 0;
  auto alloc = [&](size_t bytes) -> void* {
    void* p = wsb + off;
    off += (bytes + 255) & ~(size_t)255;
    return p;
  };
  float* ybuf = (float*)alloc((size_t)BATCH * NPTS * 256 * 4);
  float* zbuf = (float*)alloc((size_t)BATCH * NPTS * 256 * 4);
  float* xcT  = (float*)alloc((size_t)BATCH * 512 * NPTS * 4);   // channel-major fp32 (knn)
  ushort* xc_bf = (ushort*)alloc((size_t)BATCH * NPTS * 512 * 2); // NC bf16 (MFMA)
  float* h2m  = (float*)alloc((size_t)BATCH * 128 * NPTS * 4);
  float* part = (float*)alloc((size_t)BATCH * 16 * 1024 * 4);
  int*   idxb = (int*)alloc((size_t)BATCH * NPTS * KNN * 4);
  float* xxb  = (float*)alloc((size_t)BATCH * NPTS * 4);
  float* xt   = (float*)alloc((size_t)BATCH * 3 * NPTS * 4);
  float* gbuf = (float*)alloc((size_t)BATCH * 1024 * 4);
  float* f1o  = (float*)alloc((size_t)BATCH * 512 * 4);
  float* f2o  = (float*)alloc((size_t)BATCH * 256 * 4);
  float* tmat = (float*)alloc((size_t)BATCH * 9 * 4);
  float* tw1aT = (float*)alloc(3 * 64 * 4);
  float* tw1dT = (float*)alloc(3 * 64 * 4);
  float* w1aT  = (float*)alloc(3 * 64 * 4);
  float* w1dT  = (float*)alloc(3 * 64 * 4);
  float* w2aT  = (float*)alloc(64 * 64 * 4);
  float* w2dT  = (float*)alloc(64 * 64 * 4);
  float* w3aT  = (float*)alloc(64 * 128 * 4);
  float* w3dT  = (float*)alloc(64 * 128 * 4);
  ushort* w4a_bf = (ushort*)alloc(256 * 128 * 2);
  ushort* w4d_bf = (ushort*)alloc(256 * 128 * 2);
  ushort* w5_bf  = (ushort*)alloc(1024 * 512 * 2);
  float* tw2T  = (float*)alloc(64 * 128 * 4);
  float* tw3T  = (float*)alloc(128 * 1024 * 4);

  // weight prep
  wsplit_t_kernel<<<1, 256, 0, stream>>>(tw1, tw1aT, tw1dT, 64, 3);
  wsplit_t_kernel<<<1, 256, 0, stream>>>(w1, w1aT, w1dT, 64, 3);
  wsplit_t_kernel<<<16, 256, 0, stream>>>(w2, w2aT, w2dT, 64, 64);
  wsplit_t_kernel<<<32, 256, 0, stream>>>(w3, w3aT, w3dT, 128, 64);
  wsplit_bf_kernel<<<128, 256, 0, stream>>>(w4, w4a_bf, w4d_bf, 256, 128);
  cvt_bf16_kernel<<<2048, 256, 0, stream>>>(w5, w5_bf, 1024 * 512);
  wtrans_kernel<<<32, 256, 0, stream>>>(tw2, tw2T, 128, 64);
  wtrans_kernel<<<512, 256, 0, stream>>>(tw3, tw3T, 1024, 128);

  // ---- transform net ----
  xx3_kernel<<<dim3(4, 16), 256, 0, stream>>>(x, xxb);
  knn_cn_kernel<3><<<dim3(128, 16), 256, 0, stream>>>(x, 3 * NPTS, xxb, idxb);
  gemm_kernel<<<dim3(16, 1, 16), 256, 0, stream>>>(x, 3 * NPTS, 1, NPTS, tw1aT, 64, 3,
                                                   ybuf, NPTS * 64, 64);
  gemm_kernel<<<dim3(16, 1, 16), 256, 0, stream>>>(x, 3 * NPTS, 1, NPTS, tw1dT, 64, 3,
                                                   zbuf, NPTS * 64, 64);
  h12_gemm_kernel<<<dim3(256, 16), 256, 0, stream>>>(ybuf, zbuf, idxb, tw2T, h2m);
  gemm128_kernel<1><<<dim3(8, 8, 16), 256, 0, stream>>>(h2m, 128 * NPTS, NPTS, tw3T, 1024, 128,
                                                        part, 8 * 1024, 0, 1024);
  reduce_max_kernel<<<dim3(4, 16), 256, 0, stream>>>(part, gbuf, 8);
  fc1_kernel<<<16, 256, 0, stream>>>(gbuf, tfc1_w, tfc1_g, tfc1_b, f1o);
  fc2_kernel<<<16, 256, 0, stream>>>(f1o, tfc2_w, tfc2_bias, tfc2_g, tfc2_b, f2o);
  fc3_kernel<<<16, 64, 0, stream>>>(f2o, tfc3_w, tfc3_b, tmat);
  xform_kernel<<<dim3(4, 16), 256, 0, stream>>>(x, tmat, xt);

  // ---- EdgeConv 1 (C=3 -> O=64) on xt ----
  xx3_kernel<<<dim3(4, 16), 256, 0, stream>>>(xt, xxb);
  knn_cn_kernel<3><<<dim3(128, 16), 256, 0, stream>>>(xt, 3 * NPTS, xxb, idxb);
  gemm_kernel<<<dim3(16, 1, 16), 256, 0, stream>>>(xt, 3 * NPTS, 1, NPTS, w1aT, 64, 3,
                                                   ybuf, NPTS * 64, 64);
  gemm_kernel<<<dim3(16, 1, 16), 256, 0, stream>>>(xt, 3 * NPTS, 1, NPTS, w1dT, 64, 3,
                                                   zbuf, NPTS * 64, 64);
  edge_max_cn_kernel<64, 64><<<dim3(16, 16), 256, 0, stream>>>(ybuf, zbuf, idxb, xcT, xxb,
                                                               xc_bf, 0);

  // ---- EdgeConv 2 (C=64 -> O=64) ----
  knn_cn_kernel<64><<<dim3(128, 16), 256, 0, stream>>>(xcT, 512 * NPTS, xxb, idxb);
  gemm_kernel<<<dim3(16, 1, 16), 256, 0, stream>>>(xcT, 512 * NPTS, 1, NPTS, w2aT, 64, 64,
                                                   ybuf, NPTS * 64, 64);
  gemm_kernel<<<dim3(16, 1, 16), 256, 0, stream>>>(xcT, 512 * NPTS, 1, NPTS, w2dT, 64, 64,
                                                   zbuf, NPTS * 64, 64);
  edge_max_cn_kernel<64, 64><<<dim3(16, 16), 256, 0, stream>>>(ybuf, zbuf, idxb,
                                                               xcT + 64 * NPTS, xxb, xc_bf, 64);

  // ---- EdgeConv 3 (C=64 -> O=128) ----
  knn_cn_kernel<64><<<dim3(128, 16), 256, 0, stream>>>(xcT + 64 * NPTS, 512 * NPTS, xxb, idxb);
  gemm_kernel<<<dim3(16, 2, 16), 256, 0, stream>>>(xcT + 64 * NPTS, 512 * NPTS, 1, NPTS,
                                                   w3aT, 128, 64, ybuf, NPTS * 128, 128);
  gemm_kernel<<<dim3(16, 2, 16), 256, 0, stream>>>(xcT + 64 * NPTS, 512 * NPTS, 1, NPTS,
                                                   w3dT, 128, 64, zbuf, NPTS * 128, 128);
  edge_max_cn_kernel<128, 64><<<dim3(16, 16), 256, 0, stream>>>(ybuf, zbuf, idxb,
                                                                xcT + 128 * NPTS, xxb, xc_bf, 128);

  // ---- EdgeConv 4 (C=128 -> O=256): bf16 MFMA GEMMs on x3 slice (knn-safe) ----
  knn_cn_kernel<128><<<dim3(128, 16), 256, 0, stream>>>(xcT + 128 * NPTS, 512 * NPTS, xxb, idxb);
  gemm_mfma_kernel<0><<<dim3(8, 2, 16), 256, 0, stream>>>(xc_bf + 128, (long)NPTS * 512, 512,
                                                          w4a_bf, 128, 128,
                                                          ybuf, (long)NPTS * 256, 256, 0);
  gemm_mfma_kernel<0><<<dim3(8, 2, 16), 256, 0, stream>>>(xc_bf + 128, (long)NPTS * 512, 512,
                                                          w4d_bf, 128, 128,
                                                          zbuf, (long)NPTS * 256, 256, 0);
  edge_max_cn_kernel<256, 32><<<dim3(32, 16), 256, 0, stream>>>(ybuf, zbuf, idxb,
                                                                xcT + 256 * NPTS, nullptr,
                                                                xc_bf, 256);

  // ---- final: x5 = lrelu(w5 @ xc) with max over n — bf16 MFMA (knn-safe) ----
  gemm_mfma_kernel<1><<<dim3(8, 8, 16), 256, 0, stream>>>(xc_bf, (long)NPTS * 512, 512,
                                                          w5_bf, 512, 512,
                                                          part, 8 * 1024, 0, 1024);
  reduce_max_kernel<<<dim3(4, 16), 256, 0, stream>>>(part, out, 8);
}

// Round 10
// 755.382 us; speedup vs baseline: 5.3852x; 1.1063x over previous
//
#include <hip/hip_runtime.h>
#include <math.h>

#define BATCH 16
#define NPTS 1024
#define KNN 20

__device__ __forceinline__ float lrelu(float v) { return v >= 0.f ? v : 0.2f * v; }

typedef __attribute__((ext_vector_type(8))) short bf16x8;
typedef __attribute__((ext_vector_type(4))) float f32x4;
typedef unsigned long long ull;

__device__ __forceinline__ ushort f2bf(float f) {
  union { float f; unsigned u; } v; v.f = f;
  unsigned r = (v.u + 0x7FFFu + ((v.u >> 16) & 1u)) >> 16;  // RNE
  return (ushort)r;
}

// AMD canonical DPP wave-64 min reduction: row_shr 1/2/4/8 accumulate to lane15 of
// each row, bcast15/bcast31 merge rows into lane 63, readlane 63 -> uniform min.
// bound lanes keep `old` (= own value) so min is unaffected. Pure VALU, zero DS ops.
__device__ __forceinline__ unsigned wave_min_u32(unsigned v) {
  unsigned t;
  t = (unsigned)__builtin_amdgcn_update_dpp((int)v, (int)v, 0x111, 0xf, 0xf, false);
  v = t < v ? t : v;
  t = (unsigned)__builtin_amdgcn_update_dpp((int)v, (int)v, 0x112, 0xf, 0xf, false);
  v = t < v ? t : v;
  t = (unsigned)__builtin_amdgcn_update_dpp((int)v, (int)v, 0x114, 0xf, 0xf, false);
  v = t < v ? t : v;
  t = (unsigned)__builtin_amdgcn_update_dpp((int)v, (int)v, 0x118, 0xf, 0xf, false);
  v = t < v ? t : v;
  t = (unsigned)__builtin_amdgcn_update_dpp((int)v, (int)v, 0x142, 0xf, 0xf, false);
  v = t < v ? t : v;
  t = (unsigned)__builtin_amdgcn_update_dpp((int)v, (int)v, 0x143, 0xf, 0xf, false);
  v = t < v ? t : v;
  return (unsigned)__builtin_amdgcn_readlane((int)v, 63);
}

// ---- weight prep: W[O][2C] -> WaT[C][O] fp32 ; WdT[C][O] fp32 (for fp32 gemms) ----
__global__ __launch_bounds__(256)
void wsplit_t_kernel(const float* __restrict__ W, float* __restrict__ waT,
                     float* __restrict__ wdT, int O, int Cc) {
  int e = blockIdx.x * 256 + threadIdx.x;
  if (e < O * Cc) {
    int c = e / O, o = e - c * O;
    float a = W[o * 2 * Cc + c], bb = W[o * 2 * Cc + Cc + c];
    waT[e] = a; wdT[e] = bb - a;
  }
}

// ---- weight prep bf16, NON-transposed [o][c] ----
__global__ __launch_bounds__(256)
void wsplit_bf_kernel(const float* __restrict__ W, ushort* __restrict__ wa_bf,
                      ushort* __restrict__ wd_bf, int O, int Cc) {
  int e = blockIdx.x * 256 + threadIdx.x;
  if (e < O * Cc) {
    int o = e / Cc, c = e - o * Cc;
    float a = W[o * 2 * Cc + c], bb = W[o * 2 * Cc + Cc + c];
    wa_bf[e] = f2bf(a); wd_bf[e] = f2bf(bb - a);
  }
}

// ---- fp32 -> bf16 elementwise ----
__global__ __launch_bounds__(256)
void cvt_bf16_kernel(const float* __restrict__ in, ushort* __restrict__ outp, int n) {
  int e = blockIdx.x * 256 + threadIdx.x;
  if (e < n) outp[e] = f2bf(in[e]);
}

// ---- weight transpose: W[O][C] -> wT[C][O] ----
__global__ __launch_bounds__(256)
void wtrans_kernel(const float* __restrict__ W, float* __restrict__ wT, int O, int Cc) {
  int e = blockIdx.x * 256 + threadIdx.x;
  if (e < O * Cc) {
    int c = e / O, o = e - c * O;
    wT[e] = W[(size_t)o * Cc + c];
  }
}

// ---- xx[b][n] = sum_c x[b][c][n]^2 for C=3 CN input ----
__global__ __launch_bounds__(256)
void xx3_kernel(const float* __restrict__ x, float* __restrict__ xx) {
  const int b = blockIdx.y;
  const int n = blockIdx.x * 256 + threadIdx.x;
  const float* xb = x + (size_t)b * 3 * NPTS;
  float a = xb[n], bb = xb[NPTS + n], c = xb[2 * NPTS + n];
  xx[b * NPTS + n] = a * a + bb * bb + c * c;
}

// ---- knn: 8 queries/block, 16 KB LDS two-round handoff; extraction on u32
// ordered score keys: per-lane top-2 + DPP wave-min + ballot/readlane winner.
// Downstream consumers max over the k set, so extraction order is set-invariant.
template<int C>
__global__ __launch_bounds__(256)
void knn_cn_kernel(const float* __restrict__ Xt, long sb,
                   const float* __restrict__ xx, int* __restrict__ idxout) {
  __shared__ float sc4[4][NPTS];   // 16 KB
  const int b = blockIdx.y, i0 = blockIdx.x * 8;
  const int tid = threadIdx.x;
  const float* Xb = Xt + (size_t)b * sb;
  const int j0 = tid * 4;
  float acc[8][4];
  #pragma unroll
  for (int q = 0; q < 8; ++q)
    #pragma unroll
    for (int u = 0; u < 4; ++u) acc[q][u] = 0.f;
  for (int c = 0; c < C; ++c) {
    const float4 xv = *reinterpret_cast<const float4*>(Xb + (size_t)c * NPTS + j0);
    const float* xr = Xb + (size_t)c * NPTS + i0;   // uniform addresses -> scalar loads
    #pragma unroll
    for (int q = 0; q < 8; ++q) {
      const float xiq = xr[q];
      acc[q][0] = fmaf(xiq, xv.x, acc[q][0]);
      acc[q][1] = fmaf(xiq, xv.y, acc[q][1]);
      acc[q][2] = fmaf(xiq, xv.z, acc[q][2]);
      acc[q][3] = fmaf(xiq, xv.w, acc[q][3]);
    }
  }
  const float4 xxj = *reinterpret_cast<const float4*>(xx + b * NPTS + j0);
  const int wv = tid >> 6, lane = tid & 63;
  unsigned ku0[16], ku1[16];

  // round A: queries 0..3
  #pragma unroll
  for (int q = 0; q < 4; ++q) {
    float4 st;
    st.x = fmaf(-2.f, acc[q][0], xxj.x);
    st.y = fmaf(-2.f, acc[q][1], xxj.y);
    st.z = fmaf(-2.f, acc[q][2], xxj.z);
    st.w = fmaf(-2.f, acc[q][3], xxj.w);
    *reinterpret_cast<float4*>(&sc4[q][j0]) = st;
  }
  __syncthreads();
  #pragma unroll
  for (int s = 0; s < 16; ++s) {
    const unsigned u = __float_as_uint(sc4[wv][lane + 64 * s]);
    ku0[s] = u ^ ((unsigned)((int)u >> 31) | 0x80000000u);
  }
  __syncthreads();
  // round B: queries 4..7 reuse the LDS
  #pragma unroll
  for (int q = 4; q < 8; ++q) {
    float4 st;
    st.x = fmaf(-2.f, acc[q][0], xxj.x);
    st.y = fmaf(-2.f, acc[q][1], xxj.y);
    st.z = fmaf(-2.f, acc[q][2], xxj.z);
    st.w = fmaf(-2.f, acc[q][3], xxj.w);
    *reinterpret_cast<float4*>(&sc4[q - 4][j0]) = st;
  }
  __syncthreads();
  #pragma unroll
  for (int s = 0; s < 16; ++s) {
    const unsigned u = __float_as_uint(sc4[wv][lane + 64 * s]);
    ku1[s] = u ^ ((unsigned)((int)u >> 31) | 0x80000000u);
  }

  // per-lane top-2 tournaments (value + slot), strict < keeps earlier slot (smaller j)
  unsigned b1v0 = 0xFFFFFFFFu, b2v0 = 0xFFFFFFFFu; int b1s0 = 0, b2s0 = 0;
  unsigned b1v1 = 0xFFFFFFFFu, b2v1 = 0xFFFFFFFFu; int b1s1 = 0, b2s1 = 0;
  #pragma unroll
  for (int s = 0; s < 16; ++s) {
    const unsigned s0 = ku0[s], s1 = ku1[s];
    const bool a1 = s0 < b1v0, a2 = s0 < b2v0;
    const unsigned na1 = a1 ? s0 : b1v0;  const int nas1 = a1 ? s : b1s0;
    const unsigned na2 = a1 ? b1v0 : (a2 ? s0 : b2v0);
    const int nas2 = a1 ? b1s0 : (a2 ? s : b2s0);
    b1v0 = na1; b1s0 = nas1; b2v0 = na2; b2s0 = nas2;
    const bool c1c = s1 < b1v1, c2c = s1 < b2v1;
    const unsigned nc1 = c1c ? s1 : b1v1;  const int ncs1 = c1c ? s : b1s1;
    const unsigned nc2 = c1c ? b1v1 : (c2c ? s1 : b2v1);
    const int ncs2 = c1c ? b1s1 : (c2c ? s : b2s1);
    b1v1 = nc1; b1s1 = ncs1; b2v1 = nc2; b2s1 = ncs2;
  }
  const unsigned INVS = 0xFFFFFFFFu;   // > any real ordered key (finite floats)
  unsigned c1s0 = b1v0, c2s0 = b2v0;  int c1j0 = lane + (b1s0 << 6), c2j0 = lane + (b2s0 << 6);
  unsigned c1s1 = b1v1, c2s1 = b2v1;  int c1j1 = lane + (b1s1 << 6), c2j1 = lane + (b2s1 << 6);

  int my0 = 0, my1 = 0;
  for (int t = 0; t < KNN; ++t) {
    const unsigned ws0 = wave_min_u32(c1s0);
    const unsigned ws1 = wave_min_u32(c1s1);
    const int wl0 = __ffsll((long long)__ballot(c1s0 == ws0)) - 1;
    const int wl1 = __ffsll((long long)__ballot(c1s1 == ws1)) - 1;
    const int jw0 = __builtin_amdgcn_readlane(c1j0, wl0);
    const int jw1 = __builtin_amdgcn_readlane(c1j1, wl1);
    if (lane == t) { my0 = jw0; my1 = jw1; }
    const bool win0 = (lane == wl0), win1 = (lane == wl1);
    c1s0 = win0 ? c2s0 : c1s0;  c1j0 = win0 ? c2j0 : c1j0;  c2s0 = win0 ? INVS : c2s0;
    c1s1 = win1 ? c2s1 : c1s1;  c1j1 = win1 ? c2j1 : c1j1;  c2s1 = win1 ? INVS : c2s1;
    if (__any((c1s0 == INVS) || (c1s1 == INVS))) {
      if (c1s0 == INVS) {       // lane's pair consumed: refill top-2 among keys > ws0
        unsigned m1 = INVS, m2 = INVS; int r1 = 0, r2 = 0;
        #pragma unroll
        for (int s = 0; s < 16; ++s) {
          const unsigned k = ku0[s];
          const bool ok = k > ws0;
          const bool a1 = ok && (k < m1), a2 = ok && (k < m2);
          const unsigned nm1 = a1 ? k : m1;  const int nr1 = a1 ? s : r1;
          const unsigned nm2 = a1 ? m1 : (a2 ? k : m2);
          const int nr2 = a1 ? r1 : (a2 ? s : r2);
          m1 = nm1; r1 = nr1; m2 = nm2; r2 = nr2;
        }
        c1s0 = (m1 == INVS) ? 0xFFFFFFFEu : m1;  c1j0 = lane + (r1 << 6);
        c2s0 = (m2 == INVS) ? 0xFFFFFFFEu : m2;  c2j0 = lane + (r2 << 6);
      }
      if (c1s1 == INVS) {
        unsigned m1 = INVS, m2 = INVS; int r1 = 0, r2 = 0;
        #pragma unroll
        for (int s = 0; s < 16; ++s) {
          const unsigned k = ku1[s];
          const bool ok = k > ws1;
          const bool a1 = ok && (k < m1), a2 = ok && (k < m2);
          const unsigned nm1 = a1 ? k : m1;  const int nr1 = a1 ? s : r1;
          const unsigned nm2 = a1 ? m1 : (a2 ? k : m2);
          const int nr2 = a1 ? r1 : (a2 ? s : r2);
          m1 = nm1; r1 = nr1; m2 = nm2; r2 = nr2;
        }
        c1s1 = (m1 == INVS) ? 0xFFFFFFFEu : m1;  c1j1 = lane + (r1 << 6);
        c2s1 = (m2 == INVS) ? 0xFFFFFFFEu : m2;  c2j1 = lane + (r2 << 6);
      }
    }
  }
  if (lane < KNN) {
    idxout[(size_t)(b * NPTS + i0 + wv) * KNN + lane] = my0;
    idxout[(size_t)(b * NPTS + i0 + wv + 4) * KNN + lane] = my1;
  }
}

// ---- 64-tile fp32 GEMM (small conv layers feeding knn paths) ----
__global__ __launch_bounds__(256)
void gemm_kernel(const float* __restrict__ X, long sxb, int sxn, int sxc,
                 const float* __restrict__ WT, int ldW, int C,
                 float* __restrict__ out, int sob, int son) {
  __shared__ __align__(16) float Xs[16][64];
  __shared__ __align__(16) float Ws[16][64];
  const int b = blockIdx.z;
  const int n0 = blockIdx.x * 64, o0 = blockIdx.y * 64;
  const int tid = threadIdx.x;
  const int lr = tid & 63;
  const int c4 = (tid >> 6) * 4;
  const int tn = tid & 15, to = tid >> 4;
  float acc[4][4];
  #pragma unroll
  for (int i = 0; i < 4; ++i)
    #pragma unroll
    for (int j = 0; j < 4; ++j) acc[i][j] = 0.f;

  const size_t xbase = (size_t)b * sxb;
  for (int k0 = 0; k0 < C; k0 += 16) {
    #pragma unroll
    for (int u = 0; u < 4; ++u) {
      int c = k0 + c4 + u;
      float xv = 0.f, wv = 0.f;
      if (c < C) {
        xv = X[xbase + (size_t)(n0 + lr) * sxn + (size_t)c * sxc];
        wv = WT[(size_t)c * ldW + o0 + lr];
      }
      Xs[c4 + u][lr] = xv;
      Ws[c4 + u][lr] = wv;
    }
    __syncthreads();
    #pragma unroll
    for (int kk = 0; kk < 16; ++kk) {
      const float4 xa = *reinterpret_cast<const float4*>(&Xs[kk][tn * 4]);
      const float4 wb = *reinterpret_cast<const float4*>(&Ws[kk][to * 4]);
      const float xr[4] = {xa.x, xa.y, xa.z, xa.w};
      const float wr[4] = {wb.x, wb.y, wb.z, wb.w};
      #pragma unroll
      for (int i = 0; i < 4; ++i)
        #pragma unroll
        for (int j = 0; j < 4; ++j) acc[i][j] = fmaf(xr[i], wr[j], acc[i][j]);
    }
    __syncthreads();
  }
  #pragma unroll
  for (int i = 0; i < 4; ++i) {
    float4 st = make_float4(acc[i][0], acc[i][1], acc[i][2], acc[i][3]);
    *reinterpret_cast<float4*>(&out[(size_t)b * sob + (size_t)(n0 + tn * 4 + i) * son + o0 + to * 4]) = st;
  }
}

// ---- 128x128 fp32 GEMM (tw3 path only; X channel-major) ----
template<int EPI>
__global__ __launch_bounds__(256)
void gemm128_kernel(const float* __restrict__ X, long sxb, int scN,
                    const float* __restrict__ WT, int ldW, int C,
                    float* __restrict__ out, int sob, int son, int snb) {
  __shared__ __align__(16) float Xs[16][128];
  __shared__ __align__(16) float Ws[16][128];
  __shared__ __align__(16) float red[16][132];
  const int b = blockIdx.z;
  const int n0 = blockIdx.x * 128, o0 = blockIdx.y * 128;
  const int tid = threadIdx.x;
  const int tn = tid & 15, to = tid >> 4;
  float acc[8][8];
  #pragma unroll
  for (int i = 0; i < 8; ++i)
    #pragma unroll
    for (int j = 0; j < 8; ++j) acc[i][j] = 0.f;

  const size_t xbase = (size_t)b * sxb;
  for (int c0 = 0; c0 < C; c0 += 16) {
    #pragma unroll
    for (int it = 0; it < 2; ++it) {
      const int task = tid + it * 256;
      const int kk = task >> 5, n4 = (task & 31) * 4;
      *reinterpret_cast<float4*>(&Xs[kk][n4]) =
        *reinterpret_cast<const float4*>(&X[xbase + (size_t)(c0 + kk) * scN + n0 + n4]);
      *reinterpret_cast<float4*>(&Ws[kk][n4]) =
        *reinterpret_cast<const float4*>(&WT[(size_t)(c0 + kk) * ldW + o0 + n4]);
    }
    __syncthreads();
    #pragma unroll
    for (int kk = 0; kk < 16; ++kk) {
      const float4 xa0 = *reinterpret_cast<const float4*>(&Xs[kk][tn * 4]);
      const float4 xa1 = *reinterpret_cast<const float4*>(&Xs[kk][64 + tn * 4]);
      const float4 wb0 = *reinterpret_cast<const float4*>(&Ws[kk][to * 4]);
      const float4 wb1 = *reinterpret_cast<const float4*>(&Ws[kk][64 + to * 4]);
      const float xr[8] = {xa0.x, xa0.y, xa0.z, xa0.w, xa1.x, xa1.y, xa1.z, xa1.w};
      const float wr[8] = {wb0.x, wb0.y, wb0.z, wb0.w, wb1.x, wb1.y, wb1.z, wb1.w};
      #pragma unroll
      for (int i = 0; i < 8; ++i)
        #pragma unroll
        for (int j = 0; j < 8; ++j) acc[i][j] = fmaf(xr[i], wr[j], acc[i][j]);
    }
    __syncthreads();
  }

  if (EPI == 0) {
    #pragma unroll
    for (int i = 0; i < 8; ++i) {
      const int n = n0 + (i >> 2) * 64 + tn * 4 + (i & 3);
      float4 s0 = make_float4(acc[i][0], acc[i][1], acc[i][2], acc[i][3]);
      float4 s1 = make_float4(acc[i][4], acc[i][5], acc[i][6], acc[i][7]);
      *reinterpret_cast<float4*>(&out[(size_t)b * sob + (size_t)n * son + o0 + to * 4]) = s0;
      *reinterpret_cast<float4*>(&out[(size_t)b * sob + (size_t)n * son + o0 + 64 + to * 4]) = s1;
    }
  } else {
    #pragma unroll
    for (int j = 0; j < 8; ++j) {
      float m = lrelu(acc[0][j]);
      #pragma unroll
      for (int i = 1; i < 8; ++i) m = fmaxf(m, lrelu(acc[i][j]));
      red[tn][(j >> 2) * 64 + to * 4 + (j & 3)] = m;
    }
    __syncthreads();
    if (tid < 128) {
      float m = red[0][tid];
      #pragma unroll
      for (int t = 1; t < 16; ++t) m = fmaxf(m, red[t][tid]);
      out[(size_t)b * sob + (size_t)blockIdx.x * snb + o0 + tid] = m;
    }
  }
}

// ---- bf16 MFMA GEMM ----
template<int EPI>
__global__ __launch_bounds__(256)
void gemm_mfma_kernel(const ushort* __restrict__ Xg, long sxb, int ldX,
                      const ushort* __restrict__ Wg, int ldW, int K,
                      float* __restrict__ out, long sob, int son, int snb) {
  __shared__ __align__(16) ushort As[128 * 64];
  __shared__ __align__(16) ushort Bs[128 * 64];
  __shared__ float red[2][128];
  const int b = blockIdx.z;
  const int n0 = blockIdx.x * 128, o0 = blockIdx.y * 128;
  const int tid = threadIdx.x;
  const int lane = tid & 63;
  const int wrow = (tid >> 6) >> 1, wcol = (tid >> 6) & 1;
  f32x4 acc[4][4];
  #pragma unroll
  for (int i = 0; i < 4; ++i)
    #pragma unroll
    for (int j = 0; j < 4; ++j)
      #pragma unroll
      for (int r = 0; r < 4; ++r) acc[i][j][r] = 0.f;

  const ushort* Xb = Xg + (size_t)b * sxb;
  for (int kb = 0; kb < K; kb += 64) {
    #pragma unroll
    for (int i = 0; i < 4; ++i) {
      const int idx = i * 256 + tid;
      const int n = idx >> 3, kc = idx & 7;
      const bf16x8 xv = *reinterpret_cast<const bf16x8*>(&Xb[(size_t)(n0 + n) * ldX + kb + kc * 8]);
      const bf16x8 wv = *reinterpret_cast<const bf16x8*>(&Wg[(size_t)(o0 + n) * ldW + kb + kc * 8]);
      const int ad = n * 128 + ((kc * 16) ^ ((n & 7) << 4));
      *reinterpret_cast<bf16x8*>((char*)As + ad) = xv;
      *reinterpret_cast<bf16x8*>((char*)Bs + ad) = wv;
    }
    __syncthreads();
    #pragma unroll
    for (int s = 0; s < 2; ++s) {
      bf16x8 af[4], bfr[4];
      const int klane = (s * 64 + ((lane >> 4) << 4));
      #pragma unroll
      for (int f = 0; f < 4; ++f) {
        const int nl = wrow * 64 + f * 16 + (lane & 15);
        af[f] = *reinterpret_cast<const bf16x8*>((char*)As + nl * 128 + (klane ^ ((nl & 7) << 4)));
        const int ol = wcol * 64 + f * 16 + (lane & 15);
        bfr[f] = *reinterpret_cast<const bf16x8*>((char*)Bs + ol * 128 + (klane ^ ((ol & 7) << 4)));
      }
      #pragma unroll
      for (int i = 0; i < 4; ++i)
        #pragma unroll
        for (int j = 0; j < 4; ++j)
          acc[i][j] = __builtin_amdgcn_mfma_f32_16x16x32_bf16(af[i], bfr[j], acc[i][j], 0, 0, 0);
    }
    __syncthreads();
  }

  if (EPI == 0) {
    #pragma unroll
    for (int i = 0; i < 4; ++i)
      #pragma unroll
      for (int r = 0; r < 4; ++r) {
        const int n = n0 + wrow * 64 + i * 16 + ((lane >> 4) << 2) + r;
        #pragma unroll
        for (int j = 0; j < 4; ++j) {
          const int o = o0 + wcol * 64 + j * 16 + (lane & 15);
          out[(size_t)b * sob + (size_t)n * son + o] = acc[i][j][r];
        }
      }
  } else {
    #pragma unroll
    for (int j = 0; j < 4; ++j) {
      float m = -3.4e38f;
      #pragma unroll
      for (int i = 0; i < 4; ++i)
        #pragma unroll
        for (int r = 0; r < 4; ++r) m = fmaxf(m, lrelu(acc[i][j][r]));
      m = fmaxf(m, __shfl_xor(m, 16));
      m = fmaxf(m, __shfl_xor(m, 32));
      if (lane < 16) red[wrow][wcol * 64 + j * 16 + lane] = m;
    }
    __syncthreads();
    if (tid < 128) {
      float m = fmaxf(red[0][tid], red[1][tid]);
      out[(size_t)b * sob + (size_t)blockIdx.x * snb + o0 + tid] = m;
    }
  }
}

// ---- edge max, channel-major fp32 output + NC bf16 copy for MFMA consumers ----
template<int O, int TI>
__global__ __launch_bounds__(256)
void edge_max_cn_kernel(const float* __restrict__ y, const float* __restrict__ z,
                        const int* __restrict__ idx, float* __restrict__ outCN,
                        float* __restrict__ xx, ushort* __restrict__ xbf, int choff) {
  __shared__ float tile[TI][O + 1];
  const int b = blockIdx.y;
  const int i0 = blockIdx.x * TI;
  const int wv = threadIdx.x >> 6, lane = threadIdx.x & 63;
  constexpr int OSEG = O / 64;
  constexpr int ROUNDS = TI * OSEG / 4;
  for (int r = 0; r < ROUNDS; ++r) {
    const int item = r * 4 + wv;
    const int il = item / OSEG, os = item - il * OSEG;
    const int i = i0 + il, o = os * 64 + lane;
    const int* ip = idx + (size_t)(b * NPTS + i) * KNN;
    const float zv = z[(size_t)(b * NPTS + i) * O + o];
    float m = -3.4e38f;
    #pragma unroll
    for (int t = 0; t < KNN; ++t) {
      int j = ip[t];
      float v = y[(size_t)(b * NPTS + j) * O + o] + zv;
      m = fmaxf(m, lrelu(v));
    }
    tile[il][o] = m;
    xbf[(size_t)(b * NPTS + i) * 512 + choff + o] = f2bf(m);
  }
  __syncthreads();
  if (xx != nullptr && threadIdx.x < TI) {
    const int il = threadIdx.x;
    float s = 0.f;
    #pragma unroll
    for (int o = 0; o < O; ++o) { float v = tile[il][o]; s = fmaf(v, v, s); }
    xx[b * NPTS + i0 + il] = s;
  }
  for (int e = threadIdx.x; e < TI * O; e += 256) {
    const int o = e / TI, il = e - o * TI;
    outCN[(size_t)b * 512 * NPTS + (size_t)o * NPTS + i0 + il] = tile[il][o];
  }
}

// ---- h12 as edge-GEMM ----
__global__ __launch_bounds__(256)
void h12_gemm_kernel(const float* __restrict__ ya, const float* __restrict__ zb,
                     const int* __restrict__ idx, const float* __restrict__ tw2T,
                     float* __restrict__ h2m) {
  __shared__ __align__(16) float h1s[80][68];
  __shared__ __align__(16) float ws[64][128];
  __shared__ __align__(16) float zbs[4][64];
  __shared__ float ot[128][4];
  __shared__ int idxs[4][KNN];
  const int b = blockIdx.y;
  const int i0 = blockIdx.x * 4;
  const int tid = threadIdx.x;

  #pragma unroll
  for (int it = 0; it < 8; ++it) {
    const int f = tid + it * 256;
    *reinterpret_cast<float4*>(&ws[0][0] + f * 4) =
      *reinterpret_cast<const float4*>(tw2T + (size_t)f * 4);
  }
  if (tid < 64) {
    const int p = tid >> 4, cq = (tid & 15) * 4;
    *reinterpret_cast<float4*>(&zbs[p][cq]) =
      *reinterpret_cast<const float4*>(&zb[(size_t)(b * NPTS + i0 + p) * 64 + cq]);
  }
  if (tid >= 64 && tid < 64 + 4 * KNN) {
    const int e = tid - 64;
    idxs[e / KNN][e % KNN] = idx[(size_t)(b * NPTS + i0) * KNN + e];
  }
  __syncthreads();

  #pragma unroll
  for (int it = 0; it < 5; ++it) {
    const int task = tid + it * 256;
    const int e = task >> 4, cq = (task & 15) * 4;
    const int p = e / KNN, t = e - p * KNN;
    const int j = idxs[p][t];
    const float4 yv = *reinterpret_cast<const float4*>(&ya[(size_t)(b * NPTS + j) * 64 + cq]);
    const float4 zv = *reinterpret_cast<const float4*>(&zbs[p][cq]);
    float4 hv;
    hv.x = lrelu(yv.x + zv.x); hv.y = lrelu(yv.y + zv.y);
    hv.z = lrelu(yv.z + zv.z); hv.w = lrelu(yv.w + zv.w);
    *reinterpret_cast<float4*>(&h1s[e][cq]) = hv;
  }
  __syncthreads();

  const int eg = tid >> 4, og = tid & 15;
  float acc[5][8];
  #pragma unroll
  for (int u = 0; u < 5; ++u)
    #pragma unroll
    for (int v = 0; v < 8; ++v) acc[u][v] = 0.f;
  #pragma unroll 4
  for (int kk = 0; kk < 64; ++kk) {
    float hv[5];
    #pragma unroll
    for (int u = 0; u < 5; ++u) hv[u] = h1s[eg * 5 + u][kk];
    const float4 w0 = *reinterpret_cast<const float4*>(&ws[kk][og * 4]);
    const float4 w1 = *reinterpret_cast<const float4*>(&ws[kk][64 + og * 4]);
    const float wr[8] = {w0.x, w0.y, w0.z, w0.w, w1.x, w1.y, w1.z, w1.w};
    #pragma unroll
    for (int u = 0; u < 5; ++u)
      #pragma unroll
      for (int v = 0; v < 8; ++v) acc[u][v] = fmaf(hv[u], wr[v], acc[u][v]);
  }

  const int p = eg >> 2, d = eg & 3;
  float m[8];
  #pragma unroll
  for (int v = 0; v < 8; ++v) {
    float mm = lrelu(acc[0][v]);
    #pragma unroll
    for (int u = 1; u < 5; ++u) mm = fmaxf(mm, lrelu(acc[u][v]));
    mm = fmaxf(mm, __shfl_xor(mm, 16));
    mm = fmaxf(mm, __shfl_xor(mm, 32));
    m[v] = mm;
  }
  if (d == 0) {
    #pragma unroll
    for (int v = 0; v < 8; ++v) {
      const int o = og * 4 + (v & 3) + (v >> 2) * 64;
      ot[o][p] = m[v];
    }
  }
  __syncthreads();
  if (tid < 128) {
    float4 st = make_float4(ot[tid][0], ot[tid][1], ot[tid][2], ot[tid][3]);
    *reinterpret_cast<float4*>(&h2m[(size_t)(b * 128 + tid) * NPTS + i0]) = st;
  }
}

// ---- reduce partial max over nt n-tiles ----
__global__ __launch_bounds__(256)
void reduce_max_kernel(const float* __restrict__ part, float* __restrict__ outp, int nt) {
  const int b = blockIdx.y;
  const int o = blockIdx.x * 256 + threadIdx.x;
  float m = part[(size_t)(b * nt) * 1024 + o];
  for (int t = 1; t < nt; ++t) m = fmaxf(m, part[(size_t)(b * nt + t) * 1024 + o]);
  outp[b * 1024 + o] = m;
}

// ---- block reduce helper ----
__device__ __forceinline__ float block_reduce_sum(float v, float* rbuf) {
  #pragma unroll
  for (int off = 32; off > 0; off >>= 1) v += __shfl_xor(v, off);
  const int w = threadIdx.x >> 6, lane = threadIdx.x & 63;
  const int nw = blockDim.x >> 6;
  if (lane == 0) rbuf[w] = v;
  __syncthreads();
  float tot = 0.f;
  for (int i = 0; i < nw; ++i) tot += rbuf[i];
  __syncthreads();
  return tot;
}

// ---- fc1 ----
__global__ __launch_bounds__(256)
void fc1_kernel(const float* __restrict__ gin_g, const float* __restrict__ Wt,
                const float* __restrict__ gam, const float* __restrict__ bet,
                float* __restrict__ outp) {
  __shared__ __align__(16) float gin[1024];
  __shared__ float hbuf[512];
  __shared__ float rbuf[8];
  const int b = blockIdx.x, tid = threadIdx.x;
  for (int e = tid; e < 1024; e += 256) gin[e] = gin_g[b * 1024 + e];
  __syncthreads();
  float ps = 0.f;
  for (int e = tid; e < 1024; e += 256) ps = fmaf(gin[e], gin[e], ps);
  float ss = block_reduce_sum(ps, rbuf);
  float rinv = 1.0f / sqrtf(ss);
  #pragma unroll
  for (int r = 0; r < 2; ++r) {
    int o = tid + r * 256;
    const float* wrow = Wt + (size_t)o * 1024;
    float a = 0.f;
    for (int c4 = 0; c4 < 256; ++c4) {
      float4 wv = *reinterpret_cast<const float4*>(wrow + c4 * 4);
      float4 gv = *reinterpret_cast<const float4*>(&gin[c4 * 4]);
      a = fmaf(wv.x, gv.x, a); a = fmaf(wv.y, gv.y, a);
      a = fmaf(wv.z, gv.z, a); a = fmaf(wv.w, gv.w, a);
    }
    hbuf[o] = a * rinv;
  }
  __syncthreads();
  float pm = hbuf[tid] + hbuf[tid + 256];
  float mean = block_reduce_sum(pm, rbuf) * (1.f / 512.f);
  float d0 = hbuf[tid] - mean, d1 = hbuf[tid + 256] - mean;
  float var = block_reduce_sum(d0 * d0 + d1 * d1, rbuf) * (1.f / 512.f);
  float rs = 1.0f / sqrtf(var + 1e-5f);
  #pragma unroll
  for (int r = 0; r < 2; ++r) {
    int o = tid + r * 256;
    float yv = (hbuf[o] - mean) * rs * gam[o] + bet[o];
    outp[b * 512 + o] = lrelu(yv);
  }
}

// ---- fc2 ----
__global__ __launch_bounds__(256)
void fc2_kernel(const float* __restrict__ inp, const float* __restrict__ Wt,
                const float* __restrict__ bias, const float* __restrict__ gam,
                const float* __restrict__ bet, float* __restrict__ outp) {
  __shared__ __align__(16) float gin[512];
  __shared__ float rbuf[8];
  const int b = blockIdx.x, tid = threadIdx.x;
  for (int e = tid; e < 512; e += 256) gin[e] = inp[b * 512 + e];
  __syncthreads();
  float ps = 0.f;
  for (int e = tid; e < 512; e += 256) ps = fmaf(gin[e], gin[e], ps);
  float ss = block_reduce_sum(ps, rbuf);
  float rinv = 1.0f / sqrtf(ss);
  const float* wrow = Wt + (size_t)tid * 512;
  float a = 0.f;
  for (int c4 = 0; c4 < 128; ++c4) {
    float4 wv = *reinterpret_cast<const float4*>(wrow + c4 * 4);
    float4 gv = *reinterpret_cast<const float4*>(&gin[c4 * 4]);
    a = fmaf(wv.x, gv.x, a); a = fmaf(wv.y, gv.y, a);
    a = fmaf(wv.z, gv.z, a); a = fmaf(wv.w, gv.w, a);
  }
  a = a * rinv + bias[tid];
  float mean = block_reduce_sum(a, rbuf) * (1.f / 256.f);
  float d = a - mean;
  float var = block_reduce_sum(d * d, rbuf) * (1.f / 256.f);
  float rs = 1.0f / sqrtf(var + 1e-5f);
  float yv = (a - mean) * rs * gam[tid] + bet[tid];
  outp[b * 256 + tid] = lrelu(yv);
}

// ---- fc3 + identity ----
__global__ __launch_bounds__(64)
void fc3_kernel(const float* __restrict__ inp, const float* __restrict__ Wt,
                const float* __restrict__ bias, float* __restrict__ tmat) {
  __shared__ float gin[256];
  const int b = blockIdx.x, tid = threadIdx.x;
  for (int e = tid; e < 256; e += 64) gin[e] = inp[b * 256 + e];
  __syncthreads();
  if (tid < 9) {
    const float* wrow = Wt + tid * 256;
    float a = 0.f;
    for (int c = 0; c < 256; ++c) a = fmaf(wrow[c], gin[c], a);
    a += bias[tid];
    if (tid == 0 || tid == 4 || tid == 8) a += 1.f;
    tmat[b * 9 + tid] = a;
  }
}

// ---- apply 3x3 transform ----
__global__ __launch_bounds__(256)
void xform_kernel(const float* __restrict__ x, const float* __restrict__ tmat,
                  float* __restrict__ xt) {
  const int b = blockIdx.y;
  const int n = blockIdx.x * 256 + threadIdx.x;
  const float* xb = x + (size_t)b * 3 * NPTS;
  const float x0 = xb[n], x1 = xb[NPTS + n], x2 = xb[2 * NPTS + n];
  const float* t = tmat + b * 9;
  float* ob = xt + (size_t)b * 3 * NPTS;
  #pragma unroll
  for (int i = 0; i < 3; ++i)
    ob[i * NPTS + n] = fmaf(t[3 * i], x0, fmaf(t[3 * i + 1], x1, t[3 * i + 2] * x2));
}

extern "C" void kernel_launch(void* const* d_in, const int* in_sizes, int n_in,
                              void* d_out, int out_size, void* d_ws, size_t ws_size,
                              hipStream_t stream) {
  (void)in_sizes; (void)n_in; (void)out_size; (void)ws_size;
  const float* x       = (const float*)d_in[0];
  const float* tw1     = (const float*)d_in[1];
  const float* tw2     = (const float*)d_in[2];
  const float* tw3     = (const float*)d_in[3];
  const float* tfc1_w  = (const float*)d_in[4];
  const float* tfc1_g  = (const float*)d_in[5];
  const float* tfc1_b  = (const float*)d_in[6];
  const float* tfc2_w  = (const float*)d_in[7];
  const float* tfc2_bias = (const float*)d_in[8];
  const float* tfc2_g  = (const float*)d_in[9];
  const float* tfc2_b  = (const float*)d_in[10];
  const float* tfc3_w  = (const float*)d_in[11];
  const float* tfc3_b  = (const float*)d_in[12];
  const float* w1      = (const float*)d_in[13];
  const float* w2      = (const float*)d_in[14];
  const float* w3      = (const float*)d_in[15];
  const float* w4      = (const float*)d_in[16];
  const float* w5      = (const float*)d_in[17];
  float* out = (float*)d_out;

  char* wsb = (char*)d_ws;
  size_t off = 0;
  auto alloc = [&](size_t bytes) -> void* {
    void* p = wsb + off;
    off += (bytes + 255) & ~(size_t)255;
    return p;
  };
  float* ybuf = (float*)alloc((size_t)BATCH * NPTS * 256 * 4);
  float* zbuf = (float*)alloc((size_t)BATCH * NPTS * 256 * 4);
  float* xcT  = (float*)alloc((size_t)BATCH * 512 * NPTS * 4);   // channel-major fp32 (knn)
  ushort* xc_bf = (ushort*)alloc((size_t)BATCH * NPTS * 512 * 2); // NC bf16 (MFMA)
  float* h2m  = (float*)alloc((size_t)BATCH * 128 * NPTS * 4);
  float* part = (float*)alloc((size_t)BATCH * 16 * 1024 * 4);
  int*   idxb = (int*)alloc((size_t)BATCH * NPTS * KNN * 4);
  float* xxb  = (float*)alloc((size_t)BATCH * NPTS * 4);
  float* xt   = (float*)alloc((size_t)BATCH * 3 * NPTS * 4);
  float* gbuf = (float*)alloc((size_t)BATCH * 1024 * 4);
  float* f1o  = (float*)alloc((size_t)BATCH * 512 * 4);
  float* f2o  = (float*)alloc((size_t)BATCH * 256 * 4);
  float* tmat = (float*)alloc((size_t)BATCH * 9 * 4);
  float* tw1aT = (float*)alloc(3 * 64 * 4);
  float* tw1dT = (float*)alloc(3 * 64 * 4);
  float* w1aT  = (float*)alloc(3 * 64 * 4);
  float* w1dT  = (float*)alloc(3 * 64 * 4);
  float* w2aT  = (float*)alloc(64 * 64 * 4);
  float* w2dT  = (float*)alloc(64 * 64 * 4);
  float* w3aT  = (float*)alloc(64 * 128 * 4);
  float* w3dT  = (float*)alloc(64 * 128 * 4);
  ushort* w4a_bf = (ushort*)alloc(256 * 128 * 2);
  ushort* w4d_bf = (ushort*)alloc(256 * 128 * 2);
  ushort* w5_bf  = (ushort*)alloc(1024 * 512 * 2);
  float* tw2T  = (float*)alloc(64 * 128 * 4);
  float* tw3T  = (float*)alloc(128 * 1024 * 4);

  // weight prep
  wsplit_t_kernel<<<1, 256, 0, stream>>>(tw1, tw1aT, tw1dT, 64, 3);
  wsplit_t_kernel<<<1, 256, 0, stream>>>(w1, w1aT, w1dT, 64, 3);
  wsplit_t_kernel<<<16, 256, 0, stream>>>(w2, w2aT, w2dT, 64, 64);
  wsplit_t_kernel<<<32, 256, 0, stream>>>(w3, w3aT, w3dT, 128, 64);
  wsplit_bf_kernel<<<128, 256, 0, stream>>>(w4, w4a_bf, w4d_bf, 256, 128);
  cvt_bf16_kernel<<<2048, 256, 0, stream>>>(w5, w5_bf, 1024 * 512);
  wtrans_kernel<<<32, 256, 0, stream>>>(tw2, tw2T, 128, 64);
  wtrans_kernel<<<512, 256, 0, stream>>>(tw3, tw3T, 1024, 128);

  // ---- transform net ----
  xx3_kernel<<<dim3(4, 16), 256, 0, stream>>>(x, xxb);
  knn_cn_kernel<3><<<dim3(128, 16), 256, 0, stream>>>(x, 3 * NPTS, xxb, idxb);
  gemm_kernel<<<dim3(16, 1, 16), 256, 0, stream>>>(x, 3 * NPTS, 1, NPTS, tw1aT, 64, 3,
                                                   ybuf, NPTS * 64, 64);
  gemm_kernel<<<dim3(16, 1, 16), 256, 0, stream>>>(x, 3 * NPTS, 1, NPTS, tw1dT, 64, 3,
                                                   zbuf, NPTS * 64, 64);
  h12_gemm_kernel<<<dim3(256, 16), 256, 0, stream>>>(ybuf, zbuf, idxb, tw2T, h2m);
  gemm128_kernel<1><<<dim3(8, 8, 16), 256, 0, stream>>>(h2m, 128 * NPTS, NPTS, tw3T, 1024, 128,
                                                        part, 8 * 1024, 0, 1024);
  reduce_max_kernel<<<dim3(4, 16), 256, 0, stream>>>(part, gbuf, 8);
  fc1_kernel<<<16, 256, 0, stream>>>(gbuf, tfc1_w, tfc1_g, tfc1_b, f1o);
  fc2_kernel<<<16, 256, 0, stream>>>(f1o, tfc2_w, tfc2_bias, tfc2_g, tfc2_b, f2o);
  fc3_kernel<<<16, 64, 0, stream>>>(f2o, tfc3_w, tfc3_b, tmat);
  xform_kernel<<<dim3(4, 16), 256, 0, stream>>>(x, tmat, xt);

  // ---- EdgeConv 1 (C=3 -> O=64) on xt ----
  xx3_kernel<<<dim3(4, 16), 256, 0, stream>>>(xt, xxb);
  knn_cn_kernel<3><<<dim3(128, 16), 256, 0, stream>>>(xt, 3 * NPTS, xxb, idxb);
  gemm_kernel<<<dim3(16, 1, 16), 256, 0, stream>>>(xt, 3 * NPTS, 1, NPTS, w1aT, 64, 3,
                                                   ybuf, NPTS * 64, 64);
  gemm_kernel<<<dim3(16, 1, 16), 256, 0, stream>>>(xt, 3 * NPTS, 1, NPTS, w1dT, 64, 3,
                                                   zbuf, NPTS * 64, 64);
  edge_max_cn_kernel<64, 64><<<dim3(16, 16), 256, 0, stream>>>(ybuf, zbuf, idxb, xcT, xxb,
                                                               xc_bf, 0);

  // ---- EdgeConv 2 (C=64 -> O=64) ----
  knn_cn_kernel<64><<<dim3(128, 16), 256, 0, stream>>>(xcT, 512 * NPTS, xxb, idxb);
  gemm_kernel<<<dim3(16, 1, 16), 256, 0, stream>>>(xcT, 512 * NPTS, 1, NPTS, w2aT, 64, 64,
                                                   ybuf, NPTS * 64, 64);
  gemm_kernel<<<dim3(16, 1, 16), 256, 0, stream>>>(xcT, 512 * NPTS, 1, NPTS, w2dT, 64, 64,
                                                   zbuf, NPTS * 64, 64);
  edge_max_cn_kernel<64, 64><<<dim3(16, 16), 256, 0, stream>>>(ybuf, zbuf, idxb,
                                                               xcT + 64 * NPTS, xxb, xc_bf, 64);

  // ---- EdgeConv 3 (C=64 -> O=128) ----
  knn_cn_kernel<64><<<dim3(128, 16), 256, 0, stream>>>(xcT + 64 * NPTS, 512 * NPTS, xxb, idxb);
  gemm_kernel<<<dim3(16, 2, 16), 256, 0, stream>>>(xcT + 64 * NPTS, 512 * NPTS, 1, NPTS,
                                                   w3aT, 128, 64, ybuf, NPTS * 128, 128);
  gemm_kernel<<<dim3(16, 2, 16), 256, 0, stream>>>(xcT + 64 * NPTS, 512 * NPTS, 1, NPTS,
                                                   w3dT, 128, 64, zbuf, NPTS * 128, 128);
  edge_max_cn_kernel<128, 64><<<dim3(16, 16), 256, 0, stream>>>(ybuf, zbuf, idxb,
                                                                xcT + 128 * NPTS, xxb, xc_bf, 128);

  // ---- EdgeConv 4 (C=128 -> O=256): bf16 MFMA GEMMs on x3 slice (knn-safe) ----
  knn_cn_kernel<128><<<dim3(128, 16), 256, 0, stream>>>(xcT + 128 * NPTS, 512 * NPTS, xxb, idxb);
  gemm_mfma_kernel<0><<<dim3(8, 2, 16), 256, 0, stream>>>(xc_bf + 128, (long)NPTS * 512, 512,
                                                          w4a_bf, 128, 128,
                                                          ybuf, (long)NPTS * 256, 256, 0);
  gemm_mfma_kernel<0><<<dim3(8, 2, 16), 256, 0, stream>>>(xc_bf + 128, (long)NPTS * 512, 512,
                                                          w4d_bf, 128, 128,
                                                          zbuf, (long)NPTS * 256, 256, 0);
  edge_max_cn_kernel<256, 32><<<dim3(32, 16), 256, 0, stream>>>(ybuf, zbuf, idxb,
                                                                xcT + 256 * NPTS, nullptr,
                                                                xc_bf, 256);

  // ---- final: x5 = lrelu(w5 @ xc) with max over n — bf16 MFMA (knn-safe) ----
  gemm_mfma_kernel<1><<<dim3(8, 8, 16), 256, 0, stream>>>(xc_bf, (long)NPTS * 512, 512,
                                                          w5_bf, 512, 512,
                                                          part, 8 * 1024, 0, 1024);
  reduce_max_kernel<<<dim3(4, 16), 256, 0, stream>>>(part, out, 8);
}

// Round 11
// 734.937 us; speedup vs baseline: 5.5351x; 1.0278x over previous
//
#include <hip/hip_runtime.h>
#include <math.h>

#define BATCH 16
#define NPTS 1024
#define KNN 20

__device__ __forceinline__ float lrelu(float v) { return v >= 0.f ? v : 0.2f * v; }

typedef __attribute__((ext_vector_type(8))) short bf16x8;
typedef __attribute__((ext_vector_type(4))) float f32x4;
typedef unsigned long long ull;

__device__ __forceinline__ ushort f2bf(float f) {
  union { float f; unsigned u; } v; v.f = f;
  unsigned r = (v.u + 0x7FFFu + ((v.u >> 16) & 1u)) >> 16;  // RNE
  return (ushort)r;
}

// DPP wave-64 min reduction (pure VALU, zero DS ops) — verified round 10.
__device__ __forceinline__ unsigned wave_min_u32(unsigned v) {
  unsigned t;
  t = (unsigned)__builtin_amdgcn_update_dpp((int)v, (int)v, 0x111, 0xf, 0xf, false);
  v = t < v ? t : v;
  t = (unsigned)__builtin_amdgcn_update_dpp((int)v, (int)v, 0x112, 0xf, 0xf, false);
  v = t < v ? t : v;
  t = (unsigned)__builtin_amdgcn_update_dpp((int)v, (int)v, 0x114, 0xf, 0xf, false);
  v = t < v ? t : v;
  t = (unsigned)__builtin_amdgcn_update_dpp((int)v, (int)v, 0x118, 0xf, 0xf, false);
  v = t < v ? t : v;
  t = (unsigned)__builtin_amdgcn_update_dpp((int)v, (int)v, 0x142, 0xf, 0xf, false);
  v = t < v ? t : v;
  t = (unsigned)__builtin_amdgcn_update_dpp((int)v, (int)v, 0x143, 0xf, 0xf, false);
  v = t < v ? t : v;
  return (unsigned)__builtin_amdgcn_readlane((int)v, 63);
}

// ---- weight prep: W[O][2C] -> WaT[C][O] fp32 ; WdT[C][O] fp32 ----
__global__ __launch_bounds__(256)
void wsplit_t_kernel(const float* __restrict__ W, float* __restrict__ waT,
                     float* __restrict__ wdT, int O, int Cc) {
  int e = blockIdx.x * 256 + threadIdx.x;
  if (e < O * Cc) {
    int c = e / O, o = e - c * O;
    float a = W[o * 2 * Cc + c], bb = W[o * 2 * Cc + Cc + c];
    waT[e] = a; wdT[e] = bb - a;
  }
}

// ---- weight prep bf16, NON-transposed [o][c] ----
__global__ __launch_bounds__(256)
void wsplit_bf_kernel(const float* __restrict__ W, ushort* __restrict__ wa_bf,
                      ushort* __restrict__ wd_bf, int O, int Cc) {
  int e = blockIdx.x * 256 + threadIdx.x;
  if (e < O * Cc) {
    int o = e / Cc, c = e - o * Cc;
    float a = W[o * 2 * Cc + c], bb = W[o * 2 * Cc + Cc + c];
    wa_bf[e] = f2bf(a); wd_bf[e] = f2bf(bb - a);
  }
}

// ---- fp32 -> bf16 elementwise ----
__global__ __launch_bounds__(256)
void cvt_bf16_kernel(const float* __restrict__ in, ushort* __restrict__ outp, int n) {
  int e = blockIdx.x * 256 + threadIdx.x;
  if (e < n) outp[e] = f2bf(in[e]);
}

// ---- weight transpose: W[O][C] -> wT[C][O] ----
__global__ __launch_bounds__(256)
void wtrans_kernel(const float* __restrict__ W, float* __restrict__ wT, int O, int Cc) {
  int e = blockIdx.x * 256 + threadIdx.x;
  if (e < O * Cc) {
    int c = e / O, o = e - c * O;
    wT[e] = W[(size_t)o * Cc + c];
  }
}

// ---- xx[b][n] = sum_c x[b][c][n]^2 for C=3 CN input ----
__global__ __launch_bounds__(256)
void xx3_kernel(const float* __restrict__ x, float* __restrict__ xx) {
  const int b = blockIdx.y;
  const int n = blockIdx.x * 256 + threadIdx.x;
  const float* xb = x + (size_t)b * 3 * NPTS;
  float a = xb[n], bb = xb[NPTS + n], c = xb[2 * NPTS + n];
  xx[b * NPTS + n] = a * a + bb * bb + c * c;
}

// ---- knn: 16 queries/block, 16 KB LDS reused over 4 handoff rounds; each wave
// owns 4 queries (chains) extracted with interleaved DPP min + ballot/readlane.
template<int C>
__global__ __launch_bounds__(256)
void knn_cn_kernel(const float* __restrict__ Xt, long sb,
                   const float* __restrict__ xx, int* __restrict__ idxout) {
  __shared__ float sc4[4][NPTS];   // 16 KB
  const int b = blockIdx.y, i0 = blockIdx.x * 16;
  const int tid = threadIdx.x;
  const float* Xb = Xt + (size_t)b * sb;
  const int j0 = tid * 4;
  float acc[16][4];
  #pragma unroll
  for (int q = 0; q < 16; ++q)
    #pragma unroll
    for (int u = 0; u < 4; ++u) acc[q][u] = 0.f;
  for (int c = 0; c < C; ++c) {
    const float4 xv = *reinterpret_cast<const float4*>(Xb + (size_t)c * NPTS + j0);
    const float* xr = Xb + (size_t)c * NPTS + i0;   // uniform addresses -> scalar loads
    #pragma unroll
    for (int q = 0; q < 16; ++q) {
      const float xiq = xr[q];
      acc[q][0] = fmaf(xiq, xv.x, acc[q][0]);
      acc[q][1] = fmaf(xiq, xv.y, acc[q][1]);
      acc[q][2] = fmaf(xiq, xv.z, acc[q][2]);
      acc[q][3] = fmaf(xiq, xv.w, acc[q][3]);
    }
  }
  const float4 xxj = *reinterpret_cast<const float4*>(xx + b * NPTS + j0);
  const int wv = tid >> 6, lane = tid & 63;
  unsigned ku[4][16];

  #pragma unroll
  for (int r = 0; r < 4; ++r) {
    if (r > 0) __syncthreads();
    #pragma unroll
    for (int q = 0; q < 4; ++q) {
      const int qq = r * 4 + q;
      float4 st;
      st.x = fmaf(-2.f, acc[qq][0], xxj.x);
      st.y = fmaf(-2.f, acc[qq][1], xxj.y);
      st.z = fmaf(-2.f, acc[qq][2], xxj.z);
      st.w = fmaf(-2.f, acc[qq][3], xxj.w);
      *reinterpret_cast<float4*>(&sc4[q][j0]) = st;
    }
    __syncthreads();
    #pragma unroll
    for (int s = 0; s < 16; ++s) {
      const unsigned u = __float_as_uint(sc4[wv][lane + 64 * s]);
      ku[r][s] = u ^ ((unsigned)((int)u >> 31) | 0x80000000u);
    }
  }

  // per-chain top-2 tournaments (strict < keeps earlier slot)
  unsigned c1s[4], c2s[4]; int c1j[4], c2j[4];
  #pragma unroll
  for (int r = 0; r < 4; ++r) {
    unsigned b1 = 0xFFFFFFFFu, b2 = 0xFFFFFFFFu; int s1 = 0, s2 = 0;
    #pragma unroll
    for (int s = 0; s < 16; ++s) {
      const unsigned k = ku[r][s];
      const bool a1 = k < b1, a2 = k < b2;
      const unsigned n1 = a1 ? k : b1;  const int ns1 = a1 ? s : s1;
      const unsigned n2 = a1 ? b1 : (a2 ? k : b2);
      const int ns2 = a1 ? s1 : (a2 ? s : s2);
      b1 = n1; s1 = ns1; b2 = n2; s2 = ns2;
    }
    c1s[r] = b1; c1j[r] = lane + (s1 << 6);
    c2s[r] = b2; c2j[r] = lane + (s2 << 6);
  }
  const unsigned INVS = 0xFFFFFFFFu;
  int my[4] = {0, 0, 0, 0};
  for (int t = 0; t < KNN; ++t) {
    unsigned ws[4]; int wl[4], jw[4];
    #pragma unroll
    for (int r = 0; r < 4; ++r) ws[r] = wave_min_u32(c1s[r]);
    #pragma unroll
    for (int r = 0; r < 4; ++r) wl[r] = __ffsll((long long)__ballot(c1s[r] == ws[r])) - 1;
    #pragma unroll
    for (int r = 0; r < 4; ++r) jw[r] = __builtin_amdgcn_readlane(c1j[r], wl[r]);
    if (lane == t) {
      #pragma unroll
      for (int r = 0; r < 4; ++r) my[r] = jw[r];
    }
    bool cons = false;
    #pragma unroll
    for (int r = 0; r < 4; ++r) {
      const bool win = (lane == wl[r]);
      c1s[r] = win ? c2s[r] : c1s[r];
      c1j[r] = win ? c2j[r] : c1j[r];
      c2s[r] = win ? INVS : c2s[r];
      cons = cons || (c1s[r] == INVS);
    }
    if (__any(cons)) {
      #pragma unroll
      for (int r = 0; r < 4; ++r) {
        if (c1s[r] == INVS) {   // refill top-2 among keys > ws[r] (alive == key > winner)
          unsigned m1 = INVS, m2 = INVS; int r1 = 0, r2 = 0;
          #pragma unroll
          for (int s = 0; s < 16; ++s) {
            const unsigned k = ku[r][s];
            const bool ok = k > ws[r];
            const bool a1 = ok && (k < m1), a2 = ok && (k < m2);
            const unsigned nm1 = a1 ? k : m1;  const int nr1 = a1 ? s : r1;
            const unsigned nm2 = a1 ? m1 : (a2 ? k : m2);
            const int nr2 = a1 ? r1 : (a2 ? s : r2);
            m1 = nm1; r1 = nr1; m2 = nm2; r2 = nr2;
          }
          c1s[r] = (m1 == INVS) ? 0xFFFFFFFEu : m1;  c1j[r] = lane + (r1 << 6);
          c2s[r] = (m2 == INVS) ? 0xFFFFFFFEu : m2;  c2j[r] = lane + (r2 << 6);
        }
      }
    }
  }
  if (lane < KNN) {
    #pragma unroll
    for (int r = 0; r < 4; ++r)
      idxout[(size_t)(b * NPTS + i0 + r * 4 + wv) * KNN + lane] = my[r];
  }
}

// ---- dual 64-tile fp32 GEMM: shared X tile, two weight sets, two outputs ----
__global__ __launch_bounds__(256)
void gemm_dual_kernel(const float* __restrict__ X, long sxb, int sxn, int sxc,
                      const float* __restrict__ WaT, const float* __restrict__ WdT,
                      int ldW, int C,
                      float* __restrict__ outY, float* __restrict__ outZ,
                      int sob, int son) {
  __shared__ __align__(16) float Xs[16][64];
  __shared__ __align__(16) float Was[16][64];
  __shared__ __align__(16) float Wds[16][64];
  const int b = blockIdx.z;
  const int n0 = blockIdx.x * 64, o0 = blockIdx.y * 64;
  const int tid = threadIdx.x;
  const int lr = tid & 63;
  const int c4 = (tid >> 6) * 4;
  const int tn = tid & 15, to = tid >> 4;
  float accY[4][4], accZ[4][4];
  #pragma unroll
  for (int i = 0; i < 4; ++i)
    #pragma unroll
    for (int j = 0; j < 4; ++j) { accY[i][j] = 0.f; accZ[i][j] = 0.f; }

  const size_t xbase = (size_t)b * sxb;
  for (int k0 = 0; k0 < C; k0 += 16) {
    #pragma unroll
    for (int u = 0; u < 4; ++u) {
      int c = k0 + c4 + u;
      float xv = 0.f, wa = 0.f, wd = 0.f;
      if (c < C) {
        xv = X[xbase + (size_t)(n0 + lr) * sxn + (size_t)c * sxc];
        wa = WaT[(size_t)c * ldW + o0 + lr];
        wd = WdT[(size_t)c * ldW + o0 + lr];
      }
      Xs[c4 + u][lr] = xv;
      Was[c4 + u][lr] = wa;
      Wds[c4 + u][lr] = wd;
    }
    __syncthreads();
    #pragma unroll
    for (int kk = 0; kk < 16; ++kk) {
      const float4 xa = *reinterpret_cast<const float4*>(&Xs[kk][tn * 4]);
      const float4 wav = *reinterpret_cast<const float4*>(&Was[kk][to * 4]);
      const float4 wdv = *reinterpret_cast<const float4*>(&Wds[kk][to * 4]);
      const float xr[4] = {xa.x, xa.y, xa.z, xa.w};
      const float war[4] = {wav.x, wav.y, wav.z, wav.w};
      const float wdr[4] = {wdv.x, wdv.y, wdv.z, wdv.w};
      #pragma unroll
      for (int i = 0; i < 4; ++i)
        #pragma unroll
        for (int j = 0; j < 4; ++j) {
          accY[i][j] = fmaf(xr[i], war[j], accY[i][j]);
          accZ[i][j] = fmaf(xr[i], wdr[j], accZ[i][j]);
        }
    }
    __syncthreads();
  }
  #pragma unroll
  for (int i = 0; i < 4; ++i) {
    const size_t base = (size_t)b * sob + (size_t)(n0 + tn * 4 + i) * son + o0 + to * 4;
    *reinterpret_cast<float4*>(&outY[base]) =
      make_float4(accY[i][0], accY[i][1], accY[i][2], accY[i][3]);
    *reinterpret_cast<float4*>(&outZ[base]) =
      make_float4(accZ[i][0], accZ[i][1], accZ[i][2], accZ[i][3]);
  }
}

// ---- 128x128 fp32 GEMM (tw3 path only; X channel-major) ----
template<int EPI>
__global__ __launch_bounds__(256)
void gemm128_kernel(const float* __restrict__ X, long sxb, int scN,
                    const float* __restrict__ WT, int ldW, int C,
                    float* __restrict__ out, int sob, int son, int snb) {
  __shared__ __align__(16) float Xs[16][128];
  __shared__ __align__(16) float Ws[16][128];
  __shared__ __align__(16) float red[16][132];
  const int b = blockIdx.z;
  const int n0 = blockIdx.x * 128, o0 = blockIdx.y * 128;
  const int tid = threadIdx.x;
  const int tn = tid & 15, to = tid >> 4;
  float acc[8][8];
  #pragma unroll
  for (int i = 0; i < 8; ++i)
    #pragma unroll
    for (int j = 0; j < 8; ++j) acc[i][j] = 0.f;

  const size_t xbase = (size_t)b * sxb;
  for (int c0 = 0; c0 < C; c0 += 16) {
    #pragma unroll
    for (int it = 0; it < 2; ++it) {
      const int task = tid + it * 256;
      const int kk = task >> 5, n4 = (task & 31) * 4;
      *reinterpret_cast<float4*>(&Xs[kk][n4]) =
        *reinterpret_cast<const float4*>(&X[xbase + (size_t)(c0 + kk) * scN + n0 + n4]);
      *reinterpret_cast<float4*>(&Ws[kk][n4]) =
        *reinterpret_cast<const float4*>(&WT[(size_t)(c0 + kk) * ldW + o0 + n4]);
    }
    __syncthreads();
    #pragma unroll
    for (int kk = 0; kk < 16; ++kk) {
      const float4 xa0 = *reinterpret_cast<const float4*>(&Xs[kk][tn * 4]);
      const float4 xa1 = *reinterpret_cast<const float4*>(&Xs[kk][64 + tn * 4]);
      const float4 wb0 = *reinterpret_cast<const float4*>(&Ws[kk][to * 4]);
      const float4 wb1 = *reinterpret_cast<const float4*>(&Ws[kk][64 + to * 4]);
      const float xr[8] = {xa0.x, xa0.y, xa0.z, xa0.w, xa1.x, xa1.y, xa1.z, xa1.w};
      const float wr[8] = {wb0.x, wb0.y, wb0.z, wb0.w, wb1.x, wb1.y, wb1.z, wb1.w};
      #pragma unroll
      for (int i = 0; i < 8; ++i)
        #pragma unroll
        for (int j = 0; j < 8; ++j) acc[i][j] = fmaf(xr[i], wr[j], acc[i][j]);
    }
    __syncthreads();
  }

  if (EPI == 0) {
    #pragma unroll
    for (int i = 0; i < 8; ++i) {
      const int n = n0 + (i >> 2) * 64 + tn * 4 + (i & 3);
      float4 s0 = make_float4(acc[i][0], acc[i][1], acc[i][2], acc[i][3]);
      float4 s1 = make_float4(acc[i][4], acc[i][5], acc[i][6], acc[i][7]);
      *reinterpret_cast<float4*>(&out[(size_t)b * sob + (size_t)n * son + o0 + to * 4]) = s0;
      *reinterpret_cast<float4*>(&out[(size_t)b * sob + (size_t)n * son + o0 + 64 + to * 4]) = s1;
    }
  } else {
    #pragma unroll
    for (int j = 0; j < 8; ++j) {
      float m = lrelu(acc[0][j]);
      #pragma unroll
      for (int i = 1; i < 8; ++i) m = fmaxf(m, lrelu(acc[i][j]));
      red[tn][(j >> 2) * 64 + to * 4 + (j & 3)] = m;
    }
    __syncthreads();
    if (tid < 128) {
      float m = red[0][tid];
      #pragma unroll
      for (int t = 1; t < 16; ++t) m = fmaxf(m, red[t][tid]);
      out[(size_t)b * sob + (size_t)blockIdx.x * snb + o0 + tid] = m;
    }
  }
}

// ---- bf16 MFMA GEMM ----
template<int EPI>
__global__ __launch_bounds__(256)
void gemm_mfma_kernel(const ushort* __restrict__ Xg, long sxb, int ldX,
                      const ushort* __restrict__ Wg, int ldW, int K,
                      float* __restrict__ out, long sob, int son, int snb) {
  __shared__ __align__(16) ushort As[128 * 64];
  __shared__ __align__(16) ushort Bs[128 * 64];
  __shared__ float red[2][128];
  const int b = blockIdx.z;
  const int n0 = blockIdx.x * 128, o0 = blockIdx.y * 128;
  const int tid = threadIdx.x;
  const int lane = tid & 63;
  const int wrow = (tid >> 6) >> 1, wcol = (tid >> 6) & 1;
  f32x4 acc[4][4];
  #pragma unroll
  for (int i = 0; i < 4; ++i)
    #pragma unroll
    for (int j = 0; j < 4; ++j)
      #pragma unroll
      for (int r = 0; r < 4; ++r) acc[i][j][r] = 0.f;

  const ushort* Xb = Xg + (size_t)b * sxb;
  for (int kb = 0; kb < K; kb += 64) {
    #pragma unroll
    for (int i = 0; i < 4; ++i) {
      const int idx = i * 256 + tid;
      const int n = idx >> 3, kc = idx & 7;
      const bf16x8 xv = *reinterpret_cast<const bf16x8*>(&Xb[(size_t)(n0 + n) * ldX + kb + kc * 8]);
      const bf16x8 wv = *reinterpret_cast<const bf16x8*>(&Wg[(size_t)(o0 + n) * ldW + kb + kc * 8]);
      const int ad = n * 128 + ((kc * 16) ^ ((n & 7) << 4));
      *reinterpret_cast<bf16x8*>((char*)As + ad) = xv;
      *reinterpret_cast<bf16x8*>((char*)Bs + ad) = wv;
    }
    __syncthreads();
    #pragma unroll
    for (int s = 0; s < 2; ++s) {
      bf16x8 af[4], bfr[4];
      const int klane = (s * 64 + ((lane >> 4) << 4));
      #pragma unroll
      for (int f = 0; f < 4; ++f) {
        const int nl = wrow * 64 + f * 16 + (lane & 15);
        af[f] = *reinterpret_cast<const bf16x8*>((char*)As + nl * 128 + (klane ^ ((nl & 7) << 4)));
        const int ol = wcol * 64 + f * 16 + (lane & 15);
        bfr[f] = *reinterpret_cast<const bf16x8*>((char*)Bs + ol * 128 + (klane ^ ((ol & 7) << 4)));
      }
      #pragma unroll
      for (int i = 0; i < 4; ++i)
        #pragma unroll
        for (int j = 0; j < 4; ++j)
          acc[i][j] = __builtin_amdgcn_mfma_f32_16x16x32_bf16(af[i], bfr[j], acc[i][j], 0, 0, 0);
    }
    __syncthreads();
  }

  if (EPI == 0) {
    #pragma unroll
    for (int i = 0; i < 4; ++i)
      #pragma unroll
      for (int r = 0; r < 4; ++r) {
        const int n = n0 + wrow * 64 + i * 16 + ((lane >> 4) << 2) + r;
        #pragma unroll
        for (int j = 0; j < 4; ++j) {
          const int o = o0 + wcol * 64 + j * 16 + (lane & 15);
          out[(size_t)b * sob + (size_t)n * son + o] = acc[i][j][r];
        }
      }
  } else {
    #pragma unroll
    for (int j = 0; j < 4; ++j) {
      float m = -3.4e38f;
      #pragma unroll
      for (int i = 0; i < 4; ++i)
        #pragma unroll
        for (int r = 0; r < 4; ++r) m = fmaxf(m, lrelu(acc[i][j][r]));
      m = fmaxf(m, __shfl_xor(m, 16));
      m = fmaxf(m, __shfl_xor(m, 32));
      if (lane < 16) red[wrow][wcol * 64 + j * 16 + lane] = m;
    }
    __syncthreads();
    if (tid < 128) {
      float m = fmaxf(red[0][tid], red[1][tid]);
      out[(size_t)b * sob + (size_t)blockIdx.x * snb + o0 + tid] = m;
    }
  }
}

// ---- edge max, channel-major fp32 output + NC bf16 copy for MFMA consumers ----
template<int O, int TI>
__global__ __launch_bounds__(256)
void edge_max_cn_kernel(const float* __restrict__ y, const float* __restrict__ z,
                        const int* __restrict__ idx, float* __restrict__ outCN,
                        float* __restrict__ xx, ushort* __restrict__ xbf, int choff) {
  __shared__ float tile[TI][O + 1];
  const int b = blockIdx.y;
  const int i0 = blockIdx.x * TI;
  const int wv = threadIdx.x >> 6, lane = threadIdx.x & 63;
  constexpr int OSEG = O / 64;
  constexpr int ROUNDS = TI * OSEG / 4;
  for (int r = 0; r < ROUNDS; ++r) {
    const int item = r * 4 + wv;
    const int il = item / OSEG, os = item - il * OSEG;
    const int i = i0 + il, o = os * 64 + lane;
    const int* ip = idx + (size_t)(b * NPTS + i) * KNN;
    const float zv = z[(size_t)(b * NPTS + i) * O + o];
    float m = -3.4e38f;
    #pragma unroll
    for (int t = 0; t < KNN; ++t) {
      int j = ip[t];
      float v = y[(size_t)(b * NPTS + j) * O + o] + zv;
      m = fmaxf(m, lrelu(v));
    }
    tile[il][o] = m;
    xbf[(size_t)(b * NPTS + i) * 512 + choff + o] = f2bf(m);
  }
  __syncthreads();
  if (xx != nullptr && threadIdx.x < TI) {
    const int il = threadIdx.x;
    float s = 0.f;
    #pragma unroll
    for (int o = 0; o < O; ++o) { float v = tile[il][o]; s = fmaf(v, v, s); }
    xx[b * NPTS + i0 + il] = s;
  }
  for (int e = threadIdx.x; e < TI * O; e += 256) {
    const int o = e / TI, il = e - o * TI;
    outCN[(size_t)b * 512 * NPTS + (size_t)o * NPTS + i0 + il] = tile[il][o];
  }
}

// ---- h12 as edge-GEMM ----
__global__ __launch_bounds__(256)
void h12_gemm_kernel(const float* __restrict__ ya, const float* __restrict__ zb,
                     const int* __restrict__ idx, const float* __restrict__ tw2T,
                     float* __restrict__ h2m) {
  __shared__ __align__(16) float h1s[80][68];
  __shared__ __align__(16) float ws[64][128];
  __shared__ __align__(16) float zbs[4][64];
  __shared__ float ot[128][4];
  __shared__ int idxs[4][KNN];
  const int b = blockIdx.y;
  const int i0 = blockIdx.x * 4;
  const int tid = threadIdx.x;

  #pragma unroll
  for (int it = 0; it < 8; ++it) {
    const int f = tid + it * 256;
    *reinterpret_cast<float4*>(&ws[0][0] + f * 4) =
      *reinterpret_cast<const float4*>(tw2T + (size_t)f * 4);
  }
  if (tid < 64) {
    const int p = tid >> 4, cq = (tid & 15) * 4;
    *reinterpret_cast<float4*>(&zbs[p][cq]) =
      *reinterpret_cast<const float4*>(&zb[(size_t)(b * NPTS + i0 + p) * 64 + cq]);
  }
  if (tid >= 64 && tid < 64 + 4 * KNN) {
    const int e = tid - 64;
    idxs[e / KNN][e % KNN] = idx[(size_t)(b * NPTS + i0) * KNN + e];
  }
  __syncthreads();

  #pragma unroll
  for (int it = 0; it < 5; ++it) {
    const int task = tid + it * 256;
    const int e = task >> 4, cq = (task & 15) * 4;
    const int p = e / KNN, t = e - p * KNN;
    const int j = idxs[p][t];
    const float4 yv = *reinterpret_cast<const float4*>(&ya[(size_t)(b * NPTS + j) * 64 + cq]);
    const float4 zv = *reinterpret_cast<const float4*>(&zbs[p][cq]);
    float4 hv;
    hv.x = lrelu(yv.x + zv.x); hv.y = lrelu(yv.y + zv.y);
    hv.z = lrelu(yv.z + zv.z); hv.w = lrelu(yv.w + zv.w);
    *reinterpret_cast<float4*>(&h1s[e][cq]) = hv;
  }
  __syncthreads();

  const int eg = tid >> 4, og = tid & 15;
  float acc[5][8];
  #pragma unroll
  for (int u = 0; u < 5; ++u)
    #pragma unroll
    for (int v = 0; v < 8; ++v) acc[u][v] = 0.f;
  #pragma unroll 4
  for (int kk = 0; kk < 64; ++kk) {
    float hv[5];
    #pragma unroll
    for (int u = 0; u < 5; ++u) hv[u] = h1s[eg * 5 + u][kk];
    const float4 w0 = *reinterpret_cast<const float4*>(&ws[kk][og * 4]);
    const float4 w1 = *reinterpret_cast<const float4*>(&ws[kk][64 + og * 4]);
    const float wr[8] = {w0.x, w0.y, w0.z, w0.w, w1.x, w1.y, w1.z, w1.w};
    #pragma unroll
    for (int u = 0; u < 5; ++u)
      #pragma unroll
      for (int v = 0; v < 8; ++v) acc[u][v] = fmaf(hv[u], wr[v], acc[u][v]);
  }

  const int p = eg >> 2, d = eg & 3;
  float m[8];
  #pragma unroll
  for (int v = 0; v < 8; ++v) {
    float mm = lrelu(acc[0][v]);
    #pragma unroll
    for (int u = 1; u < 5; ++u) mm = fmaxf(mm, lrelu(acc[u][v]));
    mm = fmaxf(mm, __shfl_xor(mm, 16));
    mm = fmaxf(mm, __shfl_xor(mm, 32));
    m[v] = mm;
  }
  if (d == 0) {
    #pragma unroll
    for (int v = 0; v < 8; ++v) {
      const int o = og * 4 + (v & 3) + (v >> 2) * 64;
      ot[o][p] = m[v];
    }
  }
  __syncthreads();
  if (tid < 128) {
    float4 st = make_float4(ot[tid][0], ot[tid][1], ot[tid][2], ot[tid][3]);
    *reinterpret_cast<float4*>(&h2m[(size_t)(b * 128 + tid) * NPTS + i0]) = st;
  }
}

// ---- reduce partial max over nt n-tiles ----
__global__ __launch_bounds__(256)
void reduce_max_kernel(const float* __restrict__ part, float* __restrict__ outp, int nt) {
  const int b = blockIdx.y;
  const int o = blockIdx.x * 256 + threadIdx.x;
  float m = part[(size_t)(b * nt) * 1024 + o];
  for (int t = 1; t < nt; ++t) m = fmaxf(m, part[(size_t)(b * nt + t) * 1024 + o]);
  outp[b * 1024 + o] = m;
}

// ---- block reduce helper ----
__device__ __forceinline__ float block_reduce_sum(float v, float* rbuf) {
  #pragma unroll
  for (int off = 32; off > 0; off >>= 1) v += __shfl_xor(v, off);
  const int w = threadIdx.x >> 6, lane = threadIdx.x & 63;
  const int nw = blockDim.x >> 6;
  if (lane == 0) rbuf[w] = v;
  __syncthreads();
  float tot = 0.f;
  for (int i = 0; i < nw; ++i) tot += rbuf[i];
  __syncthreads();
  return tot;
}

// ---- fused: max-reduce(part) -> fc1 -> fc2 -> fc3(+I) -> xform, one block per batch ----
__global__ __launch_bounds__(256)
void fcall_kernel(const float* __restrict__ part,
                  const float* __restrict__ Wt1, const float* __restrict__ g1,
                  const float* __restrict__ bb1,
                  const float* __restrict__ Wt2, const float* __restrict__ bias2,
                  const float* __restrict__ g2, const float* __restrict__ bb2,
                  const float* __restrict__ Wt3, const float* __restrict__ bb3,
                  const float* __restrict__ x, float* __restrict__ xt) {
  __shared__ __align__(16) float gin[1024];
  __shared__ __align__(16) float f1s[512];
  __shared__ float f2s[256];
  __shared__ float hbuf[512];
  __shared__ float rbuf[8];
  __shared__ float tm[9];
  const int b = blockIdx.x, tid = threadIdx.x;
  // stage 0: max over 8 n-tiles
  for (int e = tid; e < 1024; e += 256) {
    const float* pp = part + (size_t)b * 8192 + e;
    float m = pp[0];
    #pragma unroll
    for (int t = 1; t < 8; ++t) m = fmaxf(m, pp[t * 1024]);
    gin[e] = m;
  }
  __syncthreads();
  // stage 1: fc1 (l2n -> 1024x512 -> LN -> lrelu)
  float ps = 0.f;
  for (int e = tid; e < 1024; e += 256) ps = fmaf(gin[e], gin[e], ps);
  float ss = block_reduce_sum(ps, rbuf);
  float rinv = 1.0f / sqrtf(ss);
  #pragma unroll
  for (int r = 0; r < 2; ++r) {
    int o = tid + r * 256;
    const float* wrow = Wt1 + (size_t)o * 1024;
    float a = 0.f;
    for (int c4 = 0; c4 < 256; ++c4) {
      float4 wv = *reinterpret_cast<const float4*>(wrow + c4 * 4);
      float4 gv = *reinterpret_cast<const float4*>(&gin[c4 * 4]);
      a = fmaf(wv.x, gv.x, a); a = fmaf(wv.y, gv.y, a);
      a = fmaf(wv.z, gv.z, a); a = fmaf(wv.w, gv.w, a);
    }
    hbuf[o] = a * rinv;
  }
  __syncthreads();
  float pm = hbuf[tid] + hbuf[tid + 256];
  float mean = block_reduce_sum(pm, rbuf) * (1.f / 512.f);
  float d0 = hbuf[tid] - mean, d1 = hbuf[tid + 256] - mean;
  float var = block_reduce_sum(d0 * d0 + d1 * d1, rbuf) * (1.f / 512.f);
  float rs = 1.0f / sqrtf(var + 1e-5f);
  #pragma unroll
  for (int r = 0; r < 2; ++r) {
    int o = tid + r * 256;
    f1s[o] = lrelu((hbuf[o] - mean) * rs * g1[o] + bb1[o]);
  }
  __syncthreads();
  // stage 2: fc2 (l2n -> 512x256 +bias -> LN -> lrelu)
  float ps2 = 0.f;
  for (int e = tid; e < 512; e += 256) ps2 = fmaf(f1s[e], f1s[e], ps2);
  float ss2 = block_reduce_sum(ps2, rbuf);
  float rinv2 = 1.0f / sqrtf(ss2);
  const float* wrow2 = Wt2 + (size_t)tid * 512;
  float a2 = 0.f;
  for (int c4 = 0; c4 < 128; ++c4) {
    float4 wv = *reinterpret_cast<const float4*>(wrow2 + c4 * 4);
    float4 gv = *reinterpret_cast<const float4*>(&f1s[c4 * 4]);
    a2 = fmaf(wv.x, gv.x, a2); a2 = fmaf(wv.y, gv.y, a2);
    a2 = fmaf(wv.z, gv.z, a2); a2 = fmaf(wv.w, gv.w, a2);
  }
  a2 = a2 * rinv2 + bias2[tid];
  float mean2 = block_reduce_sum(a2, rbuf) * (1.f / 256.f);
  float dd = a2 - mean2;
  float var2 = block_reduce_sum(dd * dd, rbuf) * (1.f / 256.f);
  float rs2 = 1.0f / sqrtf(var2 + 1e-5f);
  f2s[tid] = lrelu((a2 - mean2) * rs2 * g2[tid] + bb2[tid]);
  __syncthreads();
  // stage 3: fc3 + identity
  if (tid < 9) {
    const float* wrow3 = Wt3 + tid * 256;
    float a3 = 0.f;
    for (int c = 0; c < 256; ++c) a3 = fmaf(wrow3[c], f2s[c], a3);
    a3 += bb3[tid];
    if (tid == 0 || tid == 4 || tid == 8) a3 += 1.f;
    tm[tid] = a3;
  }
  __syncthreads();
  // stage 4: xform
  const float* xb = x + (size_t)b * 3 * NPTS;
  float* ob = xt + (size_t)b * 3 * NPTS;
  #pragma unroll
  for (int nt = 0; nt < 4; ++nt) {
    const int n = nt * 256 + tid;
    const float x0 = xb[n], x1 = xb[NPTS + n], x2 = xb[2 * NPTS + n];
    #pragma unroll
    for (int i = 0; i < 3; ++i)
      ob[i * NPTS + n] = fmaf(tm[3 * i], x0, fmaf(tm[3 * i + 1], x1, tm[3 * i + 2] * x2));
  }
}

extern "C" void kernel_launch(void* const* d_in, const int* in_sizes, int n_in,
                              void* d_out, int out_size, void* d_ws, size_t ws_size,
                              hipStream_t stream) {
  (void)in_sizes; (void)n_in; (void)out_size; (void)ws_size;
  const float* x       = (const float*)d_in[0];
  const float* tw1     = (const float*)d_in[1];
  const float* tw2     = (const float*)d_in[2];
  const float* tw3     = (const float*)d_in[3];
  const float* tfc1_w  = (const float*)d_in[4];
  const float* tfc1_g  = (const float*)d_in[5];
  const float* tfc1_b  = (const float*)d_in[6];
  const float* tfc2_w  = (const float*)d_in[7];
  const float* tfc2_bias = (const float*)d_in[8];
  const float* tfc2_g  = (const float*)d_in[9];
  const float* tfc2_b  = (const float*)d_in[10];
  const float* tfc3_w  = (const float*)d_in[11];
  const float* tfc3_b  = (const float*)d_in[12];
  const float* w1      = (const float*)d_in[13];
  const float* w2      = (const float*)d_in[14];
  const float* w3      = (const float*)d_in[15];
  const float* w4      = (const float*)d_in[16];
  const float* w5      = (const float*)d_in[17];
  float* out = (float*)d_out;

  char* wsb = (char*)d_ws;
  size_t off = 0;
  auto alloc = [&](size_t bytes) -> void* {
    void* p = wsb + off;
    off += (bytes + 255) & ~(size_t)255;
    return p;
  };
  float* ybuf = (float*)alloc((size_t)BATCH * NPTS * 256 * 4);
  float* zbuf = (float*)alloc((size_t)BATCH * NPTS * 256 * 4);
  float* xcT  = (float*)alloc((size_t)BATCH * 512 * NPTS * 4);   // channel-major fp32 (knn)
  ushort* xc_bf = (ushort*)alloc((size_t)BATCH * NPTS * 512 * 2); // NC bf16 (MFMA)
  float* h2m  = (float*)alloc((size_t)BATCH * 128 * NPTS * 4);
  float* part = (float*)alloc((size_t)BATCH * 16 * 1024 * 4);
  int*   idxb = (int*)alloc((size_t)BATCH * NPTS * KNN * 4);
  float* xxb  = (float*)alloc((size_t)BATCH * NPTS * 4);
  float* xt   = (float*)alloc((size_t)BATCH * 3 * NPTS * 4);
  float* tw1aT = (float*)alloc(3 * 64 * 4);
  float* tw1dT = (float*)alloc(3 * 64 * 4);
  float* w1aT  = (float*)alloc(3 * 64 * 4);
  float* w1dT  = (float*)alloc(3 * 64 * 4);
  float* w2aT  = (float*)alloc(64 * 64 * 4);
  float* w2dT  = (float*)alloc(64 * 64 * 4);
  float* w3aT  = (float*)alloc(64 * 128 * 4);
  float* w3dT  = (float*)alloc(64 * 128 * 4);
  ushort* w4a_bf = (ushort*)alloc(256 * 128 * 2);
  ushort* w4d_bf = (ushort*)alloc(256 * 128 * 2);
  ushort* w5_bf  = (ushort*)alloc(1024 * 512 * 2);
  float* tw2T  = (float*)alloc(64 * 128 * 4);
  float* tw3T  = (float*)alloc(128 * 1024 * 4);

  // weight prep
  wsplit_t_kernel<<<1, 256, 0, stream>>>(tw1, tw1aT, tw1dT, 64, 3);
  wsplit_t_kernel<<<1, 256, 0, stream>>>(w1, w1aT, w1dT, 64, 3);
  wsplit_t_kernel<<<16, 256, 0, stream>>>(w2, w2aT, w2dT, 64, 64);
  wsplit_t_kernel<<<32, 256, 0, stream>>>(w3, w3aT, w3dT, 128, 64);
  wsplit_bf_kernel<<<128, 256, 0, stream>>>(w4, w4a_bf, w4d_bf, 256, 128);
  cvt_bf16_kernel<<<2048, 256, 0, stream>>>(w5, w5_bf, 1024 * 512);
  wtrans_kernel<<<32, 256, 0, stream>>>(tw2, tw2T, 128, 64);
  wtrans_kernel<<<512, 256, 0, stream>>>(tw3, tw3T, 1024, 128);

  // ---- transform net ----
  xx3_kernel<<<dim3(4, 16), 256, 0, stream>>>(x, xxb);
  knn_cn_kernel<3><<<dim3(64, 16), 256, 0, stream>>>(x, 3 * NPTS, xxb, idxb);
  gemm_dual_kernel<<<dim3(16, 1, 16), 256, 0, stream>>>(x, 3 * NPTS, 1, NPTS, tw1aT, tw1dT,
                                                        64, 3, ybuf, zbuf, NPTS * 64, 64);
  h12_gemm_kernel<<<dim3(256, 16), 256, 0, stream>>>(ybuf, zbuf, idxb, tw2T, h2m);
  gemm128_kernel<1><<<dim3(8, 8, 16), 256, 0, stream>>>(h2m, 128 * NPTS, NPTS, tw3T, 1024, 128,
                                                        part, 8 * 1024, 0, 1024);
  fcall_kernel<<<16, 256, 0, stream>>>(part, tfc1_w, tfc1_g, tfc1_b,
                                       tfc2_w, tfc2_bias, tfc2_g, tfc2_b,
                                       tfc3_w, tfc3_b, x, xt);

  // ---- EdgeConv 1 (C=3 -> O=64) on xt ----
  xx3_kernel<<<dim3(4, 16), 256, 0, stream>>>(xt, xxb);
  knn_cn_kernel<3><<<dim3(64, 16), 256, 0, stream>>>(xt, 3 * NPTS, xxb, idxb);
  gemm_dual_kernel<<<dim3(16, 1, 16), 256, 0, stream>>>(xt, 3 * NPTS, 1, NPTS, w1aT, w1dT,
                                                        64, 3, ybuf, zbuf, NPTS * 64, 64);
  edge_max_cn_kernel<64, 64><<<dim3(16, 16), 256, 0, stream>>>(ybuf, zbuf, idxb, xcT, xxb,
                                                               xc_bf, 0);

  // ---- EdgeConv 2 (C=64 -> O=64) ----
  knn_cn_kernel<64><<<dim3(64, 16), 256, 0, stream>>>(xcT, 512 * NPTS, xxb, idxb);
  gemm_dual_kernel<<<dim3(16, 1, 16), 256, 0, stream>>>(xcT, 512 * NPTS, 1, NPTS, w2aT, w2dT,
                                                        64, 64, ybuf, zbuf, NPTS * 64, 64);
  edge_max_cn_kernel<64, 64><<<dim3(16, 16), 256, 0, stream>>>(ybuf, zbuf, idxb,
                                                               xcT + 64 * NPTS, xxb, xc_bf, 64);

  // ---- EdgeConv 3 (C=64 -> O=128) ----
  knn_cn_kernel<64><<<dim3(64, 16), 256, 0, stream>>>(xcT + 64 * NPTS, 512 * NPTS, xxb, idxb);
  gemm_dual_kernel<<<dim3(16, 2, 16), 256, 0, stream>>>(xcT + 64 * NPTS, 512 * NPTS, 1, NPTS,
                                                        w3aT, w3dT, 128, 64,
                                                        ybuf, zbuf, NPTS * 128, 128);
  edge_max_cn_kernel<128, 64><<<dim3(16, 16), 256, 0, stream>>>(ybuf, zbuf, idxb,
                                                                xcT + 128 * NPTS, xxb, xc_bf, 128);

  // ---- EdgeConv 4 (C=128 -> O=256): bf16 MFMA GEMMs on x3 slice (knn-safe) ----
  knn_cn_kernel<128><<<dim3(64, 16), 256, 0, stream>>>(xcT + 128 * NPTS, 512 * NPTS, xxb, idxb);
  gemm_mfma_kernel<0><<<dim3(8, 2, 16), 256, 0, stream>>>(xc_bf + 128, (long)NPTS * 512, 512,
                                                          w4a_bf, 128, 128,
                                                          ybuf, (long)NPTS * 256, 256, 0);
  gemm_mfma_kernel<0><<<dim3(8, 2, 16), 256, 0, stream>>>(xc_bf + 128, (long)NPTS * 512, 512,
                                                          w4d_bf, 128, 128,
                                                          zbuf, (long)NPTS * 256, 256, 0);
  edge_max_cn_kernel<256, 32><<<dim3(32, 16), 256, 0, stream>>>(ybuf, zbuf, idxb,
                                                                xcT + 256 * NPTS, nullptr,
                                                                xc_bf, 256);

  // ---- final: x5 = lrelu(w5 @ xc) with max over n — bf16 MFMA (knn-safe) ----
  gemm_mfma_kernel<1><<<dim3(8, 8, 16), 256, 0, stream>>>(xc_bf, (long)NPTS * 512, 512,
                                                          w5_bf, 512, 512,
                                                          part, 8 * 1024, 0, 1024);
  reduce_max_kernel<<<dim3(4, 16), 256, 0, stream>>>(part, out, 8);
}